// Round 4
// baseline (386.782 us; speedup 1.0000x reference)
//
#include <hip/hip_runtime.h>
#include <hip/hip_bf16.h>

// Problem constants
#define NN   10000      // nodes
#define NE   160000     // edges
#define NEP  170000     // edges + self loops
#define NEPA 170240     // padded plane stride for cex1t
#define IND  20         // input feature dim
#define HIDD 256        // hidden per head
#define NH   4          // heads layer 1
#define HCD  1024       // HEADS*HID
#define LATD 1024
#define MPAD 10112      // padded rows for h1b (>= 313*32 = 10016)

typedef __attribute__((ext_vector_type(8))) short short8v;   // 8 bf16 (4 VGPRs)
typedef __attribute__((ext_vector_type(4))) float f32x4;     // MFMA accumulator

__device__ __forceinline__ unsigned pk2(float a, float b) {
    union { __hip_bfloat16 h; unsigned short s; } x, y;
    x.h = __float2bfloat16(a); y.h = __float2bfloat16(b);
    return (unsigned)x.s | ((unsigned)y.s << 16);
}

// ---------------- block reduction helper (shuffle + tiny smem) ----------------
__device__ __forceinline__ float block_reduce_sum1(float v, float* sm) {
    #pragma unroll
    for (int o = 32; o > 0; o >>= 1) v += __shfl_xor(v, o, 64);
    int wid = threadIdx.x >> 6, lane = threadIdx.x & 63, nw = blockDim.x >> 6;
    if (lane == 0) sm[wid] = v;
    __syncthreads();
    float r = 0.f;
    for (int i = 0; i < nw; i++) r += sm[i];
    __syncthreads();
    return r;
}

// ---------------- tiny precompute: collapsed attention matrices ----------------
__global__ void k_prep(const float* __restrict__ W1, const float* __restrict__ as1,
                       const float* __restrict__ ad1, const float* __restrict__ We1,
                       const float* __restrict__ ae1, const float* __restrict__ We2,
                       const float* __restrict__ ae2, float* __restrict__ prm) {
    int t = threadIdx.x;
    if (t < 80) {
        int i = t >> 2, h = t & 3; float s = 0.f;
        for (int c = 0; c < HIDD; c++) s += W1[i*HCD + h*HIDD + c] * as1[h*HIDD + c];
        prm[t] = s;
    } else if (t < 160) {
        int u = t - 80; int i = u >> 2, h = u & 3; float s = 0.f;
        for (int c = 0; c < HIDD; c++) s += W1[i*HCD + h*HIDD + c] * ad1[h*HIDD + c];
        prm[t] = s;
    } else if (t < 172) {
        int u = t - 160; int j = u >> 2, h = u & 3; float s = 0.f;
        for (int c = 0; c < HIDD; c++) s += We1[j*HCD + h*HIDD + c] * ae1[h*HIDD + c];
        prm[t] = s;
    } else if (t < 175) {
        int j = t - 172; float s = 0.f;
        for (int c = 0; c < HIDD; c++) s += We2[j*HIDD + c] * ae2[c];
        prm[t] = s;
    }
}

// ---------------- degree + self-loop edge-attr sums ----------------
__global__ void k_deg(const int* __restrict__ ei, const float* __restrict__ ea,
                      float* __restrict__ cnt, float* __restrict__ lea3) {
    int e = blockIdx.x * 256 + threadIdx.x;
    if (e >= NE) return;
    int d = ei[NE + e];
    atomicAdd(&cnt[d], 1.0f);
    atomicAdd(&lea3[d*3+0], ea[e*3+0]);
    atomicAdd(&lea3[d*3+1], ea[e*3+1]);
    atomicAdd(&lea3[d*3+2], ea[e*3+2]);
}

// ---------------- exclusive scan of (deg+1) -> CSR offsets ----------------
__global__ void k_scan(const float* __restrict__ cnt, int* __restrict__ offs) {
    __shared__ int sm[1024];
    int t = threadIdx.x;
    int base = t * 10;
    int loc[10]; int s = 0;
    if (t < 1000) {
        #pragma unroll
        for (int i = 0; i < 10; i++) { loc[i] = s; s += (int)cnt[base + i] + 1; }
    }
    sm[t] = (t < 1000) ? s : 0;
    __syncthreads();
    for (int o = 1; o < 1024; o <<= 1) {
        int x = (t >= o) ? sm[t - o] : 0;
        __syncthreads();
        sm[t] += x;
        __syncthreads();
    }
    int pre = (t > 0) ? sm[t - 1] : 0;
    if (t < 1000) {
        #pragma unroll
        for (int i = 0; i < 10; i++) offs[base + i] = pre + loc[i];
    }
    if (t == 1023) offs[NN] = sm[1023];
}

// ---------------- h1 = x @ W1  (store bf16) ----------------
__global__ void k_gemm1(const float* __restrict__ x, const float* __restrict__ W1,
                        __hip_bfloat16* __restrict__ h1) {
    __shared__ float xs[8][IND];
    int t = threadIdx.x;
    int n0 = blockIdx.x * 8;
    int c = blockIdx.y * 256 + t;
    if (t < 8 * IND) xs[t / IND][t % IND] = x[n0 * IND + t];
    __syncthreads();
    float acc[8] = {0.f,0.f,0.f,0.f,0.f,0.f,0.f,0.f};
    #pragma unroll
    for (int i = 0; i < IND; i++) {
        float w = W1[i * HCD + c];
        #pragma unroll
        for (int m = 0; m < 8; m++) acc[m] += xs[m][i] * w;
    }
    #pragma unroll
    for (int m = 0; m < 8; m++) h1[(size_t)(n0 + m) * HCD + c] = __float2bfloat16(acc[m]);
}

// ---------------- al_src1/al_dst1 = x @ A (collapsed) ----------------
__global__ void k_al1(const float* __restrict__ x, const float* __restrict__ prm,
                      float* __restrict__ al1) {
    int v = blockIdx.x * 256 + threadIdx.x;
    if (v >= NN) return;
    float xr[IND];
    #pragma unroll
    for (int i = 0; i < IND; i++) xr[i] = x[v * IND + i];
    #pragma unroll
    for (int h = 0; h < NH; h++) {
        float s = 0.f, d = 0.f;
        #pragma unroll
        for (int i = 0; i < IND; i++) { s += xr[i] * prm[i*4 + h]; d += xr[i] * prm[80 + i*4 + h]; }
        al1[v*8 + h] = s;
        al1[v*8 + 4 + h] = d;
    }
}

// ---------------- edge pass layer 1: logits -> exp (SoA planes), CSR fill ----------------
__global__ void k_edge1(const int* __restrict__ ei, const float* __restrict__ ea,
                        const float* __restrict__ cnt, const float* __restrict__ lea3,
                        const float* __restrict__ al1, const float* __restrict__ prm,
                        const int* __restrict__ offs, int* __restrict__ fill1,
                        int* __restrict__ eslot, int* __restrict__ csrs,
                        float* __restrict__ cex1t) {
    int e = blockIdx.x * 256 + threadIdx.x;
    if (e >= NEP) return;
    int s, d; float e0, e1, e2;
    if (e < NE) {
        s = ei[e]; d = ei[NE + e];
        e0 = ea[e*3]; e1 = ea[e*3+1]; e2 = ea[e*3+2];
    } else {
        int v = e - NE; s = v; d = v;
        float ic = 1.f / fmaxf(cnt[v], 1.0f);
        e0 = lea3[v*3] * ic; e1 = lea3[v*3+1] * ic; e2 = lea3[v*3+2] * ic;
    }
    int slot = offs[d] + atomicAdd(&fill1[d], 1);
    eslot[e] = slot;
    csrs[slot] = s;
    #pragma unroll
    for (int h = 0; h < NH; h++) {
        float le = e0 * prm[160 + h] + e1 * prm[164 + h] + e2 * prm[168 + h];
        float lg = al1[s*8 + h] + al1[d*8 + 4 + h] + le;
        lg = lg > 0.f ? lg : 0.2f * lg;
        cex1t[(size_t)h * NEPA + slot] = expf(lg);
    }
}

// ---------------- layer-1 aggregation + bias + ELU + LN, wave-per-node ----------------
// Lane l owns features 16l..16l+15. Head/plane = l>>4. Single pass: accumulate
// unnormalized sum + denominator, scale at the end.
#define UNPK(U, A0, A1, AW) { unsigned _u = (U); A0 += AW * __uint_as_float(_u << 16); A1 += AW * __uint_as_float(_u & 0xffff0000u); }
__global__ void __launch_bounds__(256)
k_agg1(const int* __restrict__ offs, const int* __restrict__ csrs,
       const float* __restrict__ cex1t, const __hip_bfloat16* __restrict__ h1,
       const float* __restrict__ b1, const float* __restrict__ g1,
       const float* __restrict__ be1, __hip_bfloat16* __restrict__ h1b) {
    int l = threadIdx.x & 63;
    int v = blockIdx.x * 4 + (threadIdx.x >> 6);
    int beg = offs[v], end = offs[v + 1];
    int c = l >> 4;
    const float* plane = cex1t + (size_t)c * NEPA;
    const uint4* hU = (const uint4*)h1;
    float c0=0,c1=0,c2=0,c3=0,c4=0,c5=0,c6=0,c7=0,c8=0,c9=0,c10=0,c11=0,c12=0,c13=0,c14=0,c15=0;
    float ps = 0.f;
    int j = beg;
    while (j < end) {
        int nb = end - j; if (nb > 64) nb = 64;
        int jl = j + l; if (jl > end - 1) jl = end - 1;
        int sidx = csrs[jl];
        int u = 0;
        for (; u + 2 <= nb; u += 2) {
            int s0 = __shfl(sidx, u, 64);
            int s1 = __shfl(sidx, u + 1, 64);
            float a0 = plane[j + u];
            float a1 = plane[j + u + 1];
            uint4 p0 = hU[(size_t)s0 * 128 + l * 2];
            uint4 p1 = hU[(size_t)s0 * 128 + l * 2 + 1];
            uint4 q0 = hU[(size_t)s1 * 128 + l * 2];
            uint4 q1 = hU[(size_t)s1 * 128 + l * 2 + 1];
            ps += a0 + a1;
            UNPK(p0.x, c0, c1, a0)  UNPK(p0.y, c2, c3, a0)  UNPK(p0.z, c4, c5, a0)  UNPK(p0.w, c6, c7, a0)
            UNPK(p1.x, c8, c9, a0)  UNPK(p1.y, c10,c11,a0)  UNPK(p1.z, c12,c13,a0)  UNPK(p1.w, c14,c15,a0)
            UNPK(q0.x, c0, c1, a1)  UNPK(q0.y, c2, c3, a1)  UNPK(q0.z, c4, c5, a1)  UNPK(q0.w, c6, c7, a1)
            UNPK(q1.x, c8, c9, a1)  UNPK(q1.y, c10,c11,a1)  UNPK(q1.z, c12,c13,a1)  UNPK(q1.w, c14,c15,a1)
        }
        if (u < nb) {
            int s0 = __shfl(sidx, u, 64);
            float a0 = plane[j + u];
            uint4 p0 = hU[(size_t)s0 * 128 + l * 2];
            uint4 p1 = hU[(size_t)s0 * 128 + l * 2 + 1];
            ps += a0;
            UNPK(p0.x, c0, c1, a0)  UNPK(p0.y, c2, c3, a0)  UNPK(p0.z, c4, c5, a0)  UNPK(p0.w, c6, c7, a0)
            UNPK(p1.x, c8, c9, a0)  UNPK(p1.y, c10,c11,a0)  UNPK(p1.z, c12,c13,a0)  UNPK(p1.w, c14,c15,a0)
        }
        j += nb;
    }
    float inv = 1.f / (ps + 1e-16f);
    float vv[16] = {c0,c1,c2,c3,c4,c5,c6,c7,c8,c9,c10,c11,c12,c13,c14,c15};
    // bias + ELU (scale by inv first)
    const float4* b4 = (const float4*)(b1 + 16 * l);
    float lsum = 0.f;
    #pragma unroll
    for (int q = 0; q < 4; q++) {
        float4 bb = b4[q];
        float xv;
        xv = vv[4*q+0] * inv + bb.x; xv = xv > 0.f ? xv : expm1f(xv); vv[4*q+0] = xv; lsum += xv;
        xv = vv[4*q+1] * inv + bb.y; xv = xv > 0.f ? xv : expm1f(xv); vv[4*q+1] = xv; lsum += xv;
        xv = vv[4*q+2] * inv + bb.z; xv = xv > 0.f ? xv : expm1f(xv); vv[4*q+2] = xv; lsum += xv;
        xv = vv[4*q+3] * inv + bb.w; xv = xv > 0.f ? xv : expm1f(xv); vv[4*q+3] = xv; lsum += xv;
    }
    // LayerNorm over 1024 via wave butterfly
    #pragma unroll
    for (int o = 1; o <= 32; o <<= 1) lsum += __shfl_xor(lsum, o, 64);
    float mu = lsum * (1.f / 1024.f);
    float q2 = 0.f;
    #pragma unroll
    for (int i = 0; i < 16; i++) { float dv = vv[i] - mu; q2 += dv * dv; }
    #pragma unroll
    for (int o = 1; o <= 32; o <<= 1) q2 += __shfl_xor(q2, o, 64);
    float rstd = rsqrtf(q2 * (1.f / 1024.f) + 1e-5f);
    const float4* g4 = (const float4*)(g1 + 16 * l);
    const float4* e4 = (const float4*)(be1 + 16 * l);
    unsigned ou[8];
    #pragma unroll
    for (int q = 0; q < 4; q++) {
        float4 gg = g4[q], ee = e4[q];
        float y0 = gg.x * (vv[4*q+0] - mu) * rstd + ee.x;
        float y1 = gg.y * (vv[4*q+1] - mu) * rstd + ee.y;
        float y2 = gg.z * (vv[4*q+2] - mu) * rstd + ee.z;
        float y3 = gg.w * (vv[4*q+3] - mu) * rstd + ee.w;
        ou[2*q]   = pk2(y0, y1);
        ou[2*q+1] = pk2(y2, y3);
    }
    uint4* dst = (uint4*)(h1b + (size_t)v * HCD + 16 * l);
    dst[0] = make_uint4(ou[0], ou[1], ou[2], ou[3]);
    dst[1] = make_uint4(ou[4], ou[5], ou[6], ou[7]);
}

// ---------------- W2 -> W2t[256][1024] bf16 (LDS-tiled transpose) ----------------
__global__ void k_w2t(const float* __restrict__ W2, __hip_bfloat16* __restrict__ Bt) {
    __shared__ float sm[64][65];
    int t = threadIdx.x;
    int k0 = blockIdx.x * 64, c0 = blockIdx.y * 64;
    #pragma unroll
    for (int i = 0; i < 16; i++) {
        int idx = i * 256 + t;
        int r = idx >> 6, c = idx & 63;
        sm[r][c] = W2[(size_t)(k0 + r) * 256 + c0 + c];
    }
    __syncthreads();
    int c = t >> 2, kq = t & 3;
    unsigned int out[8];
    #pragma unroll
    for (int j = 0; j < 8; j++)
        out[j] = pk2(sm[kq * 16 + 2*j][c], sm[kq * 16 + 2*j + 1][c]);
    unsigned int* dst = (unsigned int*)(Bt + (size_t)(c0 + c) * 1024 + k0 + kq * 16);
    *(uint4*)dst = make_uint4(out[0], out[1], out[2], out[3]);
    *(uint4*)(dst + 4) = make_uint4(out[4], out[5], out[6], out[7]);
}

// ---------------- h2b = h1b @ W2t^T via MFMA bf16; BM=32, BN=256 ----------------
__global__ void __launch_bounds__(256)
k_gemm2m(const __hip_bfloat16* __restrict__ A, const __hip_bfloat16* __restrict__ Bt,
         __hip_bfloat16* __restrict__ h2b) {
    __shared__ uint4 As4[256];   // 32 rows x 64 bf16 = 4 KB, XOR-swizzled
    char* As = (char*)As4;
    int t = threadIdx.x, l = t & 63, w = t >> 6;
    int m0 = blockIdx.x * 32;
    int srow = t >> 3, skc = t & 7;
    const __hip_bfloat16* gA = A + (size_t)(m0 + srow) * 1024 + skc * 8;
    int wbyte = (srow * 128 + skc * 16) ^ ((srow & 7) << 4);
    int r0 = l & 15, g = l >> 4;
    int ra[2][2];
    #pragma unroll
    for (int m = 0; m < 2; m++)
        #pragma unroll
        for (int kk = 0; kk < 2; kk++) {
            int r = r0 + m * 16;
            ra[m][kk] = (r * 128 + kk * 64 + g * 16) ^ ((r & 7) << 4);
        }
    const __hip_bfloat16* gB = Bt + (size_t)(w * 64 + r0) * 1024 + g * 8;
    f32x4 acc[2][4];
    #pragma unroll
    for (int m = 0; m < 2; m++)
        #pragma unroll
        for (int n = 0; n < 4; n++) acc[m][n] = (f32x4){0.f,0.f,0.f,0.f};
    uint4 sreg = *(const uint4*)gA;
    for (int it = 0; it < 16; ++it) {
        *(uint4*)(As + wbyte) = sreg;
        __syncthreads();
        if (it < 15) sreg = *(const uint4*)(gA + (it + 1) * 64);
        int k0 = it * 64;
        short8v bfr[4][2];
        #pragma unroll
        for (int n = 0; n < 4; n++)
            #pragma unroll
            for (int kk = 0; kk < 2; kk++)
                bfr[n][kk] = *(const short8v*)(gB + (size_t)n * 16 * 1024 + k0 + kk * 32);
        short8v afr[2][2];
        #pragma unroll
        for (int m = 0; m < 2; m++)
            #pragma unroll
            for (int kk = 0; kk < 2; kk++)
                afr[m][kk] = *(const short8v*)(As + ra[m][kk]);
        #pragma unroll
        for (int kk = 0; kk < 2; kk++)
            #pragma unroll
            for (int m = 0; m < 2; m++)
                #pragma unroll
                for (int n = 0; n < 4; n++)
                    acc[m][n] = __builtin_amdgcn_mfma_f32_16x16x32_bf16(afr[m][kk], bfr[n][kk], acc[m][n], 0, 0, 0);
        __syncthreads();
    }
    #pragma unroll
    for (int m = 0; m < 2; m++) {
        #pragma unroll
        for (int r = 0; r < 4; r++) {
            int row = m0 + m * 16 + g * 4 + r;
            if (row < NN) {
                #pragma unroll
                for (int n = 0; n < 4; n++) {
                    int col = w * 64 + n * 16 + r0;
                    h2b[(size_t)row * HIDD + col] = __float2bfloat16(acc[m][n][r]);
                }
            }
        }
    }
}

// ---------------- al2 = h2b . a_src2 / a_dst2, wave-per-node ----------------
__global__ void __launch_bounds__(256)
k_al2(const __hip_bfloat16* __restrict__ h2b, const float* __restrict__ as2,
      const float* __restrict__ ad2, float* __restrict__ al2) {
    int l = threadIdx.x & 63;
    int v = blockIdx.x * 4 + (threadIdx.x >> 6);
    uint2 p = ((const uint2*)h2b)[(size_t)v * 64 + l];
    float f0 = __uint_as_float(p.x << 16), f1 = __uint_as_float(p.x & 0xffff0000u);
    float f2 = __uint_as_float(p.y << 16), f3 = __uint_as_float(p.y & 0xffff0000u);
    float4 sa = ((const float4*)as2)[l];
    float4 da = ((const float4*)ad2)[l];
    float s = f0*sa.x + f1*sa.y + f2*sa.z + f3*sa.w;
    float d = f0*da.x + f1*da.y + f2*da.z + f3*da.w;
    #pragma unroll
    for (int o = 1; o <= 32; o <<= 1) { s += __shfl_xor(s, o, 64); d += __shfl_xor(d, o, 64); }
    if (l == 0) { al2[v*2] = s; al2[v*2+1] = d; }
}

// ---------------- edge pass layer 2 (reuses CSR slots, inline self-loop attr) ------
__global__ void k_edge2(const int* __restrict__ ei, const float* __restrict__ ea,
                        const float* __restrict__ cnt, const float* __restrict__ lea3,
                        const float* __restrict__ al2, const float* __restrict__ prm,
                        const int* __restrict__ eslot, float* __restrict__ cex2) {
    int e = blockIdx.x * 256 + threadIdx.x;
    if (e >= NEP) return;
    int s, d; float e0, e1, e2;
    if (e < NE) {
        s = ei[e]; d = ei[NE + e];
        e0 = ea[e*3]; e1 = ea[e*3+1]; e2 = ea[e*3+2];
    } else {
        int v = e - NE; s = v; d = v;
        float ic = 1.f / fmaxf(cnt[v], 1.0f);
        e0 = lea3[v*3] * ic; e1 = lea3[v*3+1] * ic; e2 = lea3[v*3+2] * ic;
    }
    float lg = al2[s*2] + al2[d*2+1] + e0*prm[172] + e1*prm[173] + e2*prm[174];
    lg = lg > 0.f ? lg : 0.2f * lg;
    cex2[eslot[e]] = expf(lg);
}

// ---------------- layer-2 aggregation + bias + ELU + LN + pooling (fused) ----------
__global__ void __launch_bounds__(256)
k_agg2(const int* __restrict__ offs, const int* __restrict__ csrs,
       const float* __restrict__ cex2, const __hip_bfloat16* __restrict__ h2b,
       const float* __restrict__ b2, const float* __restrict__ g2,
       const float* __restrict__ be2, float* __restrict__ gsum,
       unsigned* __restrict__ gmaxU) {
    __shared__ float smS[4][256];
    int l = threadIdx.x & 63, w = threadIdx.x >> 6;
    int v = blockIdx.x * 4 + w;
    int beg = offs[v], end = offs[v + 1];
    float a0 = 0.f, a1 = 0.f, a2 = 0.f, a3 = 0.f, ps = 0.f;
    const uint2* hU = (const uint2*)h2b;
    int j = beg;
    while (j < end) {
        int nb = end - j; if (nb > 64) nb = 64;
        int jl = j + l; if (jl > end - 1) jl = end - 1;
        int sidx = csrs[jl];
        float av = cex2[jl];
        int u = 0;
        for (; u + 2 <= nb; u += 2) {
            int s0 = __shfl(sidx, u, 64);
            int s1 = __shfl(sidx, u + 1, 64);
            float w0 = __shfl(av, u, 64);
            float w1 = __shfl(av, u + 1, 64);
            uint2 p = hU[(size_t)s0 * 64 + l];
            uint2 q = hU[(size_t)s1 * 64 + l];
            ps += w0 + w1;
            a0 += w0 * __uint_as_float(p.x << 16);
            a1 += w0 * __uint_as_float(p.x & 0xffff0000u);
            a2 += w0 * __uint_as_float(p.y << 16);
            a3 += w0 * __uint_as_float(p.y & 0xffff0000u);
            a0 += w1 * __uint_as_float(q.x << 16);
            a1 += w1 * __uint_as_float(q.x & 0xffff0000u);
            a2 += w1 * __uint_as_float(q.y << 16);
            a3 += w1 * __uint_as_float(q.y & 0xffff0000u);
        }
        if (u < nb) {
            int s0 = __shfl(sidx, u, 64);
            float w0 = __shfl(av, u, 64);
            uint2 p = hU[(size_t)s0 * 64 + l];
            ps += w0;
            a0 += w0 * __uint_as_float(p.x << 16);
            a1 += w0 * __uint_as_float(p.x & 0xffff0000u);
            a2 += w0 * __uint_as_float(p.y << 16);
            a3 += w0 * __uint_as_float(p.y & 0xffff0000u);
        }
        j += nb;
    }
    float inv = 1.f / (ps + 1e-16f);
    float4 bb = ((const float4*)b2)[l];
    float v0 = a0 * inv + bb.x, v1 = a1 * inv + bb.y, v2 = a2 * inv + bb.z, v3 = a3 * inv + bb.w;
    v0 = v0 > 0.f ? v0 : expm1f(v0);
    v1 = v1 > 0.f ? v1 : expm1f(v1);
    v2 = v2 > 0.f ? v2 : expm1f(v2);
    v3 = v3 > 0.f ? v3 : expm1f(v3);
    float lsum = v0 + v1 + v2 + v3;
    #pragma unroll
    for (int o = 1; o <= 32; o <<= 1) lsum += __shfl_xor(lsum, o, 64);
    float mu = lsum * (1.f / 256.f);
    float q2 = (v0-mu)*(v0-mu) + (v1-mu)*(v1-mu) + (v2-mu)*(v2-mu) + (v3-mu)*(v3-mu);
    #pragma unroll
    for (int o = 1; o <= 32; o <<= 1) q2 += __shfl_xor(q2, o, 64);
    float rstd = rsqrtf(q2 * (1.f / 256.f) + 1e-5f);
    float4 gg = ((const float4*)g2)[l];
    float4 ee = ((const float4*)be2)[l];
    float4 outv;
    outv.x = gg.x * (v0 - mu) * rstd + ee.x;
    outv.y = gg.y * (v1 - mu) * rstd + ee.y;
    outv.z = gg.z * (v2 - mu) * rstd + ee.z;
    outv.w = gg.w * (v3 - mu) * rstd + ee.w;
    *((float4*)&smS[w][4 * l]) = outv;
    __syncthreads();
    int t = threadIdx.x;   // 256 threads == 256 features
    float s = smS[0][t] + smS[1][t] + smS[2][t] + smS[3][t];
    float m = fmaxf(fmaxf(smS[0][t], smS[1][t]), fmaxf(smS[2][t], smS[3][t]));
    atomicAdd(&gsum[t], s);
    unsigned b = __float_as_uint(m);
    unsigned k = (b & 0x80000000u) ? ~b : (b | 0x80000000u);
    atomicMax(&gmaxU[t], k);
}

// ---------------- decode pooled vector ----------------
__global__ void k_gvec(const float* __restrict__ gsum, const unsigned* __restrict__ gmaxU,
                       float* __restrict__ gvec) {
    int t = threadIdx.x;
    gvec[t] = gsum[t] * (1.f / (float)NN);
    unsigned u = gmaxU[t];
    unsigned b = (u & 0x80000000u) ? (u & 0x7fffffffu) : ~u;
    gvec[256 + t] = __uint_as_float(b);
}

// ---------------- final FC (+relu) and LN ----------------
__global__ void k_fc(const float* __restrict__ gvec, const float* __restrict__ Wfc,
                     const float* __restrict__ bfc, float* __restrict__ fcp) {
    int c = blockIdx.x * 128 + threadIdx.x;
    float acc = bfc[c];
    for (int i = 0; i < 512; i++) acc += gvec[i] * Wfc[i * LATD + c];
    fcp[c] = fmaxf(acc, 0.f);
}

__global__ void k_out(const float* __restrict__ fcp, const float* __restrict__ gf,
                      const float* __restrict__ bf, float* __restrict__ outp) {
    __shared__ float sm[16];
    int t = threadIdx.x;
    float v = fcp[t];
    float mu = block_reduce_sum1(v, sm) * (1.f / 1024.f);
    float dv = v - mu;
    float var = block_reduce_sum1(dv * dv, sm) * (1.f / 1024.f);
    float rstd = rsqrtf(var + 1e-5f);
    outp[t] = gf[t] * dv * rstd + bf[t];
}

// ---------------- launch ----------------
extern "C" void kernel_launch(void* const* d_in, const int* in_sizes, int n_in,
                              void* d_out, int out_size, void* d_ws, size_t ws_size,
                              hipStream_t stream) {
    const float* x      = (const float*)d_in[0];
    const float* ea     = (const float*)d_in[1];
    const float* W1     = (const float*)d_in[2];
    const float* a_src1 = (const float*)d_in[3];
    const float* a_dst1 = (const float*)d_in[4];
    const float* We1    = (const float*)d_in[5];
    const float* a_e1   = (const float*)d_in[6];
    const float* b1     = (const float*)d_in[7];
    const float* g1     = (const float*)d_in[8];
    const float* be1    = (const float*)d_in[9];
    const float* W2     = (const float*)d_in[10];
    const float* a_src2 = (const float*)d_in[11];
    const float* a_dst2 = (const float*)d_in[12];
    const float* We2    = (const float*)d_in[13];
    const float* a_e2   = (const float*)d_in[14];
    const float* b2     = (const float*)d_in[15];
    const float* g2     = (const float*)d_in[16];
    const float* be2    = (const float*)d_in[17];
    const float* Wfc    = (const float*)d_in[18];
    const float* bfc    = (const float*)d_in[19];
    const float* gf     = (const float*)d_in[20];
    const float* bf     = (const float*)d_in[21];
    const int*   ei     = (const int*)d_in[22];
    float* outp = (float*)d_out;

    char* p = (char*)d_ws;
    auto alloc = [&](size_t bytes) -> char* {
        char* r = p;
        p += (bytes + 255) & ~(size_t)255;
        return r;
    };
    // zero zone (one memset): cnt, lea3, fill1, gsum, gmaxU
    float* cnt     = (float*)alloc((size_t)NN * 4);
    float* lea3    = (float*)alloc((size_t)NN * 3 * 4);
    int*   fill1   = (int*)  alloc((size_t)NN * 4);
    float* gsum    = (float*)alloc(256 * 4);
    unsigned* gmaxU= (unsigned*)alloc(256 * 4);
    size_t zbytes  = (size_t)((char*)gmaxU + 256*4 - (char*)cnt);
    float* prm     = (float*)alloc(256 * 4);
    float* al1     = (float*)alloc((size_t)NN * 8 * 4);
    float* al2     = (float*)alloc((size_t)NN * 2 * 4);
    int*   offs    = (int*)  alloc((size_t)(NN + 1) * 4);
    int*   eslot   = (int*)  alloc((size_t)NEP * 4);
    int*   csrs    = (int*)  alloc((size_t)NEP * 4);
    float* cex1t   = (float*)alloc((size_t)NEPA * 4 * 4);
    float* cex2    = (float*)alloc((size_t)NEP * 4);
    __hip_bfloat16* h1  = (__hip_bfloat16*)alloc((size_t)NN * HCD * 2);
    __hip_bfloat16* h1b = (__hip_bfloat16*)alloc((size_t)MPAD * HCD * 2);
    __hip_bfloat16* w2t = (__hip_bfloat16*)alloc((size_t)HIDD * HCD * 2);
    __hip_bfloat16* h2b = (__hip_bfloat16*)alloc((size_t)NN * HIDD * 2);
    float* gvec    = (float*)alloc(512 * 4);
    float* fcp     = (float*)alloc(1024 * 4);

    hipMemsetAsync(cnt, 0, zbytes, stream);

    k_prep<<<1, 256, 0, stream>>>(W1, a_src1, a_dst1, We1, a_e1, We2, a_e2, prm);
    k_w2t<<<dim3(16, 4), 256, 0, stream>>>(W2, w2t);
    k_deg<<<(NE + 255) / 256, 256, 0, stream>>>(ei, ea, cnt, lea3);
    k_scan<<<1, 1024, 0, stream>>>(cnt, offs);
    k_gemm1<<<dim3(NN / 8, 4), 256, 0, stream>>>(x, W1, h1);
    k_al1<<<(NN + 255) / 256, 256, 0, stream>>>(x, prm, al1);
    k_edge1<<<(NEP + 255) / 256, 256, 0, stream>>>(ei, ea, cnt, lea3, al1, prm, offs,
                                                   fill1, eslot, csrs, cex1t);
    k_agg1<<<NN / 4, 256, 0, stream>>>(offs, csrs, cex1t, h1, b1, g1, be1, h1b);
    k_gemm2m<<<313, 256, 0, stream>>>(h1b, w2t, h2b);
    k_al2<<<NN / 4, 256, 0, stream>>>(h2b, a_src2, a_dst2, al2);
    k_edge2<<<(NEP + 255) / 256, 256, 0, stream>>>(ei, ea, cnt, lea3, al2, prm, eslot, cex2);
    k_agg2<<<NN / 4, 256, 0, stream>>>(offs, csrs, cex2, h2b, b2, g2, be2, gsum, gmaxU);
    k_gvec<<<1, 256, 0, stream>>>(gsum, gmaxU, gvec);
    k_fc<<<8, 128, 0, stream>>>(gvec, Wfc, bfc, fcp);
    k_out<<<1, 1024, 0, stream>>>(fcp, gf, bf, outp);
}

// Round 5
// 337.498 us; speedup vs baseline: 1.1460x; 1.1460x over previous
//
#include <hip/hip_runtime.h>
#include <hip/hip_bf16.h>

// Problem constants
#define NN   10000      // nodes
#define NE   160000     // edges
#define NEP  170000     // edges + self loops
#define NEPA 170240     // padded plane stride for cex1t
#define IND  20         // input feature dim
#define HIDD 256        // hidden per head
#define NH   4          // heads layer 1
#define HCD  1024       // HEADS*HID
#define LATD 1024
#define MPAD 10112      // padded rows for h1b (>= 313*32 = 10016)
#define NREP 32         // pooling atomic replicas (contention spread)

typedef __attribute__((ext_vector_type(8))) short short8v;   // 8 bf16 (4 VGPRs)
typedef __attribute__((ext_vector_type(4))) float f32x4;     // MFMA accumulator

__device__ __forceinline__ unsigned pk2(float a, float b) {
    union { __hip_bfloat16 h; unsigned short s; } x, y;
    x.h = __float2bfloat16(a); y.h = __float2bfloat16(b);
    return (unsigned)x.s | ((unsigned)y.s << 16);
}

// ---------------- block reduction helper (shuffle + tiny smem) ----------------
__device__ __forceinline__ float block_reduce_sum1(float v, float* sm) {
    #pragma unroll
    for (int o = 32; o > 0; o >>= 1) v += __shfl_xor(v, o, 64);
    int wid = threadIdx.x >> 6, lane = threadIdx.x & 63, nw = blockDim.x >> 6;
    if (lane == 0) sm[wid] = v;
    __syncthreads();
    float r = 0.f;
    for (int i = 0; i < nw; i++) r += sm[i];
    __syncthreads();
    return r;
}

// ---------------- tiny precompute: collapsed attention matrices ----------------
__global__ void k_prep(const float* __restrict__ W1, const float* __restrict__ as1,
                       const float* __restrict__ ad1, const float* __restrict__ We1,
                       const float* __restrict__ ae1, const float* __restrict__ We2,
                       const float* __restrict__ ae2, float* __restrict__ prm) {
    int t = threadIdx.x;
    if (t < 80) {
        int i = t >> 2, h = t & 3; float s = 0.f;
        for (int c = 0; c < HIDD; c++) s += W1[i*HCD + h*HIDD + c] * as1[h*HIDD + c];
        prm[t] = s;
    } else if (t < 160) {
        int u = t - 80; int i = u >> 2, h = u & 3; float s = 0.f;
        for (int c = 0; c < HIDD; c++) s += W1[i*HCD + h*HIDD + c] * ad1[h*HIDD + c];
        prm[t] = s;
    } else if (t < 172) {
        int u = t - 160; int j = u >> 2, h = u & 3; float s = 0.f;
        for (int c = 0; c < HIDD; c++) s += We1[j*HCD + h*HIDD + c] * ae1[h*HIDD + c];
        prm[t] = s;
    } else if (t < 175) {
        int j = t - 172; float s = 0.f;
        for (int c = 0; c < HIDD; c++) s += We2[j*HIDD + c] * ae2[c];
        prm[t] = s;
    }
}

// ---------------- degree + self-loop edge-attr sums ----------------
__global__ void k_deg(const int* __restrict__ ei, const float* __restrict__ ea,
                      float* __restrict__ cnt, float* __restrict__ lea3) {
    int e = blockIdx.x * 256 + threadIdx.x;
    if (e >= NE) return;
    int d = ei[NE + e];
    atomicAdd(&cnt[d], 1.0f);
    atomicAdd(&lea3[d*3+0], ea[e*3+0]);
    atomicAdd(&lea3[d*3+1], ea[e*3+1]);
    atomicAdd(&lea3[d*3+2], ea[e*3+2]);
}

// ---------------- exclusive scan of (deg+1) -> CSR offsets ----------------
__global__ void k_scan(const float* __restrict__ cnt, int* __restrict__ offs) {
    __shared__ int sm[1024];
    int t = threadIdx.x;
    int base = t * 10;
    int loc[10]; int s = 0;
    if (t < 1000) {
        #pragma unroll
        for (int i = 0; i < 10; i++) { loc[i] = s; s += (int)cnt[base + i] + 1; }
    }
    sm[t] = (t < 1000) ? s : 0;
    __syncthreads();
    for (int o = 1; o < 1024; o <<= 1) {
        int x = (t >= o) ? sm[t - o] : 0;
        __syncthreads();
        sm[t] += x;
        __syncthreads();
    }
    int pre = (t > 0) ? sm[t - 1] : 0;
    if (t < 1000) {
        #pragma unroll
        for (int i = 0; i < 10; i++) offs[base + i] = pre + loc[i];
    }
    if (t == 1023) offs[NN] = sm[1023];
}

// ---------------- h1 = x @ W1  (store bf16) ----------------
__global__ void k_gemm1(const float* __restrict__ x, const float* __restrict__ W1,
                        __hip_bfloat16* __restrict__ h1) {
    __shared__ float xs[8][IND];
    int t = threadIdx.x;
    int n0 = blockIdx.x * 8;
    int c = blockIdx.y * 256 + t;
    if (t < 8 * IND) xs[t / IND][t % IND] = x[n0 * IND + t];
    __syncthreads();
    float acc[8] = {0.f,0.f,0.f,0.f,0.f,0.f,0.f,0.f};
    #pragma unroll
    for (int i = 0; i < IND; i++) {
        float w = W1[i * HCD + c];
        #pragma unroll
        for (int m = 0; m < 8; m++) acc[m] += xs[m][i] * w;
    }
    #pragma unroll
    for (int m = 0; m < 8; m++) h1[(size_t)(n0 + m) * HCD + c] = __float2bfloat16(acc[m]);
}

// ---------------- al_src1/al_dst1 = x @ A (collapsed) ----------------
__global__ void k_al1(const float* __restrict__ x, const float* __restrict__ prm,
                      float* __restrict__ al1) {
    int v = blockIdx.x * 256 + threadIdx.x;
    if (v >= NN) return;
    float xr[IND];
    #pragma unroll
    for (int i = 0; i < IND; i++) xr[i] = x[v * IND + i];
    #pragma unroll
    for (int h = 0; h < NH; h++) {
        float s = 0.f, d = 0.f;
        #pragma unroll
        for (int i = 0; i < IND; i++) { s += xr[i] * prm[i*4 + h]; d += xr[i] * prm[80 + i*4 + h]; }
        al1[v*8 + h] = s;
        al1[v*8 + 4 + h] = d;
    }
}

// ---------------- edge pass layer 1: logits -> exp (SoA planes), CSR fill ----------------
__global__ void k_edge1(const int* __restrict__ ei, const float* __restrict__ ea,
                        const float* __restrict__ cnt, const float* __restrict__ lea3,
                        const float* __restrict__ al1, const float* __restrict__ prm,
                        const int* __restrict__ offs, int* __restrict__ fill1,
                        int* __restrict__ eslot, int* __restrict__ csrs,
                        float* __restrict__ cex1t) {
    int e = blockIdx.x * 256 + threadIdx.x;
    if (e >= NEP) return;
    int s, d; float e0, e1, e2;
    if (e < NE) {
        s = ei[e]; d = ei[NE + e];
        e0 = ea[e*3]; e1 = ea[e*3+1]; e2 = ea[e*3+2];
    } else {
        int v = e - NE; s = v; d = v;
        float ic = 1.f / fmaxf(cnt[v], 1.0f);
        e0 = lea3[v*3] * ic; e1 = lea3[v*3+1] * ic; e2 = lea3[v*3+2] * ic;
    }
    int slot = offs[d] + atomicAdd(&fill1[d], 1);
    eslot[e] = slot;
    csrs[slot] = s;
    #pragma unroll
    for (int h = 0; h < NH; h++) {
        float le = e0 * prm[160 + h] + e1 * prm[164 + h] + e2 * prm[168 + h];
        float lg = al1[s*8 + h] + al1[d*8 + 4 + h] + le;
        lg = lg > 0.f ? lg : 0.2f * lg;
        cex1t[(size_t)h * NEPA + slot] = expf(lg);
    }
}

// ---------------- layer-1 aggregation + bias + ELU + LN, wave-per-node ----------------
#define UNPK(U, A0, A1, AW) { unsigned _u = (U); A0 += AW * __uint_as_float(_u << 16); A1 += AW * __uint_as_float(_u & 0xffff0000u); }
__global__ void __launch_bounds__(256)
k_agg1(const int* __restrict__ offs, const int* __restrict__ csrs,
       const float* __restrict__ cex1t, const __hip_bfloat16* __restrict__ h1,
       const float* __restrict__ b1, const float* __restrict__ g1,
       const float* __restrict__ be1, __hip_bfloat16* __restrict__ h1b) {
    int l = threadIdx.x & 63;
    int v = blockIdx.x * 4 + (threadIdx.x >> 6);
    int beg = offs[v], end = offs[v + 1];
    int c = l >> 4;
    const float* plane = cex1t + (size_t)c * NEPA;
    const uint4* hU = (const uint4*)h1;
    float c0=0,c1=0,c2=0,c3=0,c4=0,c5=0,c6=0,c7=0,c8=0,c9=0,c10=0,c11=0,c12=0,c13=0,c14=0,c15=0;
    float ps = 0.f;
    int j = beg;
    while (j < end) {
        int nb = end - j; if (nb > 64) nb = 64;
        int jl = j + l; if (jl > end - 1) jl = end - 1;
        int sidx = csrs[jl];
        int u = 0;
        for (; u + 2 <= nb; u += 2) {
            int s0 = __shfl(sidx, u, 64);
            int s1 = __shfl(sidx, u + 1, 64);
            float a0 = plane[j + u];
            float a1 = plane[j + u + 1];
            uint4 p0 = hU[(size_t)s0 * 128 + l * 2];
            uint4 p1 = hU[(size_t)s0 * 128 + l * 2 + 1];
            uint4 q0 = hU[(size_t)s1 * 128 + l * 2];
            uint4 q1 = hU[(size_t)s1 * 128 + l * 2 + 1];
            ps += a0 + a1;
            UNPK(p0.x, c0, c1, a0)  UNPK(p0.y, c2, c3, a0)  UNPK(p0.z, c4, c5, a0)  UNPK(p0.w, c6, c7, a0)
            UNPK(p1.x, c8, c9, a0)  UNPK(p1.y, c10,c11,a0)  UNPK(p1.z, c12,c13,a0)  UNPK(p1.w, c14,c15,a0)
            UNPK(q0.x, c0, c1, a1)  UNPK(q0.y, c2, c3, a1)  UNPK(q0.z, c4, c5, a1)  UNPK(q0.w, c6, c7, a1)
            UNPK(q1.x, c8, c9, a1)  UNPK(q1.y, c10,c11,a1)  UNPK(q1.z, c12,c13,a1)  UNPK(q1.w, c14,c15,a1)
        }
        if (u < nb) {
            int s0 = __shfl(sidx, u, 64);
            float a0 = plane[j + u];
            uint4 p0 = hU[(size_t)s0 * 128 + l * 2];
            uint4 p1 = hU[(size_t)s0 * 128 + l * 2 + 1];
            ps += a0;
            UNPK(p0.x, c0, c1, a0)  UNPK(p0.y, c2, c3, a0)  UNPK(p0.z, c4, c5, a0)  UNPK(p0.w, c6, c7, a0)
            UNPK(p1.x, c8, c9, a0)  UNPK(p1.y, c10,c11,a0)  UNPK(p1.z, c12,c13,a0)  UNPK(p1.w, c14,c15,a0)
        }
        j += nb;
    }
    float inv = 1.f / (ps + 1e-16f);
    float vv[16] = {c0,c1,c2,c3,c4,c5,c6,c7,c8,c9,c10,c11,c12,c13,c14,c15};
    const float4* b4 = (const float4*)(b1 + 16 * l);
    float lsum = 0.f;
    #pragma unroll
    for (int q = 0; q < 4; q++) {
        float4 bb = b4[q];
        float xv;
        xv = vv[4*q+0] * inv + bb.x; xv = xv > 0.f ? xv : expm1f(xv); vv[4*q+0] = xv; lsum += xv;
        xv = vv[4*q+1] * inv + bb.y; xv = xv > 0.f ? xv : expm1f(xv); vv[4*q+1] = xv; lsum += xv;
        xv = vv[4*q+2] * inv + bb.z; xv = xv > 0.f ? xv : expm1f(xv); vv[4*q+2] = xv; lsum += xv;
        xv = vv[4*q+3] * inv + bb.w; xv = xv > 0.f ? xv : expm1f(xv); vv[4*q+3] = xv; lsum += xv;
    }
    #pragma unroll
    for (int o = 1; o <= 32; o <<= 1) lsum += __shfl_xor(lsum, o, 64);
    float mu = lsum * (1.f / 1024.f);
    float q2 = 0.f;
    #pragma unroll
    for (int i = 0; i < 16; i++) { float dv = vv[i] - mu; q2 += dv * dv; }
    #pragma unroll
    for (int o = 1; o <= 32; o <<= 1) q2 += __shfl_xor(q2, o, 64);
    float rstd = rsqrtf(q2 * (1.f / 1024.f) + 1e-5f);
    const float4* g4 = (const float4*)(g1 + 16 * l);
    const float4* e4 = (const float4*)(be1 + 16 * l);
    unsigned ou[8];
    #pragma unroll
    for (int q = 0; q < 4; q++) {
        float4 gg = g4[q], ee = e4[q];
        float y0 = gg.x * (vv[4*q+0] - mu) * rstd + ee.x;
        float y1 = gg.y * (vv[4*q+1] - mu) * rstd + ee.y;
        float y2 = gg.z * (vv[4*q+2] - mu) * rstd + ee.z;
        float y3 = gg.w * (vv[4*q+3] - mu) * rstd + ee.w;
        ou[2*q]   = pk2(y0, y1);
        ou[2*q+1] = pk2(y2, y3);
    }
    uint4* dst = (uint4*)(h1b + (size_t)v * HCD + 16 * l);
    dst[0] = make_uint4(ou[0], ou[1], ou[2], ou[3]);
    dst[1] = make_uint4(ou[4], ou[5], ou[6], ou[7]);
}

// ---------------- W2 -> W2t[256][1024] bf16 (LDS-tiled transpose) ----------------
__global__ void k_w2t(const float* __restrict__ W2, __hip_bfloat16* __restrict__ Bt) {
    __shared__ float sm[64][65];
    int t = threadIdx.x;
    int k0 = blockIdx.x * 64, c0 = blockIdx.y * 64;
    #pragma unroll
    for (int i = 0; i < 16; i++) {
        int idx = i * 256 + t;
        int r = idx >> 6, c = idx & 63;
        sm[r][c] = W2[(size_t)(k0 + r) * 256 + c0 + c];
    }
    __syncthreads();
    int c = t >> 2, kq = t & 3;
    unsigned int out[8];
    #pragma unroll
    for (int j = 0; j < 8; j++)
        out[j] = pk2(sm[kq * 16 + 2*j][c], sm[kq * 16 + 2*j + 1][c]);
    unsigned int* dst = (unsigned int*)(Bt + (size_t)(c0 + c) * 1024 + k0 + kq * 16);
    *(uint4*)dst = make_uint4(out[0], out[1], out[2], out[3]);
    *(uint4*)(dst + 4) = make_uint4(out[4], out[5], out[6], out[7]);
}

// ---------------- h2b = h1b @ W2t^T via MFMA bf16; BM=32, BN=256 ----------------
__global__ void __launch_bounds__(256)
k_gemm2m(const __hip_bfloat16* __restrict__ A, const __hip_bfloat16* __restrict__ Bt,
         __hip_bfloat16* __restrict__ h2b) {
    __shared__ uint4 As4[256];   // 32 rows x 64 bf16 = 4 KB, XOR-swizzled
    char* As = (char*)As4;
    int t = threadIdx.x, l = t & 63, w = t >> 6;
    int m0 = blockIdx.x * 32;
    int srow = t >> 3, skc = t & 7;
    const __hip_bfloat16* gA = A + (size_t)(m0 + srow) * 1024 + skc * 8;
    int wbyte = (srow * 128 + skc * 16) ^ ((srow & 7) << 4);
    int r0 = l & 15, g = l >> 4;
    int ra[2][2];
    #pragma unroll
    for (int m = 0; m < 2; m++)
        #pragma unroll
        for (int kk = 0; kk < 2; kk++) {
            int r = r0 + m * 16;
            ra[m][kk] = (r * 128 + kk * 64 + g * 16) ^ ((r & 7) << 4);
        }
    const __hip_bfloat16* gB = Bt + (size_t)(w * 64 + r0) * 1024 + g * 8;
    f32x4 acc[2][4];
    #pragma unroll
    for (int m = 0; m < 2; m++)
        #pragma unroll
        for (int n = 0; n < 4; n++) acc[m][n] = (f32x4){0.f,0.f,0.f,0.f};
    uint4 sreg = *(const uint4*)gA;
    for (int it = 0; it < 16; ++it) {
        *(uint4*)(As + wbyte) = sreg;
        __syncthreads();
        if (it < 15) sreg = *(const uint4*)(gA + (it + 1) * 64);
        int k0 = it * 64;
        short8v bfr[4][2];
        #pragma unroll
        for (int n = 0; n < 4; n++)
            #pragma unroll
            for (int kk = 0; kk < 2; kk++)
                bfr[n][kk] = *(const short8v*)(gB + (size_t)n * 16 * 1024 + k0 + kk * 32);
        short8v afr[2][2];
        #pragma unroll
        for (int m = 0; m < 2; m++)
            #pragma unroll
            for (int kk = 0; kk < 2; kk++)
                afr[m][kk] = *(const short8v*)(As + ra[m][kk]);
        #pragma unroll
        for (int kk = 0; kk < 2; kk++)
            #pragma unroll
            for (int m = 0; m < 2; m++)
                #pragma unroll
                for (int n = 0; n < 4; n++)
                    acc[m][n] = __builtin_amdgcn_mfma_f32_16x16x32_bf16(afr[m][kk], bfr[n][kk], acc[m][n], 0, 0, 0);
        __syncthreads();
    }
    #pragma unroll
    for (int m = 0; m < 2; m++) {
        #pragma unroll
        for (int r = 0; r < 4; r++) {
            int row = m0 + m * 16 + g * 4 + r;
            if (row < NN) {
                #pragma unroll
                for (int n = 0; n < 4; n++) {
                    int col = w * 64 + n * 16 + r0;
                    h2b[(size_t)row * HIDD + col] = __float2bfloat16(acc[m][n][r]);
                }
            }
        }
    }
}

// ---------------- al2 = h2b . a_src2 / a_dst2, wave-per-node ----------------
__global__ void __launch_bounds__(256)
k_al2(const __hip_bfloat16* __restrict__ h2b, const float* __restrict__ as2,
      const float* __restrict__ ad2, float* __restrict__ al2) {
    int l = threadIdx.x & 63;
    int v = blockIdx.x * 4 + (threadIdx.x >> 6);
    uint2 p = ((const uint2*)h2b)[(size_t)v * 64 + l];
    float f0 = __uint_as_float(p.x << 16), f1 = __uint_as_float(p.x & 0xffff0000u);
    float f2 = __uint_as_float(p.y << 16), f3 = __uint_as_float(p.y & 0xffff0000u);
    float4 sa = ((const float4*)as2)[l];
    float4 da = ((const float4*)ad2)[l];
    float s = f0*sa.x + f1*sa.y + f2*sa.z + f3*sa.w;
    float d = f0*da.x + f1*da.y + f2*da.z + f3*da.w;
    #pragma unroll
    for (int o = 1; o <= 32; o <<= 1) { s += __shfl_xor(s, o, 64); d += __shfl_xor(d, o, 64); }
    if (l == 0) { al2[v*2] = s; al2[v*2+1] = d; }
}

// ---------------- edge pass layer 2 (reuses CSR slots, inline self-loop attr) ------
__global__ void k_edge2(const int* __restrict__ ei, const float* __restrict__ ea,
                        const float* __restrict__ cnt, const float* __restrict__ lea3,
                        const float* __restrict__ al2, const float* __restrict__ prm,
                        const int* __restrict__ eslot, float* __restrict__ cex2) {
    int e = blockIdx.x * 256 + threadIdx.x;
    if (e >= NEP) return;
    int s, d; float e0, e1, e2;
    if (e < NE) {
        s = ei[e]; d = ei[NE + e];
        e0 = ea[e*3]; e1 = ea[e*3+1]; e2 = ea[e*3+2];
    } else {
        int v = e - NE; s = v; d = v;
        float ic = 1.f / fmaxf(cnt[v], 1.0f);
        e0 = lea3[v*3] * ic; e1 = lea3[v*3+1] * ic; e2 = lea3[v*3+2] * ic;
    }
    float lg = al2[s*2] + al2[d*2+1] + e0*prm[172] + e1*prm[173] + e2*prm[174];
    lg = lg > 0.f ? lg : 0.2f * lg;
    cex2[eslot[e]] = expf(lg);
}

// ---------------- layer-2 aggregation + bias + ELU + LN + pooling (replica atomics) ----
__global__ void __launch_bounds__(256)
k_agg2(const int* __restrict__ offs, const int* __restrict__ csrs,
       const float* __restrict__ cex2, const __hip_bfloat16* __restrict__ h2b,
       const float* __restrict__ b2, const float* __restrict__ g2,
       const float* __restrict__ be2, float* __restrict__ gsum,
       unsigned* __restrict__ gmaxU) {
    __shared__ float smS[4][256];
    int l = threadIdx.x & 63, w = threadIdx.x >> 6;
    int v = blockIdx.x * 4 + w;
    int beg = offs[v], end = offs[v + 1];
    float a0 = 0.f, a1 = 0.f, a2 = 0.f, a3 = 0.f, ps = 0.f;
    const uint2* hU = (const uint2*)h2b;
    int j = beg;
    while (j < end) {
        int nb = end - j; if (nb > 64) nb = 64;
        int jl = j + l; if (jl > end - 1) jl = end - 1;
        int sidx = csrs[jl];
        float av = cex2[jl];
        int u = 0;
        for (; u + 2 <= nb; u += 2) {
            int s0 = __shfl(sidx, u, 64);
            int s1 = __shfl(sidx, u + 1, 64);
            float w0 = __shfl(av, u, 64);
            float w1 = __shfl(av, u + 1, 64);
            uint2 p = hU[(size_t)s0 * 64 + l];
            uint2 q = hU[(size_t)s1 * 64 + l];
            ps += w0 + w1;
            a0 += w0 * __uint_as_float(p.x << 16);
            a1 += w0 * __uint_as_float(p.x & 0xffff0000u);
            a2 += w0 * __uint_as_float(p.y << 16);
            a3 += w0 * __uint_as_float(p.y & 0xffff0000u);
            a0 += w1 * __uint_as_float(q.x << 16);
            a1 += w1 * __uint_as_float(q.x & 0xffff0000u);
            a2 += w1 * __uint_as_float(q.y << 16);
            a3 += w1 * __uint_as_float(q.y & 0xffff0000u);
        }
        if (u < nb) {
            int s0 = __shfl(sidx, u, 64);
            float w0 = __shfl(av, u, 64);
            uint2 p = hU[(size_t)s0 * 64 + l];
            ps += w0;
            a0 += w0 * __uint_as_float(p.x << 16);
            a1 += w0 * __uint_as_float(p.x & 0xffff0000u);
            a2 += w0 * __uint_as_float(p.y << 16);
            a3 += w0 * __uint_as_float(p.y & 0xffff0000u);
        }
        j += nb;
    }
    float inv = 1.f / (ps + 1e-16f);
    float4 bb = ((const float4*)b2)[l];
    float v0 = a0 * inv + bb.x, v1 = a1 * inv + bb.y, v2 = a2 * inv + bb.z, v3 = a3 * inv + bb.w;
    v0 = v0 > 0.f ? v0 : expm1f(v0);
    v1 = v1 > 0.f ? v1 : expm1f(v1);
    v2 = v2 > 0.f ? v2 : expm1f(v2);
    v3 = v3 > 0.f ? v3 : expm1f(v3);
    float lsum = v0 + v1 + v2 + v3;
    #pragma unroll
    for (int o = 1; o <= 32; o <<= 1) lsum += __shfl_xor(lsum, o, 64);
    float mu = lsum * (1.f / 256.f);
    float q2 = (v0-mu)*(v0-mu) + (v1-mu)*(v1-mu) + (v2-mu)*(v2-mu) + (v3-mu)*(v3-mu);
    #pragma unroll
    for (int o = 1; o <= 32; o <<= 1) q2 += __shfl_xor(q2, o, 64);
    float rstd = rsqrtf(q2 * (1.f / 256.f) + 1e-5f);
    float4 gg = ((const float4*)g2)[l];
    float4 ee = ((const float4*)be2)[l];
    float4 outv;
    outv.x = gg.x * (v0 - mu) * rstd + ee.x;
    outv.y = gg.y * (v1 - mu) * rstd + ee.y;
    outv.z = gg.z * (v2 - mu) * rstd + ee.z;
    outv.w = gg.w * (v3 - mu) * rstd + ee.w;
    *((float4*)&smS[w][4 * l]) = outv;
    __syncthreads();
    int t = threadIdx.x;   // 256 threads == 256 features
    int rep = blockIdx.x & (NREP - 1);
    float s = smS[0][t] + smS[1][t] + smS[2][t] + smS[3][t];
    float m = fmaxf(fmaxf(smS[0][t], smS[1][t]), fmaxf(smS[2][t], smS[3][t]));
    atomicAdd(&gsum[rep * 256 + t], s);
    unsigned b = __float_as_uint(m);
    unsigned k = (b & 0x80000000u) ? ~b : (b | 0x80000000u);
    atomicMax(&gmaxU[rep * 256 + t], k);
}

// ---------------- fold replicas, decode pooled vector ----------------
__global__ void k_gvec(const float* __restrict__ gsum, const unsigned* __restrict__ gmaxU,
                       float* __restrict__ gvec) {
    int t = threadIdx.x;
    float s = 0.f; unsigned km = 0u;
    #pragma unroll
    for (int r = 0; r < NREP; r++) {
        s += gsum[r * 256 + t];
        unsigned k = gmaxU[r * 256 + t];
        km = k > km ? k : km;
    }
    gvec[t] = s * (1.f / (float)NN);
    unsigned b = (km & 0x80000000u) ? (km & 0x7fffffffu) : ~km;
    gvec[256 + t] = __uint_as_float(b);
}

// ---------------- final FC (+relu) and LN ----------------
__global__ void k_fc(const float* __restrict__ gvec, const float* __restrict__ Wfc,
                     const float* __restrict__ bfc, float* __restrict__ fcp) {
    int c = blockIdx.x * 128 + threadIdx.x;
    float acc = bfc[c];
    for (int i = 0; i < 512; i++) acc += gvec[i] * Wfc[i * LATD + c];
    fcp[c] = fmaxf(acc, 0.f);
}

__global__ void k_out(const float* __restrict__ fcp, const float* __restrict__ gf,
                      const float* __restrict__ bf, float* __restrict__ outp) {
    __shared__ float sm[16];
    int t = threadIdx.x;
    float v = fcp[t];
    float mu = block_reduce_sum1(v, sm) * (1.f / 1024.f);
    float dv = v - mu;
    float var = block_reduce_sum1(dv * dv, sm) * (1.f / 1024.f);
    float rstd = rsqrtf(var + 1e-5f);
    outp[t] = gf[t] * dv * rstd + bf[t];
}

// ---------------- launch ----------------
extern "C" void kernel_launch(void* const* d_in, const int* in_sizes, int n_in,
                              void* d_out, int out_size, void* d_ws, size_t ws_size,
                              hipStream_t stream) {
    const float* x      = (const float*)d_in[0];
    const float* ea     = (const float*)d_in[1];
    const float* W1     = (const float*)d_in[2];
    const float* a_src1 = (const float*)d_in[3];
    const float* a_dst1 = (const float*)d_in[4];
    const float* We1    = (const float*)d_in[5];
    const float* a_e1   = (const float*)d_in[6];
    const float* b1     = (const float*)d_in[7];
    const float* g1     = (const float*)d_in[8];
    const float* be1    = (const float*)d_in[9];
    const float* W2     = (const float*)d_in[10];
    const float* a_src2 = (const float*)d_in[11];
    const float* a_dst2 = (const float*)d_in[12];
    const float* We2    = (const float*)d_in[13];
    const float* a_e2   = (const float*)d_in[14];
    const float* b2     = (const float*)d_in[15];
    const float* g2     = (const float*)d_in[16];
    const float* be2    = (const float*)d_in[17];
    const float* Wfc    = (const float*)d_in[18];
    const float* bfc    = (const float*)d_in[19];
    const float* gf     = (const float*)d_in[20];
    const float* bf     = (const float*)d_in[21];
    const int*   ei     = (const int*)d_in[22];
    float* outp = (float*)d_out;

    char* p = (char*)d_ws;
    auto alloc = [&](size_t bytes) -> char* {
        char* r = p;
        p += (bytes + 255) & ~(size_t)255;
        return r;
    };
    // zero zone (one memset): cnt, lea3, fill1, gsum, gmaxU
    float* cnt     = (float*)alloc((size_t)NN * 4);
    float* lea3    = (float*)alloc((size_t)NN * 3 * 4);
    int*   fill1   = (int*)  alloc((size_t)NN * 4);
    float* gsum    = (float*)alloc((size_t)NREP * 256 * 4);
    unsigned* gmaxU= (unsigned*)alloc((size_t)NREP * 256 * 4);
    size_t zbytes  = (size_t)((char*)gmaxU + (size_t)NREP*256*4 - (char*)cnt);
    float* prm     = (float*)alloc(256 * 4);
    float* al1     = (float*)alloc((size_t)NN * 8 * 4);
    float* al2     = (float*)alloc((size_t)NN * 2 * 4);
    int*   offs    = (int*)  alloc((size_t)(NN + 1) * 4);
    int*   eslot   = (int*)  alloc((size_t)NEP * 4);
    int*   csrs    = (int*)  alloc((size_t)NEP * 4);
    float* cex1t   = (float*)alloc((size_t)NEPA * 4 * 4);
    float* cex2    = (float*)alloc((size_t)NEP * 4);
    __hip_bfloat16* h1  = (__hip_bfloat16*)alloc((size_t)NN * HCD * 2);
    __hip_bfloat16* h1b = (__hip_bfloat16*)alloc((size_t)MPAD * HCD * 2);
    __hip_bfloat16* w2t = (__hip_bfloat16*)alloc((size_t)HIDD * HCD * 2);
    __hip_bfloat16* h2b = (__hip_bfloat16*)alloc((size_t)NN * HIDD * 2);
    float* gvec    = (float*)alloc(512 * 4);
    float* fcp     = (float*)alloc(1024 * 4);

    hipMemsetAsync(cnt, 0, zbytes, stream);

    k_prep<<<1, 256, 0, stream>>>(W1, a_src1, a_dst1, We1, a_e1, We2, a_e2, prm);
    k_w2t<<<dim3(16, 4), 256, 0, stream>>>(W2, w2t);
    k_deg<<<(NE + 255) / 256, 256, 0, stream>>>(ei, ea, cnt, lea3);
    k_scan<<<1, 1024, 0, stream>>>(cnt, offs);
    k_gemm1<<<dim3(NN / 8, 4), 256, 0, stream>>>(x, W1, h1);
    k_al1<<<(NN + 255) / 256, 256, 0, stream>>>(x, prm, al1);
    k_edge1<<<(NEP + 255) / 256, 256, 0, stream>>>(ei, ea, cnt, lea3, al1, prm, offs,
                                                   fill1, eslot, csrs, cex1t);
    k_agg1<<<NN / 4, 256, 0, stream>>>(offs, csrs, cex1t, h1, b1, g1, be1, h1b);
    k_gemm2m<<<313, 256, 0, stream>>>(h1b, w2t, h2b);
    k_al2<<<NN / 4, 256, 0, stream>>>(h2b, a_src2, a_dst2, al2);
    k_edge2<<<(NEP + 255) / 256, 256, 0, stream>>>(ei, ea, cnt, lea3, al2, prm, eslot, cex2);
    k_agg2<<<NN / 4, 256, 0, stream>>>(offs, csrs, cex2, h2b, b2, g2, be2, gsum, gmaxU);
    k_gvec<<<1, 256, 0, stream>>>(gsum, gmaxU, gvec);
    k_fc<<<8, 128, 0, stream>>>(gvec, Wfc, bfc, fcp);
    k_out<<<1, 1024, 0, stream>>>(fcp, gf, bf, outp);
}

// Round 6
// 318.175 us; speedup vs baseline: 1.2156x; 1.0607x over previous
//
#include <hip/hip_runtime.h>
#include <hip/hip_bf16.h>

// Problem constants
#define NN   10000      // nodes
#define NE   160000     // edges
#define NEP  170000     // edges + self loops
#define IND  20         // input feature dim
#define HIDD 256        // hidden per head
#define NH   4          // heads layer 1
#define HCD  1024       // HEADS*HID
#define LATD 1024
#define MPAD 10112      // padded rows for h1b (>= 313*32 = 10016)
#define NREP 32         // pooling atomic replicas (contention spread)

typedef __attribute__((ext_vector_type(8))) short short8v;   // 8 bf16 (4 VGPRs)
typedef __attribute__((ext_vector_type(4))) float f32x4;     // MFMA accumulator

__device__ __forceinline__ unsigned pk2(float a, float b) {
    union { __hip_bfloat16 h; unsigned short s; } x, y;
    x.h = __float2bfloat16(a); y.h = __float2bfloat16(b);
    return (unsigned)x.s | ((unsigned)y.s << 16);
}

// ---------------- block reduction helper (shuffle + tiny smem) ----------------
__device__ __forceinline__ float block_reduce_sum1(float v, float* sm) {
    #pragma unroll
    for (int o = 32; o > 0; o >>= 1) v += __shfl_xor(v, o, 64);
    int wid = threadIdx.x >> 6, lane = threadIdx.x & 63, nw = blockDim.x >> 6;
    if (lane == 0) sm[wid] = v;
    __syncthreads();
    float r = 0.f;
    for (int i = 0; i < nw; i++) r += sm[i];
    __syncthreads();
    return r;
}

// ---------------- merged precompute: collapsed attention mats + W2 transpose + W1 bf16 ----
// blocks 0..63: W2 -> W2t[256][1024] bf16 tiles; block 64: prm; blocks 65..72: W1 -> bf16
__global__ void k_prep(const float* __restrict__ W1, const float* __restrict__ as1,
                       const float* __restrict__ ad1, const float* __restrict__ We1,
                       const float* __restrict__ ae1, const float* __restrict__ We2,
                       const float* __restrict__ ae2, const float* __restrict__ W2,
                       float* __restrict__ prm, __hip_bfloat16* __restrict__ Bt,
                       __hip_bfloat16* __restrict__ w1b) {
    int bid = blockIdx.x, t = threadIdx.x;
    if (bid < 64) {
        __shared__ float sm[64][65];
        int k0 = (bid & 15) * 64, c0 = (bid >> 4) * 64;
        #pragma unroll
        for (int i = 0; i < 16; i++) {
            int idx = i * 256 + t;
            int r = idx >> 6, c = idx & 63;
            sm[r][c] = W2[(size_t)(k0 + r) * 256 + c0 + c];
        }
        __syncthreads();
        int c = t >> 2, kq = t & 3;
        unsigned int out[8];
        #pragma unroll
        for (int j = 0; j < 8; j++)
            out[j] = pk2(sm[kq * 16 + 2*j][c], sm[kq * 16 + 2*j + 1][c]);
        unsigned int* dst = (unsigned int*)(Bt + (size_t)(c0 + c) * 1024 + k0 + kq * 16);
        *(uint4*)dst = make_uint4(out[0], out[1], out[2], out[3]);
        *(uint4*)(dst + 4) = make_uint4(out[4], out[5], out[6], out[7]);
    } else if (bid == 64) {
        if (t < 80) {
            int i = t >> 2, h = t & 3; float s = 0.f;
            for (int c = 0; c < HIDD; c++) s += W1[i*HCD + h*HIDD + c] * as1[h*HIDD + c];
            prm[t] = s;
        } else if (t < 160) {
            int u = t - 80; int i = u >> 2, h = u & 3; float s = 0.f;
            for (int c = 0; c < HIDD; c++) s += W1[i*HCD + h*HIDD + c] * ad1[h*HIDD + c];
            prm[t] = s;
        } else if (t < 172) {
            int u = t - 160; int j = u >> 2, h = u & 3; float s = 0.f;
            for (int c = 0; c < HIDD; c++) s += We1[j*HCD + h*HIDD + c] * ae1[h*HIDD + c];
            prm[t] = s;
        } else if (t < 175) {
            int j = t - 172; float s = 0.f;
            for (int c = 0; c < HIDD; c++) s += We2[j*HIDD + c] * ae2[c];
            prm[t] = s;
        }
    } else {
        int base = (bid - 65) * 2560;
        #pragma unroll
        for (int r = 0; r < 10; r++) {
            int id = base + r * 256 + t;
            w1b[id] = __float2bfloat16(W1[id]);
        }
    }
}

// ---------------- degree + self-loop edge-attr sums + al1 (merged) ----------------
__global__ void k_pre1(const int* __restrict__ ei, const float* __restrict__ ea,
                       const float* __restrict__ x, const float* __restrict__ prm,
                       float* __restrict__ cnt, float* __restrict__ lea3,
                       float* __restrict__ al1) {
    int e = blockIdx.x * 256 + threadIdx.x;
    if (e < NE) {
        int d = ei[NE + e];
        atomicAdd(&cnt[d], 1.0f);
        atomicAdd(&lea3[d*3+0], ea[e*3+0]);
        atomicAdd(&lea3[d*3+1], ea[e*3+1]);
        atomicAdd(&lea3[d*3+2], ea[e*3+2]);
    }
    if (e < NN) {
        int v = e;
        float xr[IND];
        #pragma unroll
        for (int i = 0; i < IND; i++) xr[i] = x[v * IND + i];
        #pragma unroll
        for (int h = 0; h < NH; h++) {
            float s = 0.f, d2 = 0.f;
            #pragma unroll
            for (int i = 0; i < IND; i++) { s += xr[i] * prm[i*4 + h]; d2 += xr[i] * prm[80 + i*4 + h]; }
            al1[v*8 + h] = s;
            al1[v*8 + 4 + h] = d2;
        }
    }
}

// ---------------- exclusive scan of (deg+1) -> CSR offsets ----------------
__global__ void k_scan(const float* __restrict__ cnt, int* __restrict__ offs) {
    __shared__ int sm[1024];
    int t = threadIdx.x;
    int base = t * 10;
    int loc[10]; int s = 0;
    if (t < 1000) {
        #pragma unroll
        for (int i = 0; i < 10; i++) { loc[i] = s; s += (int)cnt[base + i] + 1; }
    }
    sm[t] = (t < 1000) ? s : 0;
    __syncthreads();
    for (int o = 1; o < 1024; o <<= 1) {
        int x = (t >= o) ? sm[t - o] : 0;
        __syncthreads();
        sm[t] += x;
        __syncthreads();
    }
    int pre = (t > 0) ? sm[t - 1] : 0;
    if (t < 1000) {
        #pragma unroll
        for (int i = 0; i < 10; i++) offs[base + i] = pre + loc[i];
    }
    if (t == 1023) offs[NN] = sm[1023];
}

// ---------------- edge pass layer 1: logits -> exp (AoS float4), CSR fill, elog2 ----
__global__ void k_edge1(const int* __restrict__ ei, const float* __restrict__ ea,
                        const float* __restrict__ cnt, const float* __restrict__ lea3,
                        const float* __restrict__ al1, const float* __restrict__ prm,
                        const int* __restrict__ offs, int* __restrict__ fill1,
                        int* __restrict__ csrs, float* __restrict__ cex1,
                        float* __restrict__ elog2) {
    int e = blockIdx.x * 256 + threadIdx.x;
    if (e >= NEP) return;
    int s, d; float e0, e1, e2;
    if (e < NE) {
        s = ei[e]; d = ei[NE + e];
        e0 = ea[e*3]; e1 = ea[e*3+1]; e2 = ea[e*3+2];
    } else {
        int v = e - NE; s = v; d = v;
        float ic = 1.f / fmaxf(cnt[v], 1.0f);
        e0 = lea3[v*3] * ic; e1 = lea3[v*3+1] * ic; e2 = lea3[v*3+2] * ic;
    }
    int slot = offs[d] + atomicAdd(&fill1[d], 1);
    csrs[slot] = s;
    elog2[slot] = e0*prm[172] + e1*prm[173] + e2*prm[174];
    float ex[4];
    #pragma unroll
    for (int h = 0; h < NH; h++) {
        float le = e0 * prm[160 + h] + e1 * prm[164 + h] + e2 * prm[168 + h];
        float lg = al1[s*8 + h] + al1[d*8 + 4 + h] + le;
        lg = lg > 0.f ? lg : 0.2f * lg;
        ex[h] = expf(lg);
    }
    *(float4*)(cex1 + (size_t)slot * 4) = make_float4(ex[0], ex[1], ex[2], ex[3]);
}

// ---------------- layer-1: aggregate x (80B/edge!), project W1, bias+ELU+LN ---------
// out1[v,h] = (sum_j alpha_hj * x[s_j]) @ W1[:, h*256:(h+1)*256]  (linearity)
// Wave per node. Halves process 2 edges/iter; lanes lx<20 accumulate 4 head sums.
__global__ void __launch_bounds__(256)
k_agg1x(const int* __restrict__ offs, const int* __restrict__ csrs,
        const float* __restrict__ cex1, const float* __restrict__ x,
        const __hip_bfloat16* __restrict__ w1b, const float* __restrict__ b1,
        const float* __restrict__ g1, const float* __restrict__ be1,
        __hip_bfloat16* __restrict__ h1b) {
    __shared__ float xs[4][4][20];
    int l = threadIdx.x & 63, wid = threadIdx.x >> 6;
    int v = blockIdx.x * 4 + wid;
    int beg = offs[v], end = offs[v + 1];
    int half = l >> 5, lx = l & 31;
    float4 ps = make_float4(0.f, 0.f, 0.f, 0.f);
    float ac0 = 0.f, ac1 = 0.f, ac2 = 0.f, ac3 = 0.f;
    for (int j = beg; j < end; j += 64) {
        int nb = end - j; if (nb > 64) nb = 64;
        int jl = j + l;
        bool valid = jl < end;
        int sidx = csrs[valid ? jl : (end - 1)];
        float4 av = valid ? *(const float4*)(cex1 + (size_t)jl * 4)
                          : make_float4(0.f, 0.f, 0.f, 0.f);
        ps.x += av.x; ps.y += av.y; ps.z += av.z; ps.w += av.w;
        for (int u = 0; u < nb; u += 2) {
            int e = u + half;                       // zero-padded alpha beyond nb
            int s  = __shfl(sidx, e, 64);
            float w0 = __shfl(av.x, e, 64);
            float w1v = __shfl(av.y, e, 64);
            float w2 = __shfl(av.z, e, 64);
            float w3 = __shfl(av.w, e, 64);
            float xv = (lx < IND) ? x[(size_t)s * IND + lx] : 0.f;
            ac0 += w0 * xv; ac1 += w1v * xv; ac2 += w2 * xv; ac3 += w3 * xv;
        }
    }
    // combine the two halves
    ac0 += __shfl_xor(ac0, 32, 64);
    ac1 += __shfl_xor(ac1, 32, 64);
    ac2 += __shfl_xor(ac2, 32, 64);
    ac3 += __shfl_xor(ac3, 32, 64);
    // softmax denominators per head (full-wave butterfly)
    #pragma unroll
    for (int o = 1; o <= 32; o <<= 1) {
        ps.x += __shfl_xor(ps.x, o, 64);
        ps.y += __shfl_xor(ps.y, o, 64);
        ps.z += __shfl_xor(ps.z, o, 64);
        ps.w += __shfl_xor(ps.w, o, 64);
    }
    if (l < IND) {
        xs[wid][0][l] = ac0; xs[wid][1][l] = ac1;
        xs[wid][2][l] = ac2; xs[wid][3][l] = ac3;
    }
    __syncthreads();
    int hh = l >> 4;
    float invh = 1.f / ((hh == 0 ? ps.x : hh == 1 ? ps.y : hh == 2 ? ps.z : ps.w) + 1e-16f);
    // project: vv[c] = sum_i xagg[hh][i] * W1[i][16l+c]
    float xreg[IND];
    #pragma unroll
    for (int i = 0; i < IND; i++) xreg[i] = xs[wid][hh][i];
    float vv[16];
    #pragma unroll
    for (int c = 0; c < 16; c++) vv[c] = 0.f;
    #pragma unroll
    for (int i = 0; i < IND; i++) {
        const uint4* wp = (const uint4*)(w1b + (size_t)i * HCD + 16 * l);
        uint4 wa = wp[0], wb = wp[1];
        float xi = xreg[i];
        unsigned wd[8] = {wa.x, wa.y, wa.z, wa.w, wb.x, wb.y, wb.z, wb.w};
        #pragma unroll
        for (int q = 0; q < 8; q++) {
            vv[2*q]   += xi * __uint_as_float(wd[q] << 16);
            vv[2*q+1] += xi * __uint_as_float(wd[q] & 0xffff0000u);
        }
    }
    // normalize + bias + ELU
    const float4* b4 = (const float4*)(b1 + 16 * l);
    float lsum = 0.f;
    #pragma unroll
    for (int q = 0; q < 4; q++) {
        float4 bb = b4[q];
        float xv;
        xv = vv[4*q+0] * invh + bb.x; xv = xv > 0.f ? xv : expm1f(xv); vv[4*q+0] = xv; lsum += xv;
        xv = vv[4*q+1] * invh + bb.y; xv = xv > 0.f ? xv : expm1f(xv); vv[4*q+1] = xv; lsum += xv;
        xv = vv[4*q+2] * invh + bb.z; xv = xv > 0.f ? xv : expm1f(xv); vv[4*q+2] = xv; lsum += xv;
        xv = vv[4*q+3] * invh + bb.w; xv = xv > 0.f ? xv : expm1f(xv); vv[4*q+3] = xv; lsum += xv;
    }
    // LayerNorm over 1024 via wave butterfly
    #pragma unroll
    for (int o = 1; o <= 32; o <<= 1) lsum += __shfl_xor(lsum, o, 64);
    float mu = lsum * (1.f / 1024.f);
    float q2 = 0.f;
    #pragma unroll
    for (int i = 0; i < 16; i++) { float dv = vv[i] - mu; q2 += dv * dv; }
    #pragma unroll
    for (int o = 1; o <= 32; o <<= 1) q2 += __shfl_xor(q2, o, 64);
    float rstd = rsqrtf(q2 * (1.f / 1024.f) + 1e-5f);
    const float4* g4 = (const float4*)(g1 + 16 * l);
    const float4* e4 = (const float4*)(be1 + 16 * l);
    unsigned ou[8];
    #pragma unroll
    for (int q = 0; q < 4; q++) {
        float4 gg = g4[q], ee = e4[q];
        float y0 = gg.x * (vv[4*q+0] - mu) * rstd + ee.x;
        float y1 = gg.y * (vv[4*q+1] - mu) * rstd + ee.y;
        float y2 = gg.z * (vv[4*q+2] - mu) * rstd + ee.z;
        float y3 = gg.w * (vv[4*q+3] - mu) * rstd + ee.w;
        ou[2*q]   = pk2(y0, y1);
        ou[2*q+1] = pk2(y2, y3);
    }
    uint4* dst = (uint4*)(h1b + (size_t)v * HCD + 16 * l);
    dst[0] = make_uint4(ou[0], ou[1], ou[2], ou[3]);
    dst[1] = make_uint4(ou[4], ou[5], ou[6], ou[7]);
}

// ---------------- h2b = h1b @ W2t^T via MFMA bf16; BM=32, BN=256 ----------------
__global__ void __launch_bounds__(256)
k_gemm2m(const __hip_bfloat16* __restrict__ A, const __hip_bfloat16* __restrict__ Bt,
         __hip_bfloat16* __restrict__ h2b) {
    __shared__ uint4 As4[256];   // 32 rows x 64 bf16 = 4 KB, XOR-swizzled
    char* As = (char*)As4;
    int t = threadIdx.x, l = t & 63, w = t >> 6;
    int m0 = blockIdx.x * 32;
    int srow = t >> 3, skc = t & 7;
    const __hip_bfloat16* gA = A + (size_t)(m0 + srow) * 1024 + skc * 8;
    int wbyte = (srow * 128 + skc * 16) ^ ((srow & 7) << 4);
    int r0 = l & 15, g = l >> 4;
    int ra[2][2];
    #pragma unroll
    for (int m = 0; m < 2; m++)
        #pragma unroll
        for (int kk = 0; kk < 2; kk++) {
            int r = r0 + m * 16;
            ra[m][kk] = (r * 128 + kk * 64 + g * 16) ^ ((r & 7) << 4);
        }
    const __hip_bfloat16* gB = Bt + (size_t)(w * 64 + r0) * 1024 + g * 8;
    f32x4 acc[2][4];
    #pragma unroll
    for (int m = 0; m < 2; m++)
        #pragma unroll
        for (int n = 0; n < 4; n++) acc[m][n] = (f32x4){0.f,0.f,0.f,0.f};
    uint4 sreg = *(const uint4*)gA;
    for (int it = 0; it < 16; ++it) {
        *(uint4*)(As + wbyte) = sreg;
        __syncthreads();
        if (it < 15) sreg = *(const uint4*)(gA + (it + 1) * 64);
        int k0 = it * 64;
        short8v bfr[4][2];
        #pragma unroll
        for (int n = 0; n < 4; n++)
            #pragma unroll
            for (int kk = 0; kk < 2; kk++)
                bfr[n][kk] = *(const short8v*)(gB + (size_t)n * 16 * 1024 + k0 + kk * 32);
        short8v afr[2][2];
        #pragma unroll
        for (int m = 0; m < 2; m++)
            #pragma unroll
            for (int kk = 0; kk < 2; kk++)
                afr[m][kk] = *(const short8v*)(As + ra[m][kk]);
        #pragma unroll
        for (int kk = 0; kk < 2; kk++)
            #pragma unroll
            for (int m = 0; m < 2; m++)
                #pragma unroll
                for (int n = 0; n < 4; n++)
                    acc[m][n] = __builtin_amdgcn_mfma_f32_16x16x32_bf16(afr[m][kk], bfr[n][kk], acc[m][n], 0, 0, 0);
        __syncthreads();
    }
    #pragma unroll
    for (int m = 0; m < 2; m++) {
        #pragma unroll
        for (int r = 0; r < 4; r++) {
            int row = m0 + m * 16 + g * 4 + r;
            if (row < NN) {
                #pragma unroll
                for (int n = 0; n < 4; n++) {
                    int col = w * 64 + n * 16 + r0;
                    h2b[(size_t)row * HIDD + col] = __float2bfloat16(acc[m][n][r]);
                }
            }
        }
    }
}

// ---------------- al2 = h2b . a_src2 / a_dst2, wave-per-node ----------------
__global__ void __launch_bounds__(256)
k_al2(const __hip_bfloat16* __restrict__ h2b, const float* __restrict__ as2,
      const float* __restrict__ ad2, float* __restrict__ al2) {
    int l = threadIdx.x & 63;
    int v = blockIdx.x * 4 + (threadIdx.x >> 6);
    uint2 p = ((const uint2*)h2b)[(size_t)v * 64 + l];
    float f0 = __uint_as_float(p.x << 16), f1 = __uint_as_float(p.x & 0xffff0000u);
    float f2 = __uint_as_float(p.y << 16), f3 = __uint_as_float(p.y & 0xffff0000u);
    float4 sa = ((const float4*)as2)[l];
    float4 da = ((const float4*)ad2)[l];
    float s = f0*sa.x + f1*sa.y + f2*sa.z + f3*sa.w;
    float d = f0*da.x + f1*da.y + f2*da.z + f3*da.w;
    #pragma unroll
    for (int o = 1; o <= 32; o <<= 1) { s += __shfl_xor(s, o, 64); d += __shfl_xor(d, o, 64); }
    if (l == 0) { al2[v*2] = s; al2[v*2+1] = d; }
}

// ---------------- layer-2: inline logits + aggregate + bias+ELU+LN + pooling --------
__global__ void __launch_bounds__(256)
k_agg2(const int* __restrict__ offs, const int* __restrict__ csrs,
       const float* __restrict__ elog2, const float* __restrict__ al2,
       const __hip_bfloat16* __restrict__ h2b, const float* __restrict__ b2,
       const float* __restrict__ g2, const float* __restrict__ be2,
       float* __restrict__ gsum, unsigned* __restrict__ gmaxU) {
    __shared__ float smS[4][256];
    int l = threadIdx.x & 63, w = threadIdx.x >> 6;
    int v = blockIdx.x * 4 + w;
    int beg = offs[v], end = offs[v + 1];
    float ald = al2[2*v + 1];
    float a0 = 0.f, a1 = 0.f, a2 = 0.f, a3 = 0.f, ps = 0.f;
    const uint2* hU = (const uint2*)h2b;
    for (int j = beg; j < end; j += 64) {
        int nb = end - j; if (nb > 64) nb = 64;
        int jl = j + l;
        bool valid = jl < end;
        int sidx = csrs[valid ? jl : (end - 1)];
        float wv = 0.f;
        if (valid) {
            float lg = al2[2*sidx] + ald + elog2[jl];
            lg = lg > 0.f ? lg : 0.2f * lg;
            wv = expf(lg);
        }
        ps += wv;
        for (int u = 0; u < nb; u += 2) {
            int s0 = __shfl(sidx, u, 64);
            int s1 = __shfl(sidx, u + 1, 64);       // zero-padded weight if u+1==nb
            float w0 = __shfl(wv, u, 64);
            float w1 = __shfl(wv, u + 1, 64);
            uint2 p = hU[(size_t)s0 * 64 + l];
            uint2 q = hU[(size_t)s1 * 64 + l];
            a0 += w0 * __uint_as_float(p.x << 16);
            a1 += w0 * __uint_as_float(p.x & 0xffff0000u);
            a2 += w0 * __uint_as_float(p.y << 16);
            a3 += w0 * __uint_as_float(p.y & 0xffff0000u);
            a0 += w1 * __uint_as_float(q.x << 16);
            a1 += w1 * __uint_as_float(q.x & 0xffff0000u);
            a2 += w1 * __uint_as_float(q.y << 16);
            a3 += w1 * __uint_as_float(q.y & 0xffff0000u);
        }
    }
    #pragma unroll
    for (int o = 1; o <= 32; o <<= 1) ps += __shfl_xor(ps, o, 64);
    float inv = 1.f / (ps + 1e-16f);
    float4 bb = ((const float4*)b2)[l];
    float v0 = a0 * inv + bb.x, v1 = a1 * inv + bb.y, v2 = a2 * inv + bb.z, v3 = a3 * inv + bb.w;
    v0 = v0 > 0.f ? v0 : expm1f(v0);
    v1 = v1 > 0.f ? v1 : expm1f(v1);
    v2 = v2 > 0.f ? v2 : expm1f(v2);
    v3 = v3 > 0.f ? v3 : expm1f(v3);
    float lsum = v0 + v1 + v2 + v3;
    #pragma unroll
    for (int o = 1; o <= 32; o <<= 1) lsum += __shfl_xor(lsum, o, 64);
    float mu = lsum * (1.f / 256.f);
    float q2 = (v0-mu)*(v0-mu) + (v1-mu)*(v1-mu) + (v2-mu)*(v2-mu) + (v3-mu)*(v3-mu);
    #pragma unroll
    for (int o = 1; o <= 32; o <<= 1) q2 += __shfl_xor(q2, o, 64);
    float rstd = rsqrtf(q2 * (1.f / 256.f) + 1e-5f);
    float4 gg = ((const float4*)g2)[l];
    float4 ee = ((const float4*)be2)[l];
    float4 outv;
    outv.x = gg.x * (v0 - mu) * rstd + ee.x;
    outv.y = gg.y * (v1 - mu) * rstd + ee.y;
    outv.z = gg.z * (v2 - mu) * rstd + ee.z;
    outv.w = gg.w * (v3 - mu) * rstd + ee.w;
    *((float4*)&smS[w][4 * l]) = outv;
    __syncthreads();
    int t = threadIdx.x;   // 256 threads == 256 features
    int rep = blockIdx.x & (NREP - 1);
    float s = smS[0][t] + smS[1][t] + smS[2][t] + smS[3][t];
    float m = fmaxf(fmaxf(smS[0][t], smS[1][t]), fmaxf(smS[2][t], smS[3][t]));
    atomicAdd(&gsum[rep * 256 + t], s);
    unsigned b = __float_as_uint(m);
    unsigned k = (b & 0x80000000u) ? ~b : (b | 0x80000000u);
    atomicMax(&gmaxU[rep * 256 + t], k);
}

// ---------------- fold replicas, decode pooled vector ----------------
__global__ void k_gvec(const float* __restrict__ gsum, const unsigned* __restrict__ gmaxU,
                       float* __restrict__ gvec) {
    int t = threadIdx.x;
    float s = 0.f; unsigned km = 0u;
    #pragma unroll
    for (int r = 0; r < NREP; r++) {
        s += gsum[r * 256 + t];
        unsigned k = gmaxU[r * 256 + t];
        km = k > km ? k : km;
    }
    gvec[t] = s * (1.f / (float)NN);
    unsigned b = (km & 0x80000000u) ? (km & 0x7fffffffu) : ~km;
    gvec[256 + t] = __uint_as_float(b);
}

// ---------------- final FC (+relu) and LN ----------------
__global__ void k_fc(const float* __restrict__ gvec, const float* __restrict__ Wfc,
                     const float* __restrict__ bfc, float* __restrict__ fcp) {
    int c = blockIdx.x * 128 + threadIdx.x;
    float acc = bfc[c];
    for (int i = 0; i < 512; i++) acc += gvec[i] * Wfc[i * LATD + c];
    fcp[c] = fmaxf(acc, 0.f);
}

__global__ void k_out(const float* __restrict__ fcp, const float* __restrict__ gf,
                      const float* __restrict__ bf, float* __restrict__ outp) {
    __shared__ float sm[16];
    int t = threadIdx.x;
    float v = fcp[t];
    float mu = block_reduce_sum1(v, sm) * (1.f / 1024.f);
    float dv = v - mu;
    float var = block_reduce_sum1(dv * dv, sm) * (1.f / 1024.f);
    float rstd = rsqrtf(var + 1e-5f);
    outp[t] = gf[t] * dv * rstd + bf[t];
}

// ---------------- launch ----------------
extern "C" void kernel_launch(void* const* d_in, const int* in_sizes, int n_in,
                              void* d_out, int out_size, void* d_ws, size_t ws_size,
                              hipStream_t stream) {
    const float* x      = (const float*)d_in[0];
    const float* ea     = (const float*)d_in[1];
    const float* W1     = (const float*)d_in[2];
    const float* a_src1 = (const float*)d_in[3];
    const float* a_dst1 = (const float*)d_in[4];
    const float* We1    = (const float*)d_in[5];
    const float* a_e1   = (const float*)d_in[6];
    const float* b1     = (const float*)d_in[7];
    const float* g1     = (const float*)d_in[8];
    const float* be1    = (const float*)d_in[9];
    const float* W2     = (const float*)d_in[10];
    const float* a_src2 = (const float*)d_in[11];
    const float* a_dst2 = (const float*)d_in[12];
    const float* We2    = (const float*)d_in[13];
    const float* a_e2   = (const float*)d_in[14];
    const float* b2     = (const float*)d_in[15];
    const float* g2     = (const float*)d_in[16];
    const float* be2    = (const float*)d_in[17];
    const float* Wfc    = (const float*)d_in[18];
    const float* bfc    = (const float*)d_in[19];
    const float* gf     = (const float*)d_in[20];
    const float* bf     = (const float*)d_in[21];
    const int*   ei     = (const int*)d_in[22];
    float* outp = (float*)d_out;

    char* p = (char*)d_ws;
    auto alloc = [&](size_t bytes) -> char* {
        char* r = p;
        p += (bytes + 255) & ~(size_t)255;
        return r;
    };
    // zero zone (one memset): cnt, lea3, fill1, gsum, gmaxU
    float* cnt     = (float*)alloc((size_t)NN * 4);
    float* lea3    = (float*)alloc((size_t)NN * 3 * 4);
    int*   fill1   = (int*)  alloc((size_t)NN * 4);
    float* gsum    = (float*)alloc((size_t)NREP * 256 * 4);
    unsigned* gmaxU= (unsigned*)alloc((size_t)NREP * 256 * 4);
    size_t zbytes  = (size_t)((char*)gmaxU + (size_t)NREP*256*4 - (char*)cnt);
    float* prm     = (float*)alloc(256 * 4);
    float* al1     = (float*)alloc((size_t)NN * 8 * 4);
    float* al2     = (float*)alloc((size_t)NN * 2 * 4);
    int*   offs    = (int*)  alloc((size_t)(NN + 1) * 4);
    int*   csrs    = (int*)  alloc((size_t)NEP * 4);
    float* cex1    = (float*)alloc((size_t)NEP * 4 * 4);
    float* elog2   = (float*)alloc((size_t)NEP * 4);
    __hip_bfloat16* w1b = (__hip_bfloat16*)alloc((size_t)IND * HCD * 2);
    __hip_bfloat16* h1b = (__hip_bfloat16*)alloc((size_t)MPAD * HCD * 2);
    __hip_bfloat16* w2t = (__hip_bfloat16*)alloc((size_t)HIDD * HCD * 2);
    __hip_bfloat16* h2b = (__hip_bfloat16*)alloc((size_t)NN * HIDD * 2);
    float* gvec    = (float*)alloc(512 * 4);
    float* fcp     = (float*)alloc(1024 * 4);

    hipMemsetAsync(cnt, 0, zbytes, stream);

    k_prep<<<73, 256, 0, stream>>>(W1, a_src1, a_dst1, We1, a_e1, We2, a_e2, W2,
                                   prm, w2t, w1b);
    k_pre1<<<(NE + 255) / 256, 256, 0, stream>>>(ei, ea, x, prm, cnt, lea3, al1);
    k_scan<<<1, 1024, 0, stream>>>(cnt, offs);
    k_edge1<<<(NEP + 255) / 256, 256, 0, stream>>>(ei, ea, cnt, lea3, al1, prm, offs,
                                                   fill1, csrs, cex1, elog2);
    k_agg1x<<<NN / 4, 256, 0, stream>>>(offs, csrs, cex1, x, w1b, b1, g1, be1, h1b);
    k_gemm2m<<<313, 256, 0, stream>>>(h1b, w2t, h2b);
    k_al2<<<NN / 4, 256, 0, stream>>>(h2b, a_src2, a_dst2, al2);
    k_agg2<<<NN / 4, 256, 0, stream>>>(offs, csrs, elog2, al2, h2b, b2, g2, be2,
                                       gsum, gmaxU);
    k_gvec<<<1, 256, 0, stream>>>(gsum, gmaxU, gvec);
    k_fc<<<8, 128, 0, stream>>>(gvec, Wfc, bfc, fcp);
    k_out<<<1, 1024, 0, stream>>>(fcp, gf, bf, outp);
}

// Round 7
// 305.548 us; speedup vs baseline: 1.2659x; 1.0413x over previous
//
#include <hip/hip_runtime.h>
#include <hip/hip_bf16.h>

// Problem constants
#define NN   10000      // nodes
#define NE   160000     // edges
#define NEP  170000     // edges + self loops
#define IND  20         // input feature dim
#define HIDD 256        // hidden per head
#define NH   4          // heads layer 1
#define HCD  1024       // HEADS*HID
#define LATD 1024
#define MPAD 10112      // padded rows for h1b (>= 313*32 = 10016)
#define NREP 128        // pooling atomic replicas (contention spread)

typedef __attribute__((ext_vector_type(8))) short short8v;   // 8 bf16 (4 VGPRs)
typedef __attribute__((ext_vector_type(4))) float f32x4;     // MFMA accumulator

__device__ __forceinline__ unsigned pk2(float a, float b) {
    union { __hip_bfloat16 h; unsigned short s; } x, y;
    x.h = __float2bfloat16(a); y.h = __float2bfloat16(b);
    return (unsigned)x.s | ((unsigned)y.s << 16);
}

// ---------------- block reduction helpers (shuffle + tiny smem) ----------------
__device__ __forceinline__ float block_reduce_sum1(float v, float* sm) {
    #pragma unroll
    for (int o = 32; o > 0; o >>= 1) v += __shfl_xor(v, o, 64);
    int wid = threadIdx.x >> 6, lane = threadIdx.x & 63, nw = blockDim.x >> 6;
    if (lane == 0) sm[wid] = v;
    __syncthreads();
    float r = 0.f;
    for (int i = 0; i < nw; i++) r += sm[i];
    __syncthreads();
    return r;
}

__device__ __forceinline__ void block_reduce_sum4(float* v, float* sm) {
    #pragma unroll
    for (int h = 0; h < 4; h++) {
        #pragma unroll
        for (int o = 32; o > 0; o >>= 1) v[h] += __shfl_xor(v[h], o, 64);
    }
    int wid = threadIdx.x >> 6, lane = threadIdx.x & 63, nw = blockDim.x >> 6;
    if (lane == 0) {
        sm[wid*4+0] = v[0]; sm[wid*4+1] = v[1]; sm[wid*4+2] = v[2]; sm[wid*4+3] = v[3];
    }
    __syncthreads();
    float r[4] = {0.f, 0.f, 0.f, 0.f};
    for (int i = 0; i < nw; i++) {
        r[0] += sm[i*4+0]; r[1] += sm[i*4+1]; r[2] += sm[i*4+2]; r[3] += sm[i*4+3];
    }
    __syncthreads();
    v[0] = r[0]; v[1] = r[1]; v[2] = r[2]; v[3] = r[3];
}

// ---------------- merged precompute: collapsed attention mats + W2 transpose + W1 bf16 ----
__global__ void k_prep(const float* __restrict__ W1, const float* __restrict__ as1,
                       const float* __restrict__ ad1, const float* __restrict__ We1,
                       const float* __restrict__ ae1, const float* __restrict__ We2,
                       const float* __restrict__ ae2, const float* __restrict__ W2,
                       float* __restrict__ prm, __hip_bfloat16* __restrict__ Bt,
                       __hip_bfloat16* __restrict__ w1b) {
    int bid = blockIdx.x, t = threadIdx.x;
    if (bid < 64) {
        __shared__ float sm[64][65];
        int k0 = (bid & 15) * 64, c0 = (bid >> 4) * 64;
        #pragma unroll
        for (int i = 0; i < 16; i++) {
            int idx = i * 256 + t;
            int r = idx >> 6, c = idx & 63;
            sm[r][c] = W2[(size_t)(k0 + r) * 256 + c0 + c];
        }
        __syncthreads();
        int c = t >> 2, kq = t & 3;
        unsigned int out[8];
        #pragma unroll
        for (int j = 0; j < 8; j++)
            out[j] = pk2(sm[kq * 16 + 2*j][c], sm[kq * 16 + 2*j + 1][c]);
        unsigned int* dst = (unsigned int*)(Bt + (size_t)(c0 + c) * 1024 + k0 + kq * 16);
        *(uint4*)dst = make_uint4(out[0], out[1], out[2], out[3]);
        *(uint4*)(dst + 4) = make_uint4(out[4], out[5], out[6], out[7]);
    } else if (bid == 64) {
        if (t < 80) {
            int i = t >> 2, h = t & 3; float s = 0.f;
            for (int c = 0; c < HIDD; c++) s += W1[i*HCD + h*HIDD + c] * as1[h*HIDD + c];
            prm[t] = s;
        } else if (t < 160) {
            int u = t - 80; int i = u >> 2, h = u & 3; float s = 0.f;
            for (int c = 0; c < HIDD; c++) s += W1[i*HCD + h*HIDD + c] * ad1[h*HIDD + c];
            prm[t] = s;
        } else if (t < 172) {
            int u = t - 160; int j = u >> 2, h = u & 3; float s = 0.f;
            for (int c = 0; c < HIDD; c++) s += We1[j*HCD + h*HIDD + c] * ae1[h*HIDD + c];
            prm[t] = s;
        } else if (t < 175) {
            int j = t - 172; float s = 0.f;
            for (int c = 0; c < HIDD; c++) s += We2[j*HIDD + c] * ae2[c];
            prm[t] = s;
        }
    } else {
        int base = (bid - 65) * 2560;
        #pragma unroll
        for (int r = 0; r < 10; r++) {
            int id = base + r * 256 + t;
            w1b[id] = __float2bfloat16(W1[id]);
        }
    }
}

// ---------------- degree + self-loop edge-attr sums + al1 (merged) ----------------
__global__ void k_pre1(const int* __restrict__ ei, const float* __restrict__ ea,
                       const float* __restrict__ x, const float* __restrict__ prm,
                       float* __restrict__ cnt, float* __restrict__ lea3,
                       float* __restrict__ al1) {
    int e = blockIdx.x * 256 + threadIdx.x;
    if (e < NE) {
        int d = ei[NE + e];
        atomicAdd(&cnt[d], 1.0f);
        atomicAdd(&lea3[d*3+0], ea[e*3+0]);
        atomicAdd(&lea3[d*3+1], ea[e*3+1]);
        atomicAdd(&lea3[d*3+2], ea[e*3+2]);
    }
    if (e < NN) {
        int v = e;
        float xr[IND];
        #pragma unroll
        for (int i = 0; i < IND; i++) xr[i] = x[v * IND + i];
        #pragma unroll
        for (int h = 0; h < NH; h++) {
            float s = 0.f, d2 = 0.f;
            #pragma unroll
            for (int i = 0; i < IND; i++) { s += xr[i] * prm[i*4 + h]; d2 += xr[i] * prm[80 + i*4 + h]; }
            al1[v*8 + h] = s;
            al1[v*8 + 4 + h] = d2;
        }
    }
}

// ---------------- exclusive scan of (deg+1) -> CSR offsets ----------------
__global__ void k_scan(const float* __restrict__ cnt, int* __restrict__ offs) {
    __shared__ int sm[1024];
    int t = threadIdx.x;
    int base = t * 10;
    int loc[10]; int s = 0;
    if (t < 1000) {
        #pragma unroll
        for (int i = 0; i < 10; i++) { loc[i] = s; s += (int)cnt[base + i] + 1; }
    }
    sm[t] = (t < 1000) ? s : 0;
    __syncthreads();
    for (int o = 1; o < 1024; o <<= 1) {
        int x = (t >= o) ? sm[t - o] : 0;
        __syncthreads();
        sm[t] += x;
        __syncthreads();
    }
    int pre = (t > 0) ? sm[t - 1] : 0;
    if (t < 1000) {
        #pragma unroll
        for (int i = 0; i < 10; i++) offs[base + i] = pre + loc[i];
    }
    if (t == 1023) offs[NN] = sm[1023];
}

// ---------------- edge pass layer 1: logits -> exp (AoS float4), CSR fill, elog2 ----
__global__ void k_edge1(const int* __restrict__ ei, const float* __restrict__ ea,
                        const float* __restrict__ cnt, const float* __restrict__ lea3,
                        const float* __restrict__ al1, const float* __restrict__ prm,
                        const int* __restrict__ offs, int* __restrict__ fill1,
                        int* __restrict__ csrs, float* __restrict__ cex1,
                        float* __restrict__ elog2) {
    int e = blockIdx.x * 256 + threadIdx.x;
    if (e >= NEP) return;
    int s, d; float e0, e1, e2;
    if (e < NE) {
        s = ei[e]; d = ei[NE + e];
        e0 = ea[e*3]; e1 = ea[e*3+1]; e2 = ea[e*3+2];
    } else {
        int v = e - NE; s = v; d = v;
        float ic = 1.f / fmaxf(cnt[v], 1.0f);
        e0 = lea3[v*3] * ic; e1 = lea3[v*3+1] * ic; e2 = lea3[v*3+2] * ic;
    }
    int slot = offs[d] + atomicAdd(&fill1[d], 1);
    csrs[slot] = s;
    elog2[slot] = e0*prm[172] + e1*prm[173] + e2*prm[174];
    float ex[4];
    #pragma unroll
    for (int h = 0; h < NH; h++) {
        float le = e0 * prm[160 + h] + e1 * prm[164 + h] + e2 * prm[168 + h];
        float lg = al1[s*8 + h] + al1[d*8 + 4 + h] + le;
        lg = lg > 0.f ? lg : 0.2f * lg;
        ex[h] = expf(lg);
    }
    *(float4*)(cex1 + (size_t)slot * 4) = make_float4(ex[0], ex[1], ex[2], ex[3]);
}

// ---------------- layer-1: lane-parallel x-aggregate + W1 project + bias+ELU+LN -----
// Block = 4 nodes. Edge phase: wave n = node; lane = (e=l>>3, fs=l&7): 8 edges/step,
// all loads lane-independent (no dynamic shuffles). Reduce over e via 3 xor-steps.
// Projection: thread t -> features 4t..4t+3 (head hh=t>>6) for all 4 nodes (shared wd).
__global__ void __launch_bounds__(256)
k_agg1y(const int* __restrict__ offs, const int* __restrict__ csrs,
        const float* __restrict__ cex1, const float* __restrict__ x,
        const __hip_bfloat16* __restrict__ w1b, const float* __restrict__ b1,
        const float* __restrict__ g1, const float* __restrict__ be1,
        __hip_bfloat16* __restrict__ h1b) {
    __shared__ float xsn[4][NH][20];   // normalized aggregated x per node, head
    __shared__ float smr[16];
    int t = threadIdx.x, l = t & 63, n0 = t >> 6;
    int v4 = blockIdx.x * 4;
    {
        int v = v4 + n0;
        int beg = offs[v], end = offs[v + 1];
        int e = l >> 3, fs = l & 7;
        float acc[4][3] = {{0.f,0.f,0.f},{0.f,0.f,0.f},{0.f,0.f,0.f},{0.f,0.f,0.f}};
        float psa[4] = {0.f, 0.f, 0.f, 0.f};
        for (int j0 = beg; j0 < end; j0 += 8) {
            int jl = j0 + e;
            bool valid = jl < end;
            int s = csrs[valid ? jl : beg];
            float4 a4 = valid ? *(const float4*)(cex1 + (size_t)jl * 4)
                              : make_float4(0.f, 0.f, 0.f, 0.f);
            psa[0] += a4.x; psa[1] += a4.y; psa[2] += a4.z; psa[3] += a4.w;
            #pragma unroll
            for (int k = 0; k < 3; k++) {
                int fi = fs * 3 + k;
                float xv = (fi < IND) ? x[(size_t)s * IND + fi] : 0.f;
                acc[0][k] += a4.x * xv; acc[1][k] += a4.y * xv;
                acc[2][k] += a4.z * xv; acc[3][k] += a4.w * xv;
            }
        }
        // reduce over e (lane bits 3..5)
        #pragma unroll
        for (int o = 8; o <= 32; o <<= 1) {
            #pragma unroll
            for (int h = 0; h < 4; h++) {
                psa[h] += __shfl_xor(psa[h], o, 64);
                #pragma unroll
                for (int k = 0; k < 3; k++) acc[h][k] += __shfl_xor(acc[h][k], o, 64);
            }
        }
        if (e == 0) {   // lanes 0..7 hold totals; write normalized
            #pragma unroll
            for (int h = 0; h < 4; h++) {
                float inv = 1.f / (psa[h] + 1e-16f);
                #pragma unroll
                for (int k = 0; k < 3; k++) {
                    int fi = fs * 3 + k;
                    if (fi < IND) xsn[n0][h][fi] = acc[h][k] * inv;
                }
            }
        }
    }
    __syncthreads();
    // projection for all 4 nodes
    int hh = t >> 6;
    float vv[4][4] = {{0.f,0.f,0.f,0.f},{0.f,0.f,0.f,0.f},{0.f,0.f,0.f,0.f},{0.f,0.f,0.f,0.f}};
    #pragma unroll
    for (int i = 0; i < IND; i++) {
        uint2 wd = *(const uint2*)(w1b + (size_t)i * HCD + 4 * t);
        float w0 = __uint_as_float(wd.x << 16);
        float w1 = __uint_as_float(wd.x & 0xffff0000u);
        float w2 = __uint_as_float(wd.y << 16);
        float w3 = __uint_as_float(wd.y & 0xffff0000u);
        #pragma unroll
        for (int n = 0; n < 4; n++) {
            float xi = xsn[n][hh][i];
            vv[n][0] += xi * w0; vv[n][1] += xi * w1;
            vv[n][2] += xi * w2; vv[n][3] += xi * w3;
        }
    }
    float4 bb = ((const float4*)b1)[t];
    float ls[4];
    #pragma unroll
    for (int n = 0; n < 4; n++) {
        float s0, s1, s2, s3;
        s0 = vv[n][0] + bb.x; s0 = s0 > 0.f ? s0 : expm1f(s0);
        s1 = vv[n][1] + bb.y; s1 = s1 > 0.f ? s1 : expm1f(s1);
        s2 = vv[n][2] + bb.z; s2 = s2 > 0.f ? s2 : expm1f(s2);
        s3 = vv[n][3] + bb.w; s3 = s3 > 0.f ? s3 : expm1f(s3);
        vv[n][0] = s0; vv[n][1] = s1; vv[n][2] = s2; vv[n][3] = s3;
        ls[n] = s0 + s1 + s2 + s3;
    }
    block_reduce_sum4(ls, smr);
    float mu[4], q2[4];
    #pragma unroll
    for (int n = 0; n < 4; n++) {
        mu[n] = ls[n] * (1.f / 1024.f);
        float d0 = vv[n][0]-mu[n], d1 = vv[n][1]-mu[n], d2 = vv[n][2]-mu[n], d3 = vv[n][3]-mu[n];
        q2[n] = d0*d0 + d1*d1 + d2*d2 + d3*d3;
    }
    block_reduce_sum4(q2, smr);
    float4 gg = ((const float4*)g1)[t];
    float4 ee = ((const float4*)be1)[t];
    #pragma unroll
    for (int n = 0; n < 4; n++) {
        float rstd = rsqrtf(q2[n] * (1.f / 1024.f) + 1e-5f);
        float y0 = gg.x * (vv[n][0] - mu[n]) * rstd + ee.x;
        float y1 = gg.y * (vv[n][1] - mu[n]) * rstd + ee.y;
        float y2 = gg.z * (vv[n][2] - mu[n]) * rstd + ee.z;
        float y3 = gg.w * (vv[n][3] - mu[n]) * rstd + ee.w;
        *(uint2*)(h1b + (size_t)(v4 + n) * HCD + 4 * t) = make_uint2(pk2(y0, y1), pk2(y2, y3));
    }
}

// ---------------- h2b = h1b @ W2t^T via MFMA bf16; BM=32, BN=256 ----------------
__global__ void __launch_bounds__(256)
k_gemm2m(const __hip_bfloat16* __restrict__ A, const __hip_bfloat16* __restrict__ Bt,
         __hip_bfloat16* __restrict__ h2b) {
    __shared__ uint4 As4[256];   // 32 rows x 64 bf16 = 4 KB, XOR-swizzled
    char* As = (char*)As4;
    int t = threadIdx.x, l = t & 63, w = t >> 6;
    int m0 = blockIdx.x * 32;
    int srow = t >> 3, skc = t & 7;
    const __hip_bfloat16* gA = A + (size_t)(m0 + srow) * 1024 + skc * 8;
    int wbyte = (srow * 128 + skc * 16) ^ ((srow & 7) << 4);
    int r0 = l & 15, g = l >> 4;
    int ra[2][2];
    #pragma unroll
    for (int m = 0; m < 2; m++)
        #pragma unroll
        for (int kk = 0; kk < 2; kk++) {
            int r = r0 + m * 16;
            ra[m][kk] = (r * 128 + kk * 64 + g * 16) ^ ((r & 7) << 4);
        }
    const __hip_bfloat16* gB = Bt + (size_t)(w * 64 + r0) * 1024 + g * 8;
    f32x4 acc[2][4];
    #pragma unroll
    for (int m = 0; m < 2; m++)
        #pragma unroll
        for (int n = 0; n < 4; n++) acc[m][n] = (f32x4){0.f,0.f,0.f,0.f};
    uint4 sreg = *(const uint4*)gA;
    for (int it = 0; it < 16; ++it) {
        *(uint4*)(As + wbyte) = sreg;
        __syncthreads();
        if (it < 15) sreg = *(const uint4*)(gA + (it + 1) * 64);
        int k0 = it * 64;
        short8v bfr[4][2];
        #pragma unroll
        for (int n = 0; n < 4; n++)
            #pragma unroll
            for (int kk = 0; kk < 2; kk++)
                bfr[n][kk] = *(const short8v*)(gB + (size_t)n * 16 * 1024 + k0 + kk * 32);
        short8v afr[2][2];
        #pragma unroll
        for (int m = 0; m < 2; m++)
            #pragma unroll
            for (int kk = 0; kk < 2; kk++)
                afr[m][kk] = *(const short8v*)(As + ra[m][kk]);
        #pragma unroll
        for (int kk = 0; kk < 2; kk++)
            #pragma unroll
            for (int m = 0; m < 2; m++)
                #pragma unroll
                for (int n = 0; n < 4; n++)
                    acc[m][n] = __builtin_amdgcn_mfma_f32_16x16x32_bf16(afr[m][kk], bfr[n][kk], acc[m][n], 0, 0, 0);
        __syncthreads();
    }
    #pragma unroll
    for (int m = 0; m < 2; m++) {
        #pragma unroll
        for (int r = 0; r < 4; r++) {
            int row = m0 + m * 16 + g * 4 + r;
            if (row < NN) {
                #pragma unroll
                for (int n = 0; n < 4; n++) {
                    int col = w * 64 + n * 16 + r0;
                    h2b[(size_t)row * HIDD + col] = __float2bfloat16(acc[m][n][r]);
                }
            }
        }
    }
}

// ---------------- al2 = h2b . a_src2 / a_dst2, wave-per-node ----------------
__global__ void __launch_bounds__(256)
k_al2(const __hip_bfloat16* __restrict__ h2b, const float* __restrict__ as2,
      const float* __restrict__ ad2, float* __restrict__ al2) {
    int l = threadIdx.x & 63;
    int v = blockIdx.x * 4 + (threadIdx.x >> 6);
    uint2 p = ((const uint2*)h2b)[(size_t)v * 64 + l];
    float f0 = __uint_as_float(p.x << 16), f1 = __uint_as_float(p.x & 0xffff0000u);
    float f2 = __uint_as_float(p.y << 16), f3 = __uint_as_float(p.y & 0xffff0000u);
    float4 sa = ((const float4*)as2)[l];
    float4 da = ((const float4*)ad2)[l];
    float s = f0*sa.x + f1*sa.y + f2*sa.z + f3*sa.w;
    float d = f0*da.x + f1*da.y + f2*da.z + f3*da.w;
    #pragma unroll
    for (int o = 1; o <= 32; o <<= 1) { s += __shfl_xor(s, o, 64); d += __shfl_xor(d, o, 64); }
    if (l == 0) { al2[v*2] = s; al2[v*2+1] = d; }
}

// ---------------- layer-2: block-per-node; LDS alphas, coalesced gather, LN+pool ----
__global__ void __launch_bounds__(256)
k_agg2y(const int* __restrict__ offs, const int* __restrict__ csrs,
        const float* __restrict__ elog2, const float* __restrict__ al2,
        const __hip_bfloat16* __restrict__ h2b, const float* __restrict__ b2,
        const float* __restrict__ g2, const float* __restrict__ be2,
        float* __restrict__ gsum, unsigned* __restrict__ gmaxU) {
    __shared__ float sal[128];
    __shared__ int   ssr[128];
    __shared__ float sred[16];
    int t = threadIdx.x;
    int v = blockIdx.x;
    int beg = offs[v], end = offs[v + 1];
    float ald = al2[2 * v + 1];
    float acc = 0.f, ps = 0.f;
    for (int j0 = beg; j0 < end; j0 += 128) {
        int nb = end - j0; if (nb > 128) nb = 128;
        __syncthreads();
        if (t < 128) {
            int jl = j0 + t;
            float wv = 0.f; int s = 0;
            if (jl < end) {
                s = csrs[jl];
                float lg = al2[2 * s] + ald + elog2[jl];
                lg = lg > 0.f ? lg : 0.2f * lg;
                wv = expf(lg);
            }
            sal[t] = wv; ssr[t] = s;
            ps += wv;
        }
        __syncthreads();
        int nbr = (nb + 3) & ~3;
        for (int u = 0; u < nbr; u += 4) {
            float a0 = sal[u], a1 = sal[u+1], a2 = sal[u+2], a3 = sal[u+3];
            int s0 = ssr[u], s1 = ssr[u+1], s2 = ssr[u+2], s3 = ssr[u+3];
            float h0 = __bfloat162float(h2b[(size_t)s0 * HIDD + t]);
            float h1 = __bfloat162float(h2b[(size_t)s1 * HIDD + t]);
            float h2 = __bfloat162float(h2b[(size_t)s2 * HIDD + t]);
            float h3 = __bfloat162float(h2b[(size_t)s3 * HIDD + t]);
            acc += a0*h0 + a1*h1 + a2*h2 + a3*h3;
        }
    }
    float pst = block_reduce_sum1(ps, sred);
    float inv = 1.f / (pst + 1e-16f);
    float vf = acc * inv + b2[t];
    vf = vf > 0.f ? vf : expm1f(vf);
    float mu = block_reduce_sum1(vf, sred) * (1.f / 256.f);
    float dv = vf - mu;
    float var = block_reduce_sum1(dv * dv, sred) * (1.f / 256.f);
    float rstd = rsqrtf(var + 1e-5f);
    float outv = g2[t] * dv * rstd + be2[t];
    int rep = blockIdx.x & (NREP - 1);
    atomicAdd(&gsum[rep * 256 + t], outv);
    unsigned b = __float_as_uint(outv);
    unsigned k = (b & 0x80000000u) ? ~b : (b | 0x80000000u);
    atomicMax(&gmaxU[rep * 256 + t], k);
}

// ---------------- fold replicas, decode pooled vector ----------------
__global__ void k_gvec(const float* __restrict__ gsum, const unsigned* __restrict__ gmaxU,
                       float* __restrict__ gvec) {
    int t = threadIdx.x;
    float s = 0.f; unsigned km = 0u;
    for (int r = 0; r < NREP; r++) {
        s += gsum[r * 256 + t];
        unsigned k = gmaxU[r * 256 + t];
        km = k > km ? k : km;
    }
    gvec[t] = s * (1.f / (float)NN);
    unsigned b = (km & 0x80000000u) ? (km & 0x7fffffffu) : ~km;
    gvec[256 + t] = __uint_as_float(b);
}

// ---------------- final FC: split-K partial sums into fcacc ----------------
__global__ void k_fc(const float* __restrict__ gvec, const float* __restrict__ Wfc,
                     float* __restrict__ fcacc) {
    int t = threadIdx.x;
    int kc = blockIdx.x >> 2;                 // 0..7 -> 64 K-rows each
    int c = (blockIdx.x & 3) * 256 + t;
    int r0 = kc * 64;
    float acc = 0.f;
    #pragma unroll 8
    for (int i = 0; i < 64; i++) acc += gvec[r0 + i] * Wfc[(size_t)(r0 + i) * LATD + c];
    atomicAdd(&fcacc[c], acc);
}

__global__ void k_out(const float* __restrict__ fcacc, const float* __restrict__ bfc,
                      const float* __restrict__ gf, const float* __restrict__ bf,
                      float* __restrict__ outp) {
    __shared__ float sm[16];
    int t = threadIdx.x;
    float v = fmaxf(fcacc[t] + bfc[t], 0.f);
    float mu = block_reduce_sum1(v, sm) * (1.f / 1024.f);
    float dv = v - mu;
    float var = block_reduce_sum1(dv * dv, sm) * (1.f / 1024.f);
    float rstd = rsqrtf(var + 1e-5f);
    outp[t] = gf[t] * dv * rstd + bf[t];
}

// ---------------- launch ----------------
extern "C" void kernel_launch(void* const* d_in, const int* in_sizes, int n_in,
                              void* d_out, int out_size, void* d_ws, size_t ws_size,
                              hipStream_t stream) {
    const float* x      = (const float*)d_in[0];
    const float* ea     = (const float*)d_in[1];
    const float* W1     = (const float*)d_in[2];
    const float* a_src1 = (const float*)d_in[3];
    const float* a_dst1 = (const float*)d_in[4];
    const float* We1    = (const float*)d_in[5];
    const float* a_e1   = (const float*)d_in[6];
    const float* b1     = (const float*)d_in[7];
    const float* g1     = (const float*)d_in[8];
    const float* be1    = (const float*)d_in[9];
    const float* W2     = (const float*)d_in[10];
    const float* a_src2 = (const float*)d_in[11];
    const float* a_dst2 = (const float*)d_in[12];
    const float* We2    = (const float*)d_in[13];
    const float* a_e2   = (const float*)d_in[14];
    const float* b2     = (const float*)d_in[15];
    const float* g2     = (const float*)d_in[16];
    const float* be2    = (const float*)d_in[17];
    const float* Wfc    = (const float*)d_in[18];
    const float* bfc    = (const float*)d_in[19];
    const float* gf     = (const float*)d_in[20];
    const float* bf     = (const float*)d_in[21];
    const int*   ei     = (const int*)d_in[22];
    float* outp = (float*)d_out;

    char* p = (char*)d_ws;
    auto alloc = [&](size_t bytes) -> char* {
        char* r = p;
        p += (bytes + 255) & ~(size_t)255;
        return r;
    };
    // zero zone (one memset): cnt, lea3, fill1, gsum, gmaxU, fcacc
    float* cnt     = (float*)alloc((size_t)NN * 4);
    float* lea3    = (float*)alloc((size_t)NN * 3 * 4);
    int*   fill1   = (int*)  alloc((size_t)NN * 4);
    float* gsum    = (float*)alloc((size_t)NREP * 256 * 4);
    unsigned* gmaxU= (unsigned*)alloc((size_t)NREP * 256 * 4);
    float* fcacc   = (float*)alloc(1024 * 4);
    size_t zbytes  = (size_t)((char*)fcacc + 1024*4 - (char*)cnt);
    float* prm     = (float*)alloc(256 * 4);
    float* al1     = (float*)alloc((size_t)NN * 8 * 4);
    float* al2     = (float*)alloc((size_t)NN * 2 * 4);
    int*   offs    = (int*)  alloc((size_t)(NN + 1) * 4);
    int*   csrs    = (int*)  alloc((size_t)NEP * 4);
    float* cex1    = (float*)alloc((size_t)NEP * 4 * 4);
    float* elog2   = (float*)alloc((size_t)NEP * 4);
    __hip_bfloat16* w1b = (__hip_bfloat16*)alloc((size_t)IND * HCD * 2);
    __hip_bfloat16* h1b = (__hip_bfloat16*)alloc((size_t)MPAD * HCD * 2);
    __hip_bfloat16* w2t = (__hip_bfloat16*)alloc((size_t)HIDD * HCD * 2);
    __hip_bfloat16* h2b = (__hip_bfloat16*)alloc((size_t)NN * HIDD * 2);
    float* gvec    = (float*)alloc(512 * 4);

    hipMemsetAsync(cnt, 0, zbytes, stream);

    k_prep<<<73, 256, 0, stream>>>(W1, a_src1, a_dst1, We1, a_e1, We2, a_e2, W2,
                                   prm, w2t, w1b);
    k_pre1<<<(NE + 255) / 256, 256, 0, stream>>>(ei, ea, x, prm, cnt, lea3, al1);
    k_scan<<<1, 1024, 0, stream>>>(cnt, offs);
    k_edge1<<<(NEP + 255) / 256, 256, 0, stream>>>(ei, ea, cnt, lea3, al1, prm, offs,
                                                   fill1, csrs, cex1, elog2);
    k_agg1y<<<NN / 4, 256, 0, stream>>>(offs, csrs, cex1, x, w1b, b1, g1, be1, h1b);
    k_gemm2m<<<313, 256, 0, stream>>>(h1b, w2t, h2b);
    k_al2<<<NN / 4, 256, 0, stream>>>(h2b, a_src2, a_dst2, al2);
    k_agg2y<<<NN, 256, 0, stream>>>(offs, csrs, elog2, al2, h2b, b2, g2, be2,
                                    gsum, gmaxU);
    k_gvec<<<1, 256, 0, stream>>>(gsum, gmaxU, gvec);
    k_fc<<<32, 256, 0, stream>>>(gvec, Wfc, fcacc);
    k_out<<<1, 1024, 0, stream>>>(fcacc, bfc, gf, bf, outp);
}

// Round 10
// 283.469 us; speedup vs baseline: 1.3645x; 1.0779x over previous
//
#include <hip/hip_runtime.h>
#include <hip/hip_bf16.h>

// Problem constants
#define NN   10000      // nodes
#define NE   160000     // edges
#define NEP  170000     // edges + self loops
#define IND  20         // input feature dim
#define HIDD 256        // hidden per head
#define NH   4          // heads layer 1
#define HCD  1024       // HEADS*HID
#define LATD 1024
#define MPAD 10112      // padded rows for h1b (>= 313*32 = 10016)
#define NREP 128        // pooling atomic replicas (contention spread)

typedef __attribute__((ext_vector_type(8))) short short8v;   // 8 bf16 (4 VGPRs)
typedef __attribute__((ext_vector_type(4))) float f32x4;     // MFMA accumulator

__device__ __forceinline__ unsigned pk2(float a, float b) {
    union { __hip_bfloat16 h; unsigned short s; } x, y;
    x.h = __float2bfloat16(a); y.h = __float2bfloat16(b);
    return (unsigned)x.s | ((unsigned)y.s << 16);
}

__device__ __forceinline__ unsigned short bf16bits(float a) {
    union { __hip_bfloat16 h; unsigned short s; } x;
    x.h = __float2bfloat16(a);
    return x.s;
}

// ---------------- block reduction helper ----------------
__device__ __forceinline__ float block_reduce_sum1(float v, float* sm) {
    #pragma unroll
    for (int o = 32; o > 0; o >>= 1) v += __shfl_xor(v, o, 64);
    int wid = threadIdx.x >> 6, lane = threadIdx.x & 63, nw = blockDim.x >> 6;
    if (lane == 0) sm[wid] = v;
    __syncthreads();
    float r = 0.f;
    for (int i = 0; i < nw; i++) r += sm[i];
    __syncthreads();
    return r;
}

// ---------------- merged front: W2 transpose + prm + W1t + deg/lea3 ----------------
// blocks 0..63: W2 -> W2t tiles; 64: prm; 65..72: W1 -> w1t[1024][32] bf16 (k-padded);
// blocks 73..697: degree/lea3 atomics.  NOTE: nothing in this kernel READS prm —
// al1 moved to the k_scan launch to avoid the intra-grid race (round-9 bug).
__global__ void k_front(const float* __restrict__ W1, const float* __restrict__ as1,
                        const float* __restrict__ ad1, const float* __restrict__ We1,
                        const float* __restrict__ ae1, const float* __restrict__ We2,
                        const float* __restrict__ ae2, const float* __restrict__ W2,
                        const int* __restrict__ ei, const float* __restrict__ ea,
                        float* __restrict__ prm, __hip_bfloat16* __restrict__ Bt,
                        __hip_bfloat16* __restrict__ w1t,
                        float* __restrict__ cnt, float* __restrict__ lea3) {
    int bid = blockIdx.x, t = threadIdx.x;
    if (bid < 64) {
        __shared__ float sm[64][65];
        int k0 = (bid & 15) * 64, c0 = (bid >> 4) * 64;
        #pragma unroll
        for (int i = 0; i < 16; i++) {
            int idx = i * 256 + t;
            int r = idx >> 6, c = idx & 63;
            sm[r][c] = W2[(size_t)(k0 + r) * 256 + c0 + c];
        }
        __syncthreads();
        int c = t >> 2, kq = t & 3;
        unsigned int out[8];
        #pragma unroll
        for (int j = 0; j < 8; j++)
            out[j] = pk2(sm[kq * 16 + 2*j][c], sm[kq * 16 + 2*j + 1][c]);
        unsigned int* dst = (unsigned int*)(Bt + (size_t)(c0 + c) * 1024 + k0 + kq * 16);
        *(uint4*)dst = make_uint4(out[0], out[1], out[2], out[3]);
        *(uint4*)(dst + 4) = make_uint4(out[4], out[5], out[6], out[7]);
    } else if (bid == 64) {
        if (t < 80) {
            int i = t >> 2, h = t & 3; float s = 0.f;
            for (int c = 0; c < HIDD; c++) s += W1[i*HCD + h*HIDD + c] * as1[h*HIDD + c];
            prm[t] = s;
        } else if (t < 160) {
            int u = t - 80; int i = u >> 2, h = u & 3; float s = 0.f;
            for (int c = 0; c < HIDD; c++) s += W1[i*HCD + h*HIDD + c] * ad1[h*HIDD + c];
            prm[t] = s;
        } else if (t < 172) {
            int u = t - 160; int j = u >> 2, h = u & 3; float s = 0.f;
            for (int c = 0; c < HIDD; c++) s += We1[j*HCD + h*HIDD + c] * ae1[h*HIDD + c];
            prm[t] = s;
        } else if (t < 175) {
            int j = t - 172; float s = 0.f;
            for (int c = 0; c < HIDD; c++) s += We2[j*HIDD + c] * ae2[c];
            prm[t] = s;
        }
    } else if (bid < 73) {
        // w1t[f][k] = W1[k][f] (bf16, k>=20 zero)
        int f = (bid - 65) * 128 + (t >> 1);
        int half = t & 1;
        #pragma unroll
        for (int kk = 0; kk < 16; kk++) {
            int k = half * 16 + kk;
            float v = (k < IND) ? W1[(size_t)k * HCD + f] : 0.f;
            w1t[(size_t)f * 32 + k] = __float2bfloat16(v);
        }
    } else {
        int e = (bid - 73) * 256 + t;
        if (e < NE) {
            int d = ei[NE + e];
            atomicAdd(&cnt[d], 1.0f);
            atomicAdd(&lea3[d*3+0], ea[e*3+0]);
            atomicAdd(&lea3[d*3+1], ea[e*3+1]);
            atomicAdd(&lea3[d*3+2], ea[e*3+2]);
        }
    }
}

// ---------------- scan (block 0) + al1 (blocks 1..10); prm from PRIOR launch -------
__global__ void k_scan(const float* __restrict__ cnt, const float* __restrict__ x,
                       const float* __restrict__ prm, int* __restrict__ offs,
                       float* __restrict__ al1) {
    if (blockIdx.x == 0) {
        __shared__ int sm[1024];
        int t = threadIdx.x;
        int base = t * 10;
        int loc[10]; int s = 0;
        if (t < 1000) {
            #pragma unroll
            for (int i = 0; i < 10; i++) { loc[i] = s; s += (int)cnt[base + i] + 1; }
        }
        sm[t] = (t < 1000) ? s : 0;
        __syncthreads();
        for (int o = 1; o < 1024; o <<= 1) {
            int xv = (t >= o) ? sm[t - o] : 0;
            __syncthreads();
            sm[t] += xv;
            __syncthreads();
        }
        int pre = (t > 0) ? sm[t - 1] : 0;
        if (t < 1000) {
            #pragma unroll
            for (int i = 0; i < 10; i++) offs[base + i] = pre + loc[i];
        }
        if (t == 1023) offs[NN] = sm[1023];
    } else {
        int v = (blockIdx.x - 1) * 1024 + threadIdx.x;
        if (v < NN) {
            float xr[IND];
            #pragma unroll
            for (int i = 0; i < IND; i++) xr[i] = x[v * IND + i];
            #pragma unroll
            for (int h = 0; h < NH; h++) {
                float s = 0.f, d2 = 0.f;
                #pragma unroll
                for (int i = 0; i < IND; i++) { s += xr[i] * prm[i*4 + h]; d2 += xr[i] * prm[80 + i*4 + h]; }
                al1[v*8 + h] = s;
                al1[v*8 + 4 + h] = d2;
            }
        }
    }
}

// ---------------- edge pass layer 1: logits -> exp, CSR fill, elog2 ----------------
__global__ void k_edge1(const int* __restrict__ ei, const float* __restrict__ ea,
                        const float* __restrict__ cnt, const float* __restrict__ lea3,
                        const float* __restrict__ al1, const float* __restrict__ prm,
                        const int* __restrict__ offs, int* __restrict__ fill1,
                        int* __restrict__ csrs, float* __restrict__ cex1,
                        float* __restrict__ elog2) {
    int e = blockIdx.x * 256 + threadIdx.x;
    if (e >= NEP) return;
    int s, d; float e0, e1, e2;
    if (e < NE) {
        s = ei[e]; d = ei[NE + e];
        e0 = ea[e*3]; e1 = ea[e*3+1]; e2 = ea[e*3+2];
    } else {
        int v = e - NE; s = v; d = v;
        float ic = 1.f / fmaxf(cnt[v], 1.0f);
        e0 = lea3[v*3] * ic; e1 = lea3[v*3+1] * ic; e2 = lea3[v*3+2] * ic;
    }
    int slot = offs[d] + atomicAdd(&fill1[d], 1);
    csrs[slot] = s;
    elog2[slot] = e0*prm[172] + e1*prm[173] + e2*prm[174];
    float ex[4];
    #pragma unroll
    for (int h = 0; h < NH; h++) {
        float le = e0 * prm[160 + h] + e1 * prm[164 + h] + e2 * prm[168 + h];
        float lg = al1[s*8 + h] + al1[d*8 + 4 + h] + le;
        lg = lg > 0.f ? lg : 0.2f * lg;
        ex[h] = __expf(lg);
    }
    *(float4*)(cex1 + (size_t)slot * 4) = make_float4(ex[0], ex[1], ex[2], ex[3]);
}

// ---------------- layer-1 fused: edge-agg x + MFMA projection + bias+ELU+LN ---------
// Block = 16 nodes, 4 waves. Phase 1: wave w aggregates nodes w*4..w*4+3:
//   lane=(e=l>>2: 16 edges, fs=l&3: 5 feats each); normalized bf16 -> LDS xb[16][4][32].
// Phase 2: wave w = head w. Swapped-operand MFMA: D[f][v] = sum_k W1t[f][k]*xb[v][k].
__global__ void __launch_bounds__(256)
k_l1(const int* __restrict__ offs, const int* __restrict__ csrs,
     const float* __restrict__ cex1, const float* __restrict__ x,
     const __hip_bfloat16* __restrict__ w1t, const float* __restrict__ b1,
     const float* __restrict__ g1, const float* __restrict__ be1,
     __hip_bfloat16* __restrict__ h1b) {
    __shared__ unsigned short xb[16][4][32];   // [node][head][k] bf16, 4 KB
    __shared__ float sred[4][16][2];           // [wave][node][{sum,sumsq}]
    int t = threadIdx.x, l = t & 63, w = t >> 6;
    int vbase = blockIdx.x * 16;
    ((uint4*)xb)[t] = make_uint4(0, 0, 0, 0);  // zero incl. k=20..31 pad
    __syncthreads();
    int e = l >> 2, fs = l & 3;
    for (int nl = 0; nl < 4; nl++) {
        int v = vbase + w * 4 + nl;
        int beg = offs[v], end = offs[v + 1];
        float acc[4][5] = {};
        float psa[4] = {0.f, 0.f, 0.f, 0.f};
        for (int j0 = beg; j0 < end; j0 += 16) {
            int jl = j0 + e;
            bool valid = jl < end;
            int s = csrs[valid ? jl : beg];
            float4 a4 = valid ? *(const float4*)(cex1 + (size_t)jl * 4)
                              : make_float4(0.f, 0.f, 0.f, 0.f);
            psa[0] += a4.x; psa[1] += a4.y; psa[2] += a4.z; psa[3] += a4.w;
            #pragma unroll
            for (int k = 0; k < 5; k++) {
                float xv = x[(size_t)s * IND + fs * 5 + k];
                acc[0][k] += a4.x * xv; acc[1][k] += a4.y * xv;
                acc[2][k] += a4.z * xv; acc[3][k] += a4.w * xv;
            }
        }
        #pragma unroll
        for (int o = 4; o <= 32; o <<= 1) {
            #pragma unroll
            for (int h = 0; h < 4; h++) {
                psa[h] += __shfl_xor(psa[h], o, 64);
                #pragma unroll
                for (int k = 0; k < 5; k++) acc[h][k] += __shfl_xor(acc[h][k], o, 64);
            }
        }
        if (e == 0) {
            int node = w * 4 + nl;
            #pragma unroll
            for (int h = 0; h < 4; h++) {
                float inv = 1.f / (psa[h] + 1e-16f);
                #pragma unroll
                for (int k = 0; k < 5; k++)
                    xb[node][h][fs * 5 + k] = bf16bits(acc[h][k] * inv);
            }
        }
    }
    __syncthreads();
    // Phase 2: MFMA projection, head = w
    int vn = l & 15, g = l >> 4;
    short8v bfrag = *(const short8v*)&xb[vn][w][g * 8];
    const __hip_bfloat16* wp = w1t + ((size_t)w * 256 + vn) * 32 + g * 8;
    f32x4 accp[16];
    #pragma unroll
    for (int ft = 0; ft < 16; ft++) {
        short8v afrag = *(const short8v*)(wp + (size_t)ft * 16 * 32);
        accp[ft] = __builtin_amdgcn_mfma_f32_16x16x32_bf16(afrag, bfrag,
                                                           (f32x4){0.f,0.f,0.f,0.f}, 0, 0, 0);
    }
    // bias + ELU + LN stats (lane owns node vn; holds 64 of its 1024 feats, head w)
    float s1 = 0.f, s2 = 0.f;
    #pragma unroll
    for (int ft = 0; ft < 16; ft++) {
        int fb = w * 256 + ft * 16 + g * 4;
        float4 bb = *(const float4*)(b1 + fb);
        #pragma unroll
        for (int r = 0; r < 4; r++) {
            float xv = accp[ft][r] + ((const float*)&bb)[r];
            xv = xv > 0.f ? xv : (__expf(xv) - 1.f);
            accp[ft][r] = xv;
            s1 += xv; s2 += xv * xv;
        }
    }
    s1 += __shfl_xor(s1, 16, 64); s1 += __shfl_xor(s1, 32, 64);
    s2 += __shfl_xor(s2, 16, 64); s2 += __shfl_xor(s2, 32, 64);
    if (g == 0) { sred[w][vn][0] = s1; sred[w][vn][1] = s2; }
    __syncthreads();
    float S1 = sred[0][vn][0] + sred[1][vn][0] + sred[2][vn][0] + sred[3][vn][0];
    float S2 = sred[0][vn][1] + sred[1][vn][1] + sred[2][vn][1] + sred[3][vn][1];
    float mu = S1 * (1.f / 1024.f);
    float var = S2 * (1.f / 1024.f) - mu * mu;
    float rstd = rsqrtf(var + 1e-5f);
    int v = vbase + vn;
    #pragma unroll
    for (int ft = 0; ft < 16; ft++) {
        int fb = w * 256 + ft * 16 + g * 4;
        float4 gg = *(const float4*)(g1 + fb);
        float4 ee = *(const float4*)(be1 + fb);
        unsigned p0 = pk2(gg.x * (accp[ft][0] - mu) * rstd + ee.x,
                          gg.y * (accp[ft][1] - mu) * rstd + ee.y);
        unsigned p1 = pk2(gg.z * (accp[ft][2] - mu) * rstd + ee.z,
                          gg.w * (accp[ft][3] - mu) * rstd + ee.w);
        *(uint2*)(h1b + (size_t)v * HCD + fb) = make_uint2(p0, p1);
    }
}

// ---------------- h2b = h1b @ W2t^T via MFMA; BM=32, BN=256; al2 epilogue ----------
__global__ void __launch_bounds__(256)
k_gemm2m(const __hip_bfloat16* __restrict__ A, const __hip_bfloat16* __restrict__ Bt,
         const float* __restrict__ as2, const float* __restrict__ ad2,
         __hip_bfloat16* __restrict__ h2b, float* __restrict__ al2) {
    __shared__ uint4 As4[256];           // 32 rows x 64 bf16, XOR-swizzled
    __shared__ float part[4][32][2];     // [wave][row][{s,d}]
    char* As = (char*)As4;
    int t = threadIdx.x, l = t & 63, w = t >> 6;
    int m0 = blockIdx.x * 32;
    int srow = t >> 3, skc = t & 7;
    const __hip_bfloat16* gA = A + (size_t)(m0 + srow) * 1024 + skc * 8;
    int wbyte = (srow * 128 + skc * 16) ^ ((srow & 7) << 4);
    int r0 = l & 15, g = l >> 4;
    int ra[2][2];
    #pragma unroll
    for (int m = 0; m < 2; m++)
        #pragma unroll
        for (int kk = 0; kk < 2; kk++) {
            int r = r0 + m * 16;
            ra[m][kk] = (r * 128 + kk * 64 + g * 16) ^ ((r & 7) << 4);
        }
    const __hip_bfloat16* gB = Bt + (size_t)(w * 64 + r0) * 1024 + g * 8;
    f32x4 acc[2][4];
    #pragma unroll
    for (int m = 0; m < 2; m++)
        #pragma unroll
        for (int n = 0; n < 4; n++) acc[m][n] = (f32x4){0.f,0.f,0.f,0.f};
    uint4 sreg = *(const uint4*)gA;
    for (int it = 0; it < 16; ++it) {
        *(uint4*)(As + wbyte) = sreg;
        __syncthreads();
        if (it < 15) sreg = *(const uint4*)(gA + (it + 1) * 64);
        int k0 = it * 64;
        short8v bfr[4][2];
        #pragma unroll
        for (int n = 0; n < 4; n++)
            #pragma unroll
            for (int kk = 0; kk < 2; kk++)
                bfr[n][kk] = *(const short8v*)(gB + (size_t)n * 16 * 1024 + k0 + kk * 32);
        short8v afr[2][2];
        #pragma unroll
        for (int m = 0; m < 2; m++)
            #pragma unroll
            for (int kk = 0; kk < 2; kk++)
                afr[m][kk] = *(const short8v*)(As + ra[m][kk]);
        #pragma unroll
        for (int kk = 0; kk < 2; kk++)
            #pragma unroll
            for (int m = 0; m < 2; m++)
                #pragma unroll
                for (int n = 0; n < 4; n++)
                    acc[m][n] = __builtin_amdgcn_mfma_f32_16x16x32_bf16(afr[m][kk], bfr[n][kk], acc[m][n], 0, 0, 0);
        __syncthreads();
    }
    // store h2b + al2 partials
    float as2v[4], ad2v[4];
    #pragma unroll
    for (int n = 0; n < 4; n++) {
        int col = w * 64 + n * 16 + r0;
        as2v[n] = as2[col]; ad2v[n] = ad2[col];
    }
    float sp[2][4], dp[2][4];
    #pragma unroll
    for (int m = 0; m < 2; m++)
        #pragma unroll
        for (int r = 0; r < 4; r++) { sp[m][r] = 0.f; dp[m][r] = 0.f; }
    #pragma unroll
    for (int m = 0; m < 2; m++) {
        #pragma unroll
        for (int r = 0; r < 4; r++) {
            int row = m0 + m * 16 + g * 4 + r;
            if (row < NN) {
                #pragma unroll
                for (int n = 0; n < 4; n++) {
                    int col = w * 64 + n * 16 + r0;
                    h2b[(size_t)row * HIDD + col] = __float2bfloat16(acc[m][n][r]);
                    sp[m][r] += acc[m][n][r] * as2v[n];
                    dp[m][r] += acc[m][n][r] * ad2v[n];
                }
            }
        }
    }
    #pragma unroll
    for (int o = 1; o <= 8; o <<= 1) {
        #pragma unroll
        for (int m = 0; m < 2; m++)
            #pragma unroll
            for (int r = 0; r < 4; r++) {
                sp[m][r] += __shfl_xor(sp[m][r], o, 64);
                dp[m][r] += __shfl_xor(dp[m][r], o, 64);
            }
    }
    if (r0 == 0) {
        #pragma unroll
        for (int m = 0; m < 2; m++)
            #pragma unroll
            for (int r = 0; r < 4; r++) {
                part[w][m * 16 + g * 4 + r][0] = sp[m][r];
                part[w][m * 16 + g * 4 + r][1] = dp[m][r];
            }
    }
    __syncthreads();
    if (t < 64) {
        int row = t >> 1, c = t & 1;
        if (m0 + row < NN) {
            float s = part[0][row][c] + part[1][row][c] + part[2][row][c] + part[3][row][c];
            al2[(m0 + row) * 2 + c] = s;
        }
    }
}

// ---------------- layer-2: inline logits + gather + bias+ELU+LN + pooling ----------
__global__ void __launch_bounds__(256)
k_agg2y(const int* __restrict__ offs, const int* __restrict__ csrs,
        const float* __restrict__ elog2, const float* __restrict__ al2,
        const __hip_bfloat16* __restrict__ h2b, const float* __restrict__ b2,
        const float* __restrict__ g2, const float* __restrict__ be2,
        float* __restrict__ gsum, unsigned* __restrict__ gmaxU) {
    __shared__ float sal[128];
    __shared__ int   ssr[128];
    __shared__ float sred[16];
    int t = threadIdx.x;
    int v = blockIdx.x;
    int beg = offs[v], end = offs[v + 1];
    float ald = al2[2 * v + 1];
    float acc = 0.f, ps = 0.f;
    for (int j0 = beg; j0 < end; j0 += 128) {
        int nb = end - j0; if (nb > 128) nb = 128;
        __syncthreads();
        if (t < 128) {
            int jl = j0 + t;
            float wv = 0.f; int s = 0;
            if (jl < end) {
                s = csrs[jl];
                float lg = al2[2 * s] + ald + elog2[jl];
                lg = lg > 0.f ? lg : 0.2f * lg;
                wv = __expf(lg);
            }
            sal[t] = wv; ssr[t] = s;
            ps += wv;
        }
        __syncthreads();
        int nbr = (nb + 3) & ~3;
        for (int u = 0; u < nbr; u += 4) {
            float a0 = sal[u], a1 = sal[u+1], a2 = sal[u+2], a3 = sal[u+3];
            int s0 = ssr[u], s1 = ssr[u+1], s2 = ssr[u+2], s3 = ssr[u+3];
            float h0 = __bfloat162float(h2b[(size_t)s0 * HIDD + t]);
            float h1 = __bfloat162float(h2b[(size_t)s1 * HIDD + t]);
            float h2 = __bfloat162float(h2b[(size_t)s2 * HIDD + t]);
            float h3 = __bfloat162float(h2b[(size_t)s3 * HIDD + t]);
            acc += a0*h0 + a1*h1 + a2*h2 + a3*h3;
        }
    }
    float pst = block_reduce_sum1(ps, sred);
    float inv = 1.f / (pst + 1e-16f);
    float vf = acc * inv + b2[t];
    vf = vf > 0.f ? vf : (__expf(vf) - 1.f);
    float mu = block_reduce_sum1(vf, sred) * (1.f / 256.f);
    float dv = vf - mu;
    float var = block_reduce_sum1(dv * dv, sred) * (1.f / 256.f);
    float rstd = rsqrtf(var + 1e-5f);
    float outv = g2[t] * dv * rstd + be2[t];
    int rep = blockIdx.x & (NREP - 1);
    atomicAdd(&gsum[rep * 256 + t], outv);
    unsigned b = __float_as_uint(outv);
    unsigned k = (b & 0x80000000u) ? ~b : (b | 0x80000000u);
    atomicMax(&gmaxU[rep * 256 + t], k);
}

// ---------------- fold gvec + split-K FC into fcacc ----------------
__global__ void k_fcg(const float* __restrict__ gsum, const unsigned* __restrict__ gmaxU,
                      const float* __restrict__ Wfc, float* __restrict__ fcacc) {
    __shared__ float gv[512];
    int t = threadIdx.x;
    float s = 0.f; unsigned km = 0u;
    for (int r = 0; r < NREP; r++) {
        s += gsum[r * 256 + t];
        unsigned k = gmaxU[r * 256 + t];
        km = k > km ? k : km;
    }
    gv[t] = s * (1.f / (float)NN);
    unsigned b = (km & 0x80000000u) ? (km & 0x7fffffffu) : ~km;
    gv[256 + t] = __uint_as_float(b);
    __syncthreads();
    int kc = blockIdx.x >> 2;
    int c = (blockIdx.x & 3) * 256 + t;
    int r0 = kc * 64;
    float acc = 0.f;
    #pragma unroll 8
    for (int i = 0; i < 64; i++) acc += gv[r0 + i] * Wfc[(size_t)(r0 + i) * LATD + c];
    atomicAdd(&fcacc[c], acc);
}

__global__ void k_out(const float* __restrict__ fcacc, const float* __restrict__ bfc,
                      const float* __restrict__ gf, const float* __restrict__ bf,
                      float* __restrict__ outp) {
    __shared__ float sm[16];
    int t = threadIdx.x;
    float v = fmaxf(fcacc[t] + bfc[t], 0.f);
    float mu = block_reduce_sum1(v, sm) * (1.f / 1024.f);
    float dv = v - mu;
    float var = block_reduce_sum1(dv * dv, sm) * (1.f / 1024.f);
    float rstd = rsqrtf(var + 1e-5f);
    outp[t] = gf[t] * dv * rstd + bf[t];
}

// ---------------- launch ----------------
extern "C" void kernel_launch(void* const* d_in, const int* in_sizes, int n_in,
                              void* d_out, int out_size, void* d_ws, size_t ws_size,
                              hipStream_t stream) {
    const float* x      = (const float*)d_in[0];
    const float* ea     = (const float*)d_in[1];
    const float* W1     = (const float*)d_in[2];
    const float* a_src1 = (const float*)d_in[3];
    const float* a_dst1 = (const float*)d_in[4];
    const float* We1    = (const float*)d_in[5];
    const float* a_e1   = (const float*)d_in[6];
    const float* b1     = (const float*)d_in[7];
    const float* g1     = (const float*)d_in[8];
    const float* be1    = (const float*)d_in[9];
    const float* W2     = (const float*)d_in[10];
    const float* a_src2 = (const float*)d_in[11];
    const float* a_dst2 = (const float*)d_in[12];
    const float* We2    = (const float*)d_in[13];
    const float* a_e2   = (const float*)d_in[14];
    const float* b2     = (const float*)d_in[15];
    const float* g2     = (const float*)d_in[16];
    const float* be2    = (const float*)d_in[17];
    const float* Wfc    = (const float*)d_in[18];
    const float* bfc    = (const float*)d_in[19];
    const float* gf     = (const float*)d_in[20];
    const float* bf     = (const float*)d_in[21];
    const int*   ei     = (const int*)d_in[22];
    float* outp = (float*)d_out;

    char* p = (char*)d_ws;
    auto alloc = [&](size_t bytes) -> char* {
        char* r = p;
        p += (bytes + 255) & ~(size_t)255;
        return r;
    };
    // zero zone (one memset): cnt, lea3, fill1, gsum, gmaxU, fcacc
    float* cnt     = (float*)alloc((size_t)NN * 4);
    float* lea3    = (float*)alloc((size_t)NN * 3 * 4);
    int*   fill1   = (int*)  alloc((size_t)NN * 4);
    float* gsum    = (float*)alloc((size_t)NREP * 256 * 4);
    unsigned* gmaxU= (unsigned*)alloc((size_t)NREP * 256 * 4);
    float* fcacc   = (float*)alloc(1024 * 4);
    size_t zbytes  = (size_t)((char*)fcacc + 1024*4 - (char*)cnt);
    float* prm     = (float*)alloc(256 * 4);
    float* al1     = (float*)alloc((size_t)NN * 8 * 4);
    float* al2     = (float*)alloc((size_t)NN * 2 * 4);
    int*   offs    = (int*)  alloc((size_t)(NN + 1) * 4);
    int*   csrs    = (int*)  alloc((size_t)NEP * 4);
    float* cex1    = (float*)alloc((size_t)NEP * 4 * 4);
    float* elog2   = (float*)alloc((size_t)NEP * 4);
    __hip_bfloat16* w1t = (__hip_bfloat16*)alloc((size_t)HCD * 32 * 2);
    __hip_bfloat16* h1b = (__hip_bfloat16*)alloc((size_t)MPAD * HCD * 2);
    __hip_bfloat16* w2t = (__hip_bfloat16*)alloc((size_t)HIDD * HCD * 2);
    __hip_bfloat16* h2b = (__hip_bfloat16*)alloc((size_t)NN * HIDD * 2);

    hipMemsetAsync(cnt, 0, zbytes, stream);

    k_front<<<73 + (NE + 255) / 256, 256, 0, stream>>>(W1, a_src1, a_dst1, We1, a_e1,
                                                       We2, a_e2, W2, ei, ea,
                                                       prm, w2t, w1t, cnt, lea3);
    k_scan<<<11, 1024, 0, stream>>>(cnt, x, prm, offs, al1);
    k_edge1<<<(NEP + 255) / 256, 256, 0, stream>>>(ei, ea, cnt, lea3, al1, prm, offs,
                                                   fill1, csrs, cex1, elog2);
    k_l1<<<NN / 16, 256, 0, stream>>>(offs, csrs, cex1, x, w1t, b1, g1, be1, h1b);
    k_gemm2m<<<313, 256, 0, stream>>>(h1b, w2t, a_src2, a_dst2, h2b, al2);
    k_agg2y<<<NN, 256, 0, stream>>>(offs, csrs, elog2, al2, h2b, b2, g2, be2,
                                    gsum, gmaxU);
    k_fcg<<<32, 256, 0, stream>>>(gsum, gmaxU, Wfc, fcacc);
    k_out<<<1, 1024, 0, stream>>>(fcacc, bfc, gf, bf, outp);
}

// Round 11
// 271.562 us; speedup vs baseline: 1.4243x; 1.0438x over previous
//
#include <hip/hip_runtime.h>
#include <hip/hip_bf16.h>

// Problem constants
#define NN   10000      // nodes
#define NE   160000     // edges
#define NEP  170000     // edges + self loops
#define IND  20         // input feature dim
#define HIDD 256        // hidden per head
#define NH   4          // heads layer 1
#define HCD  1024       // HEADS*HID
#define LATD 1024
#define MPAD 10112      // padded rows for h1b (>= 313*32 = 10016)
#define NREP 128        // pooling atomic replicas (contention spread)

typedef __attribute__((ext_vector_type(8))) short short8v;   // 8 bf16 (4 VGPRs)
typedef __attribute__((ext_vector_type(4))) float f32x4;     // MFMA accumulator

__device__ __forceinline__ unsigned pk2(float a, float b) {
    union { __hip_bfloat16 h; unsigned short s; } x, y;
    x.h = __float2bfloat16(a); y.h = __float2bfloat16(b);
    return (unsigned)x.s | ((unsigned)y.s << 16);
}

__device__ __forceinline__ unsigned short bf16bits(float a) {
    union { __hip_bfloat16 h; unsigned short s; } x;
    x.h = __float2bfloat16(a);
    return x.s;
}

// ---------------- block reduction helper ----------------
__device__ __forceinline__ float block_reduce_sum1(float v, float* sm) {
    #pragma unroll
    for (int o = 32; o > 0; o >>= 1) v += __shfl_xor(v, o, 64);
    int wid = threadIdx.x >> 6, lane = threadIdx.x & 63, nw = blockDim.x >> 6;
    if (lane == 0) sm[wid] = v;
    __syncthreads();
    float r = 0.f;
    for (int i = 0; i < nw; i++) r += sm[i];
    __syncthreads();
    return r;
}

// ---------------- merged front: W2 transpose + prm + W1t + degree histogram --------
// blocks 0..63: W2 -> W2t tiles; 64: prm; 65..72: W1 -> w1t[1024][32] bf16 (k-padded);
// blocks 73..697: degree histogram, ONE int atomic per edge (lea3 atomics deleted —
// self-loop attr mean now computed CSR-side in k_self).
__global__ void k_front(const float* __restrict__ W1, const float* __restrict__ as1,
                        const float* __restrict__ ad1, const float* __restrict__ We1,
                        const float* __restrict__ ae1, const float* __restrict__ We2,
                        const float* __restrict__ ae2, const float* __restrict__ W2,
                        const int* __restrict__ ei,
                        float* __restrict__ prm, __hip_bfloat16* __restrict__ Bt,
                        __hip_bfloat16* __restrict__ w1t, int* __restrict__ cnt) {
    int bid = blockIdx.x, t = threadIdx.x;
    if (bid < 64) {
        __shared__ float sm[64][65];
        int k0 = (bid & 15) * 64, c0 = (bid >> 4) * 64;
        #pragma unroll
        for (int i = 0; i < 16; i++) {
            int idx = i * 256 + t;
            int r = idx >> 6, c = idx & 63;
            sm[r][c] = W2[(size_t)(k0 + r) * 256 + c0 + c];
        }
        __syncthreads();
        int c = t >> 2, kq = t & 3;
        unsigned int out[8];
        #pragma unroll
        for (int j = 0; j < 8; j++)
            out[j] = pk2(sm[kq * 16 + 2*j][c], sm[kq * 16 + 2*j + 1][c]);
        unsigned int* dst = (unsigned int*)(Bt + (size_t)(c0 + c) * 1024 + k0 + kq * 16);
        *(uint4*)dst = make_uint4(out[0], out[1], out[2], out[3]);
        *(uint4*)(dst + 4) = make_uint4(out[4], out[5], out[6], out[7]);
    } else if (bid == 64) {
        if (t < 80) {
            int i = t >> 2, h = t & 3; float s = 0.f;
            for (int c = 0; c < HIDD; c++) s += W1[i*HCD + h*HIDD + c] * as1[h*HIDD + c];
            prm[t] = s;
        } else if (t < 160) {
            int u = t - 80; int i = u >> 2, h = u & 3; float s = 0.f;
            for (int c = 0; c < HIDD; c++) s += W1[i*HCD + h*HIDD + c] * ad1[h*HIDD + c];
            prm[t] = s;
        } else if (t < 172) {
            int u = t - 160; int j = u >> 2, h = u & 3; float s = 0.f;
            for (int c = 0; c < HIDD; c++) s += We1[j*HCD + h*HIDD + c] * ae1[h*HIDD + c];
            prm[t] = s;
        } else if (t < 175) {
            int j = t - 172; float s = 0.f;
            for (int c = 0; c < HIDD; c++) s += We2[j*HIDD + c] * ae2[c];
            prm[t] = s;
        }
    } else if (bid < 73) {
        // w1t[f][k] = W1[k][f] (bf16, k>=20 zero)
        int f = (bid - 65) * 128 + (t >> 1);
        int half = t & 1;
        #pragma unroll
        for (int kk = 0; kk < 16; kk++) {
            int k = half * 16 + kk;
            float v = (k < IND) ? W1[(size_t)k * HCD + f] : 0.f;
            w1t[(size_t)f * 32 + k] = __float2bfloat16(v);
        }
    } else {
        int e = (bid - 73) * 256 + t;
        if (e < NE) atomicAdd(&cnt[ei[NE + e]], 1);
    }
}

// ---------------- scan (block 0) + al1 (blocks 1..10); prm from PRIOR launch -------
__global__ void k_scan(const int* __restrict__ cnt, const float* __restrict__ x,
                       const float* __restrict__ prm, int* __restrict__ offs,
                       float* __restrict__ al1) {
    if (blockIdx.x == 0) {
        __shared__ int sm[1024];
        int t = threadIdx.x;
        int base = t * 10;
        int loc[10]; int s = 0;
        if (t < 1000) {
            #pragma unroll
            for (int i = 0; i < 10; i++) { loc[i] = s; s += cnt[base + i] + 1; }
        }
        sm[t] = (t < 1000) ? s : 0;
        __syncthreads();
        for (int o = 1; o < 1024; o <<= 1) {
            int xv = (t >= o) ? sm[t - o] : 0;
            __syncthreads();
            sm[t] += xv;
            __syncthreads();
        }
        int pre = (t > 0) ? sm[t - 1] : 0;
        if (t < 1000) {
            #pragma unroll
            for (int i = 0; i < 10; i++) offs[base + i] = pre + loc[i];
        }
        if (t == 1023) offs[NN] = sm[1023];
    } else {
        int v = (blockIdx.x - 1) * 1024 + threadIdx.x;
        if (v < NN) {
            float xr[IND];
            #pragma unroll
            for (int i = 0; i < IND; i++) xr[i] = x[v * IND + i];
            #pragma unroll
            for (int h = 0; h < NH; h++) {
                float s = 0.f, d2 = 0.f;
                #pragma unroll
                for (int i = 0; i < IND; i++) { s += xr[i] * prm[i*4 + h]; d2 += xr[i] * prm[80 + i*4 + h]; }
                al1[v*8 + h] = s;
                al1[v*8 + 4 + h] = d2;
            }
        }
    }
}

// ---------------- edge pass layer 1 (real edges only): logits, CSR fill, ea scatter -
__global__ void k_edge1(const int* __restrict__ ei, const float* __restrict__ ea,
                        const float* __restrict__ al1, const float* __restrict__ prm,
                        const int* __restrict__ offs, int* __restrict__ fill1,
                        int* __restrict__ csrs, float* __restrict__ cex1,
                        float* __restrict__ elog2, float* __restrict__ ea3) {
    int e = blockIdx.x * 256 + threadIdx.x;
    if (e >= NE) return;
    int s = ei[e], d = ei[NE + e];
    float e0 = ea[e*3], e1 = ea[e*3+1], e2 = ea[e*3+2];
    int slot = offs[d] + atomicAdd(&fill1[d], 1);
    csrs[slot] = s;
    ea3[(size_t)slot * 3]     = e0;
    ea3[(size_t)slot * 3 + 1] = e1;
    ea3[(size_t)slot * 3 + 2] = e2;
    elog2[slot] = e0*prm[172] + e1*prm[173] + e2*prm[174];
    float ex[4];
    #pragma unroll
    for (int h = 0; h < NH; h++) {
        float le = e0 * prm[160 + h] + e1 * prm[164 + h] + e2 * prm[168 + h];
        float lg = al1[s*8 + h] + al1[d*8 + 4 + h] + le;
        lg = lg > 0.f ? lg : 0.2f * lg;
        ex[h] = __expf(lg);
    }
    *(float4*)(cex1 + (size_t)slot * 4) = make_float4(ex[0], ex[1], ex[2], ex[3]);
}

// ---------------- self-loop pass: mean ea over CSR range -> last slot --------------
// Thread per node. Slots [beg, end-1) hold real edges (contiguous), end-1 reserved.
__global__ void k_self(const int* __restrict__ offs, const float* __restrict__ ea3,
                       const float* __restrict__ al1, const float* __restrict__ prm,
                       int* __restrict__ csrs, float* __restrict__ cex1,
                       float* __restrict__ elog2) {
    int v = blockIdx.x * 256 + threadIdx.x;
    if (v >= NN) return;
    int beg = offs[v], end1 = offs[v + 1] - 1;   // end1 = self-loop slot
    float s0 = 0.f, s1 = 0.f, s2 = 0.f;
    for (int j = beg; j < end1; ++j) {
        s0 += ea3[(size_t)j * 3];
        s1 += ea3[(size_t)j * 3 + 1];
        s2 += ea3[(size_t)j * 3 + 2];
    }
    float ic = 1.f / fmaxf((float)(end1 - beg), 1.0f);
    float e0 = s0 * ic, e1 = s1 * ic, e2 = s2 * ic;
    csrs[end1] = v;
    elog2[end1] = e0*prm[172] + e1*prm[173] + e2*prm[174];
    float ex[4];
    #pragma unroll
    for (int h = 0; h < NH; h++) {
        float le = e0 * prm[160 + h] + e1 * prm[164 + h] + e2 * prm[168 + h];
        float lg = al1[v*8 + h] + al1[v*8 + 4 + h] + le;
        lg = lg > 0.f ? lg : 0.2f * lg;
        ex[h] = __expf(lg);
    }
    *(float4*)(cex1 + (size_t)end1 * 4) = make_float4(ex[0], ex[1], ex[2], ex[3]);
}

// ---------------- layer-1 fused: edge-agg x + MFMA projection + bias+ELU+LN ---------
// Block = 16 nodes, 4 waves. Phase 1: wave w aggregates nodes w*4..w*4+3:
//   lane=(e=l>>2: 16 edges, fs=l&3: 5 feats each); normalized bf16 -> LDS xb[16][4][32].
// Phase 2: wave w = head w. Swapped-operand MFMA: D[f][v] = sum_k W1t[f][k]*xb[v][k].
__global__ void __launch_bounds__(256)
k_l1(const int* __restrict__ offs, const int* __restrict__ csrs,
     const float* __restrict__ cex1, const float* __restrict__ x,
     const __hip_bfloat16* __restrict__ w1t, const float* __restrict__ b1,
     const float* __restrict__ g1, const float* __restrict__ be1,
     __hip_bfloat16* __restrict__ h1b) {
    __shared__ unsigned short xb[16][4][32];   // [node][head][k] bf16, 4 KB
    __shared__ float sred[4][16][2];           // [wave][node][{sum,sumsq}]
    int t = threadIdx.x, l = t & 63, w = t >> 6;
    int vbase = blockIdx.x * 16;
    ((uint4*)xb)[t] = make_uint4(0, 0, 0, 0);  // zero incl. k=20..31 pad
    __syncthreads();
    int e = l >> 2, fs = l & 3;
    for (int nl = 0; nl < 4; nl++) {
        int v = vbase + w * 4 + nl;
        int beg = offs[v], end = offs[v + 1];
        float acc[4][5] = {};
        float psa[4] = {0.f, 0.f, 0.f, 0.f};
        for (int j0 = beg; j0 < end; j0 += 16) {
            int jl = j0 + e;
            bool valid = jl < end;
            int s = csrs[valid ? jl : beg];
            float4 a4 = valid ? *(const float4*)(cex1 + (size_t)jl * 4)
                              : make_float4(0.f, 0.f, 0.f, 0.f);
            psa[0] += a4.x; psa[1] += a4.y; psa[2] += a4.z; psa[3] += a4.w;
            #pragma unroll
            for (int k = 0; k < 5; k++) {
                float xv = x[(size_t)s * IND + fs * 5 + k];
                acc[0][k] += a4.x * xv; acc[1][k] += a4.y * xv;
                acc[2][k] += a4.z * xv; acc[3][k] += a4.w * xv;
            }
        }
        #pragma unroll
        for (int o = 4; o <= 32; o <<= 1) {
            #pragma unroll
            for (int h = 0; h < 4; h++) {
                psa[h] += __shfl_xor(psa[h], o, 64);
                #pragma unroll
                for (int k = 0; k < 5; k++) acc[h][k] += __shfl_xor(acc[h][k], o, 64);
            }
        }
        if (e == 0) {
            int node = w * 4 + nl;
            #pragma unroll
            for (int h = 0; h < 4; h++) {
                float inv = 1.f / (psa[h] + 1e-16f);
                #pragma unroll
                for (int k = 0; k < 5; k++)
                    xb[node][h][fs * 5 + k] = bf16bits(acc[h][k] * inv);
            }
        }
    }
    __syncthreads();
    // Phase 2: MFMA projection, head = w
    int vn = l & 15, g = l >> 4;
    short8v bfrag = *(const short8v*)&xb[vn][w][g * 8];
    const __hip_bfloat16* wp = w1t + ((size_t)w * 256 + vn) * 32 + g * 8;
    f32x4 accp[16];
    #pragma unroll
    for (int ft = 0; ft < 16; ft++) {
        short8v afrag = *(const short8v*)(wp + (size_t)ft * 16 * 32);
        accp[ft] = __builtin_amdgcn_mfma_f32_16x16x32_bf16(afrag, bfrag,
                                                           (f32x4){0.f,0.f,0.f,0.f}, 0, 0, 0);
    }
    // bias + ELU + LN stats (lane owns node vn; holds 64 of its 1024 feats, head w)
    float s1 = 0.f, s2 = 0.f;
    #pragma unroll
    for (int ft = 0; ft < 16; ft++) {
        int fb = w * 256 + ft * 16 + g * 4;
        float4 bb = *(const float4*)(b1 + fb);
        #pragma unroll
        for (int r = 0; r < 4; r++) {
            float xv = accp[ft][r] + ((const float*)&bb)[r];
            xv = xv > 0.f ? xv : (__expf(xv) - 1.f);
            accp[ft][r] = xv;
            s1 += xv; s2 += xv * xv;
        }
    }
    s1 += __shfl_xor(s1, 16, 64); s1 += __shfl_xor(s1, 32, 64);
    s2 += __shfl_xor(s2, 16, 64); s2 += __shfl_xor(s2, 32, 64);
    if (g == 0) { sred[w][vn][0] = s1; sred[w][vn][1] = s2; }
    __syncthreads();
    float S1 = sred[0][vn][0] + sred[1][vn][0] + sred[2][vn][0] + sred[3][vn][0];
    float S2 = sred[0][vn][1] + sred[1][vn][1] + sred[2][vn][1] + sred[3][vn][1];
    float mu = S1 * (1.f / 1024.f);
    float var = S2 * (1.f / 1024.f) - mu * mu;
    float rstd = rsqrtf(var + 1e-5f);
    int v = vbase + vn;
    #pragma unroll
    for (int ft = 0; ft < 16; ft++) {
        int fb = w * 256 + ft * 16 + g * 4;
        float4 gg = *(const float4*)(g1 + fb);
        float4 ee = *(const float4*)(be1 + fb);
        unsigned p0 = pk2(gg.x * (accp[ft][0] - mu) * rstd + ee.x,
                          gg.y * (accp[ft][1] - mu) * rstd + ee.y);
        unsigned p1 = pk2(gg.z * (accp[ft][2] - mu) * rstd + ee.z,
                          gg.w * (accp[ft][3] - mu) * rstd + ee.w);
        *(uint2*)(h1b + (size_t)v * HCD + fb) = make_uint2(p0, p1);
    }
}

// ---------------- h2b = h1b @ W2t^T via MFMA; BM=32, BN=256; al2 epilogue ----------
__global__ void __launch_bounds__(256)
k_gemm2m(const __hip_bfloat16* __restrict__ A, const __hip_bfloat16* __restrict__ Bt,
         const float* __restrict__ as2, const float* __restrict__ ad2,
         __hip_bfloat16* __restrict__ h2b, float* __restrict__ al2) {
    __shared__ uint4 As4[256];           // 32 rows x 64 bf16, XOR-swizzled
    __shared__ float part[4][32][2];     // [wave][row][{s,d}]
    char* As = (char*)As4;
    int t = threadIdx.x, l = t & 63, w = t >> 6;
    int m0 = blockIdx.x * 32;
    int srow = t >> 3, skc = t & 7;
    const __hip_bfloat16* gA = A + (size_t)(m0 + srow) * 1024 + skc * 8;
    int wbyte = (srow * 128 + skc * 16) ^ ((srow & 7) << 4);
    int r0 = l & 15, g = l >> 4;
    int ra[2][2];
    #pragma unroll
    for (int m = 0; m < 2; m++)
        #pragma unroll
        for (int kk = 0; kk < 2; kk++) {
            int r = r0 + m * 16;
            ra[m][kk] = (r * 128 + kk * 64 + g * 16) ^ ((r & 7) << 4);
        }
    const __hip_bfloat16* gB = Bt + (size_t)(w * 64 + r0) * 1024 + g * 8;
    f32x4 acc[2][4];
    #pragma unroll
    for (int m = 0; m < 2; m++)
        #pragma unroll
        for (int n = 0; n < 4; n++) acc[m][n] = (f32x4){0.f,0.f,0.f,0.f};
    uint4 sreg = *(const uint4*)gA;
    for (int it = 0; it < 16; ++it) {
        *(uint4*)(As + wbyte) = sreg;
        __syncthreads();
        if (it < 15) sreg = *(const uint4*)(gA + (it + 1) * 64);
        int k0 = it * 64;
        short8v bfr[4][2];
        #pragma unroll
        for (int n = 0; n < 4; n++)
            #pragma unroll
            for (int kk = 0; kk < 2; kk++)
                bfr[n][kk] = *(const short8v*)(gB + (size_t)n * 16 * 1024 + k0 + kk * 32);
        short8v afr[2][2];
        #pragma unroll
        for (int m = 0; m < 2; m++)
            #pragma unroll
            for (int kk = 0; kk < 2; kk++)
                afr[m][kk] = *(const short8v*)(As + ra[m][kk]);
        #pragma unroll
        for (int kk = 0; kk < 2; kk++)
            #pragma unroll
            for (int m = 0; m < 2; m++)
                #pragma unroll
                for (int n = 0; n < 4; n++)
                    acc[m][n] = __builtin_amdgcn_mfma_f32_16x16x32_bf16(afr[m][kk], bfr[n][kk], acc[m][n], 0, 0, 0);
        __syncthreads();
    }
    // store h2b + al2 partials
    float as2v[4], ad2v[4];
    #pragma unroll
    for (int n = 0; n < 4; n++) {
        int col = w * 64 + n * 16 + r0;
        as2v[n] = as2[col]; ad2v[n] = ad2[col];
    }
    float sp[2][4], dp[2][4];
    #pragma unroll
    for (int m = 0; m < 2; m++)
        #pragma unroll
        for (int r = 0; r < 4; r++) { sp[m][r] = 0.f; dp[m][r] = 0.f; }
    #pragma unroll
    for (int m = 0; m < 2; m++) {
        #pragma unroll
        for (int r = 0; r < 4; r++) {
            int row = m0 + m * 16 + g * 4 + r;
            if (row < NN) {
                #pragma unroll
                for (int n = 0; n < 4; n++) {
                    int col = w * 64 + n * 16 + r0;
                    h2b[(size_t)row * HIDD + col] = __float2bfloat16(acc[m][n][r]);
                    sp[m][r] += acc[m][n][r] * as2v[n];
                    dp[m][r] += acc[m][n][r] * ad2v[n];
                }
            }
        }
    }
    #pragma unroll
    for (int o = 1; o <= 8; o <<= 1) {
        #pragma unroll
        for (int m = 0; m < 2; m++)
            #pragma unroll
            for (int r = 0; r < 4; r++) {
                sp[m][r] += __shfl_xor(sp[m][r], o, 64);
                dp[m][r] += __shfl_xor(dp[m][r], o, 64);
            }
    }
    if (r0 == 0) {
        #pragma unroll
        for (int m = 0; m < 2; m++)
            #pragma unroll
            for (int r = 0; r < 4; r++) {
                part[w][m * 16 + g * 4 + r][0] = sp[m][r];
                part[w][m * 16 + g * 4 + r][1] = dp[m][r];
            }
    }
    __syncthreads();
    if (t < 64) {
        int row = t >> 1, c = t & 1;
        if (m0 + row < NN) {
            float s = part[0][row][c] + part[1][row][c] + part[2][row][c] + part[3][row][c];
            al2[(m0 + row) * 2 + c] = s;
        }
    }
}

// ---------------- layer-2: inline logits + gather + bias+ELU+LN + pooling ----------
__global__ void __launch_bounds__(256)
k_agg2y(const int* __restrict__ offs, const int* __restrict__ csrs,
        const float* __restrict__ elog2, const float* __restrict__ al2,
        const __hip_bfloat16* __restrict__ h2b, const float* __restrict__ b2,
        const float* __restrict__ g2, const float* __restrict__ be2,
        float* __restrict__ gsum, unsigned* __restrict__ gmaxU) {
    __shared__ float sal[128];
    __shared__ int   ssr[128];
    __shared__ float sred[16];
    int t = threadIdx.x;
    int v = blockIdx.x;
    int beg = offs[v], end = offs[v + 1];
    float ald = al2[2 * v + 1];
    float acc = 0.f, ps = 0.f;
    for (int j0 = beg; j0 < end; j0 += 128) {
        int nb = end - j0; if (nb > 128) nb = 128;
        __syncthreads();
        if (t < 128) {
            int jl = j0 + t;
            float wv = 0.f; int s = 0;
            if (jl < end) {
                s = csrs[jl];
                float lg = al2[2 * s] + ald + elog2[jl];
                lg = lg > 0.f ? lg : 0.2f * lg;
                wv = __expf(lg);
            }
            sal[t] = wv; ssr[t] = s;
            ps += wv;
        }
        __syncthreads();
        int nbr = (nb + 3) & ~3;
        for (int u = 0; u < nbr; u += 4) {
            float a0 = sal[u], a1 = sal[u+1], a2 = sal[u+2], a3 = sal[u+3];
            int s0 = ssr[u], s1 = ssr[u+1], s2 = ssr[u+2], s3 = ssr[u+3];
            float h0 = __bfloat162float(h2b[(size_t)s0 * HIDD + t]);
            float h1 = __bfloat162float(h2b[(size_t)s1 * HIDD + t]);
            float h2 = __bfloat162float(h2b[(size_t)s2 * HIDD + t]);
            float h3 = __bfloat162float(h2b[(size_t)s3 * HIDD + t]);
            acc += a0*h0 + a1*h1 + a2*h2 + a3*h3;
        }
    }
    float pst = block_reduce_sum1(ps, sred);
    float inv = 1.f / (pst + 1e-16f);
    float vf = acc * inv + b2[t];
    vf = vf > 0.f ? vf : (__expf(vf) - 1.f);
    float mu = block_reduce_sum1(vf, sred) * (1.f / 256.f);
    float dv = vf - mu;
    float var = block_reduce_sum1(dv * dv, sred) * (1.f / 256.f);
    float rstd = rsqrtf(var + 1e-5f);
    float outv = g2[t] * dv * rstd + be2[t];
    int rep = blockIdx.x & (NREP - 1);
    atomicAdd(&gsum[rep * 256 + t], outv);
    unsigned b = __float_as_uint(outv);
    unsigned k = (b & 0x80000000u) ? ~b : (b | 0x80000000u);
    atomicMax(&gmaxU[rep * 256 + t], k);
}

// ---------------- fold gvec + split-K FC into fcacc ----------------
__global__ void k_fcg(const float* __restrict__ gsum, const unsigned* __restrict__ gmaxU,
                      const float* __restrict__ Wfc, float* __restrict__ fcacc) {
    __shared__ float gv[512];
    int t = threadIdx.x;
    float s = 0.f; unsigned km = 0u;
    for (int r = 0; r < NREP; r++) {
        s += gsum[r * 256 + t];
        unsigned k = gmaxU[r * 256 + t];
        km = k > km ? k : km;
    }
    gv[t] = s * (1.f / (float)NN);
    unsigned b = (km & 0x80000000u) ? (km & 0x7fffffffu) : ~km;
    gv[256 + t] = __uint_as_float(b);
    __syncthreads();
    int kc = blockIdx.x >> 2;
    int c = (blockIdx.x & 3) * 256 + t;
    int r0 = kc * 64;
    float acc = 0.f;
    #pragma unroll 8
    for (int i = 0; i < 64; i++) acc += gv[r0 + i] * Wfc[(size_t)(r0 + i) * LATD + c];
    atomicAdd(&fcacc[c], acc);
}

__global__ void k_out(const float* __restrict__ fcacc, const float* __restrict__ bfc,
                      const float* __restrict__ gf, const float* __restrict__ bf,
                      float* __restrict__ outp) {
    __shared__ float sm[16];
    int t = threadIdx.x;
    float v = fmaxf(fcacc[t] + bfc[t], 0.f);
    float mu = block_reduce_sum1(v, sm) * (1.f / 1024.f);
    float dv = v - mu;
    float var = block_reduce_sum1(dv * dv, sm) * (1.f / 1024.f);
    float rstd = rsqrtf(var + 1e-5f);
    outp[t] = gf[t] * dv * rstd + bf[t];
}

// ---------------- launch ----------------
extern "C" void kernel_launch(void* const* d_in, const int* in_sizes, int n_in,
                              void* d_out, int out_size, void* d_ws, size_t ws_size,
                              hipStream_t stream) {
    const float* x      = (const float*)d_in[0];
    const float* ea     = (const float*)d_in[1];
    const float* W1     = (const float*)d_in[2];
    const float* a_src1 = (const float*)d_in[3];
    const float* a_dst1 = (const float*)d_in[4];
    const float* We1    = (const float*)d_in[5];
    const float* a_e1   = (const float*)d_in[6];
    const float* b1     = (const float*)d_in[7];
    const float* g1     = (const float*)d_in[8];
    const float* be1    = (const float*)d_in[9];
    const float* W2     = (const float*)d_in[10];
    const float* a_src2 = (const float*)d_in[11];
    const float* a_dst2 = (const float*)d_in[12];
    const float* We2    = (const float*)d_in[13];
    const float* a_e2   = (const float*)d_in[14];
    const float* b2     = (const float*)d_in[15];
    const float* g2     = (const float*)d_in[16];
    const float* be2    = (const float*)d_in[17];
    const float* Wfc    = (const float*)d_in[18];
    const float* bfc    = (const float*)d_in[19];
    const float* gf     = (const float*)d_in[20];
    const float* bf     = (const float*)d_in[21];
    const int*   ei     = (const int*)d_in[22];
    float* outp = (float*)d_out;

    char* p = (char*)d_ws;
    auto alloc = [&](size_t bytes) -> char* {
        char* r = p;
        p += (bytes + 255) & ~(size_t)255;
        return r;
    };
    // zero zone (one memset): cnt, fill1, gsum, gmaxU, fcacc
    int*   cnt     = (int*)  alloc((size_t)NN * 4);
    int*   fill1   = (int*)  alloc((size_t)NN * 4);
    float* gsum    = (float*)alloc((size_t)NREP * 256 * 4);
    unsigned* gmaxU= (unsigned*)alloc((size_t)NREP * 256 * 4);
    float* fcacc   = (float*)alloc(1024 * 4);
    size_t zbytes  = (size_t)((char*)fcacc + 1024*4 - (char*)cnt);
    float* prm     = (float*)alloc(256 * 4);
    float* al1     = (float*)alloc((size_t)NN * 8 * 4);
    float* al2     = (float*)alloc((size_t)NN * 2 * 4);
    int*   offs    = (int*)  alloc((size_t)(NN + 1) * 4);
    int*   csrs    = (int*)  alloc((size_t)NEP * 4);
    float* cex1    = (float*)alloc((size_t)NEP * 4 * 4);
    float* elog2   = (float*)alloc((size_t)NEP * 4);
    float* ea3     = (float*)alloc((size_t)NEP * 3 * 4);
    __hip_bfloat16* w1t = (__hip_bfloat16*)alloc((size_t)HCD * 32 * 2);
    __hip_bfloat16* h1b = (__hip_bfloat16*)alloc((size_t)MPAD * HCD * 2);
    __hip_bfloat16* w2t = (__hip_bfloat16*)alloc((size_t)HIDD * HCD * 2);
    __hip_bfloat16* h2b = (__hip_bfloat16*)alloc((size_t)NN * HIDD * 2);

    hipMemsetAsync(cnt, 0, zbytes, stream);

    k_front<<<73 + (NE + 255) / 256, 256, 0, stream>>>(W1, a_src1, a_dst1, We1, a_e1,
                                                       We2, a_e2, W2, ei,
                                                       prm, w2t, w1t, cnt);
    k_scan<<<11, 1024, 0, stream>>>(cnt, x, prm, offs, al1);
    k_edge1<<<(NE + 255) / 256, 256, 0, stream>>>(ei, ea, al1, prm, offs,
                                                  fill1, csrs, cex1, elog2, ea3);
    k_self<<<(NN + 255) / 256, 256, 0, stream>>>(offs, ea3, al1, prm, csrs, cex1, elog2);
    k_l1<<<NN / 16, 256, 0, stream>>>(offs, csrs, cex1, x, w1t, b1, g1, be1, h1b);
    k_gemm2m<<<313, 256, 0, stream>>>(h1b, w2t, a_src2, a_dst2, h2b, al2);
    k_agg2y<<<NN, 256, 0, stream>>>(offs, csrs, elog2, al2, h2b, b2, g2, be2,
                                    gsum, gmaxU);
    k_fcg<<<32, 256, 0, stream>>>(gsum, gmaxU, Wfc, fcacc);
    k_out<<<1, 1024, 0, stream>>>(fcacc, bfc, gf, bf, outp);
}

// Round 13
// 261.883 us; speedup vs baseline: 1.4769x; 1.0370x over previous
//
#include <hip/hip_runtime.h>
#include <hip/hip_bf16.h>

// Problem constants
#define NN   10000      // nodes
#define NE   160000     // edges
#define NEP  170000     // edges + self loops
#define IND  20         // input feature dim
#define HIDD 256        // hidden per head
#define NH   4          // heads layer 1
#define HCD  1024       // HEADS*HID
#define LATD 1024
#define MPAD 10112      // padded rows for h1b (>= 313*32 = 10016)
#define NREP 128        // pooling atomic replicas (contention spread)

typedef __attribute__((ext_vector_type(8))) short short8v;   // 8 bf16 (4 VGPRs)
typedef __attribute__((ext_vector_type(4))) float f32x4;     // MFMA accumulator

__device__ __forceinline__ unsigned pk2(float a, float b) {
    union { __hip_bfloat16 h; unsigned short s; } x, y;
    x.h = __float2bfloat16(a); y.h = __float2bfloat16(b);
    return (unsigned)x.s | ((unsigned)y.s << 16);
}

__device__ __forceinline__ unsigned short bf16bits(float a) {
    union { __hip_bfloat16 h; unsigned short s; } x;
    x.h = __float2bfloat16(a);
    return x.s;
}

// ---------------- block reduction helper ----------------
__device__ __forceinline__ float block_reduce_sum1(float v, float* sm) {
    #pragma unroll
    for (int o = 32; o > 0; o >>= 1) v += __shfl_xor(v, o, 64);
    int wid = threadIdx.x >> 6, lane = threadIdx.x & 63, nw = blockDim.x >> 6;
    if (lane == 0) sm[wid] = v;
    __syncthreads();
    float r = 0.f;
    for (int i = 0; i < nw; i++) r += sm[i];
    __syncthreads();
    return r;
}

// ---------------- merged front: W2 transpose + prm + W1t + degree histogram --------
__global__ void k_front(const float* __restrict__ W1, const float* __restrict__ as1,
                        const float* __restrict__ ad1, const float* __restrict__ We1,
                        const float* __restrict__ ae1, const float* __restrict__ We2,
                        const float* __restrict__ ae2, const float* __restrict__ W2,
                        const int* __restrict__ ei,
                        float* __restrict__ prm, __hip_bfloat16* __restrict__ Bt,
                        __hip_bfloat16* __restrict__ w1t, int* __restrict__ cnt) {
    int bid = blockIdx.x, t = threadIdx.x;
    if (bid < 64) {
        __shared__ float sm[64][65];
        int k0 = (bid & 15) * 64, c0 = (bid >> 4) * 64;
        #pragma unroll
        for (int i = 0; i < 16; i++) {
            int idx = i * 256 + t;
            int r = idx >> 6, c = idx & 63;
            sm[r][c] = W2[(size_t)(k0 + r) * 256 + c0 + c];
        }
        __syncthreads();
        int c = t >> 2, kq = t & 3;
        unsigned int out[8];
        #pragma unroll
        for (int j = 0; j < 8; j++)
            out[j] = pk2(sm[kq * 16 + 2*j][c], sm[kq * 16 + 2*j + 1][c]);
        unsigned int* dst = (unsigned int*)(Bt + (size_t)(c0 + c) * 1024 + k0 + kq * 16);
        *(uint4*)dst = make_uint4(out[0], out[1], out[2], out[3]);
        *(uint4*)(dst + 4) = make_uint4(out[4], out[5], out[6], out[7]);
    } else if (bid == 64) {
        if (t < 80) {
            int i = t >> 2, h = t & 3; float s = 0.f;
            for (int c = 0; c < HIDD; c++) s += W1[i*HCD + h*HIDD + c] * as1[h*HIDD + c];
            prm[t] = s;
        } else if (t < 160) {
            int u = t - 80; int i = u >> 2, h = u & 3; float s = 0.f;
            for (int c = 0; c < HIDD; c++) s += W1[i*HCD + h*HIDD + c] * ad1[h*HIDD + c];
            prm[t] = s;
        } else if (t < 172) {
            int u = t - 160; int j = u >> 2, h = u & 3; float s = 0.f;
            for (int c = 0; c < HIDD; c++) s += We1[j*HCD + h*HIDD + c] * ae1[h*HIDD + c];
            prm[t] = s;
        } else if (t < 175) {
            int j = t - 172; float s = 0.f;
            for (int c = 0; c < HIDD; c++) s += We2[j*HIDD + c] * ae2[c];
            prm[t] = s;
        }
    } else if (bid < 73) {
        // w1t[f][k] = W1[k][f] (bf16, k>=20 zero)
        int f = (bid - 65) * 128 + (t >> 1);
        int half = t & 1;
        #pragma unroll
        for (int kk = 0; kk < 16; kk++) {
            int k = half * 16 + kk;
            float v = (k < IND) ? W1[(size_t)k * HCD + f] : 0.f;
            w1t[(size_t)f * 32 + k] = __float2bfloat16(v);
        }
    } else {
        int e = (bid - 73) * 256 + t;
        if (e < NE) atomicAdd(&cnt[ei[NE + e]], 1);
    }
}

// ---------------- scan (block 0) + al1 (blocks 1..10); prm from PRIOR launch -------
__global__ void k_scan(const int* __restrict__ cnt, const float* __restrict__ x,
                       const float* __restrict__ prm, int* __restrict__ offs,
                       float* __restrict__ al1) {
    if (blockIdx.x == 0) {
        __shared__ int sm[1024];
        int t = threadIdx.x;
        int base = t * 10;
        int loc[10]; int s = 0;
        if (t < 1000) {
            #pragma unroll
            for (int i = 0; i < 10; i++) { loc[i] = s; s += cnt[base + i] + 1; }
        }
        sm[t] = (t < 1000) ? s : 0;
        __syncthreads();
        for (int o = 1; o < 1024; o <<= 1) {
            int xv = (t >= o) ? sm[t - o] : 0;
            __syncthreads();
            sm[t] += xv;
            __syncthreads();
        }
        int pre = (t > 0) ? sm[t - 1] : 0;
        if (t < 1000) {
            #pragma unroll
            for (int i = 0; i < 10; i++) offs[base + i] = pre + loc[i];
        }
        if (t == 1023) offs[NN] = sm[1023];
    } else {
        int v = (blockIdx.x - 1) * 1024 + threadIdx.x;
        if (v < NN) {
            float xr[IND];
            #pragma unroll
            for (int i = 0; i < IND; i++) xr[i] = x[v * IND + i];
            #pragma unroll
            for (int h = 0; h < NH; h++) {
                float s = 0.f, d2 = 0.f;
                #pragma unroll
                for (int i = 0; i < IND; i++) { s += xr[i] * prm[i*4 + h]; d2 += xr[i] * prm[80 + i*4 + h]; }
                al1[v*8 + h] = s;
                al1[v*8 + 4 + h] = d2;
            }
        }
    }
}

// ---------------- edge pass layer 1 (real edges only): logits, CSR fill, ea scatter -
__global__ void k_edge1(const int* __restrict__ ei, const float* __restrict__ ea,
                        const float* __restrict__ al1, const float* __restrict__ prm,
                        const int* __restrict__ offs, int* __restrict__ fill1,
                        int* __restrict__ csrs, float* __restrict__ cex1,
                        float* __restrict__ elog2, float* __restrict__ ea3) {
    int e = blockIdx.x * 256 + threadIdx.x;
    if (e >= NE) return;
    int s = ei[e], d = ei[NE + e];
    float e0 = ea[e*3], e1 = ea[e*3+1], e2 = ea[e*3+2];
    int slot = offs[d] + atomicAdd(&fill1[d], 1);
    csrs[slot] = s;
    ea3[(size_t)slot * 3]     = e0;
    ea3[(size_t)slot * 3 + 1] = e1;
    ea3[(size_t)slot * 3 + 2] = e2;
    elog2[slot] = e0*prm[172] + e1*prm[173] + e2*prm[174];
    float ex[4];
    #pragma unroll
    for (int h = 0; h < NH; h++) {
        float le = e0 * prm[160 + h] + e1 * prm[164 + h] + e2 * prm[168 + h];
        float lg = al1[s*8 + h] + al1[d*8 + 4 + h] + le;
        lg = lg > 0.f ? lg : 0.2f * lg;
        ex[h] = __expf(lg);
    }
    *(float4*)(cex1 + (size_t)slot * 4) = make_float4(ex[0], ex[1], ex[2], ex[3]);
}

// ---------------- layer-1 fused: edge-agg x (+inline self-loop) + MFMA proj + LN ----
// Block = 16 nodes, 4 waves. Phase 1: wave w aggregates nodes w*4..w*4+3 over REAL
// edges [beg, end-1); ea3 component sums ride the same xor-butterfly; the self-loop
// alpha is then computed inline (replaces the old low-occupancy k_self kernel) and
// lane 0 emits csrs/elog2 for the reserved last slot (needed by k_agg2y).
// Phase 2: wave w = head w. Swapped-operand MFMA: D[f][v] = sum_k W1t[f][k]*xb[v][k].
__global__ void __launch_bounds__(256)
k_l1(const int* __restrict__ offs, const int* __restrict__ csrs_in,
     const float* __restrict__ cex1, const float* __restrict__ ea3,
     const float* __restrict__ al1, const float* __restrict__ x,
     const __hip_bfloat16* __restrict__ w1t, const float* __restrict__ prm,
     const float* __restrict__ b1, const float* __restrict__ g1,
     const float* __restrict__ be1, int* __restrict__ csrs_out,
     float* __restrict__ elog2, __hip_bfloat16* __restrict__ h1b) {
    __shared__ unsigned short xb[16][4][32];   // [node][head][k] bf16, 4 KB
    __shared__ float sred[4][16][2];           // [wave][node][{sum,sumsq}]
    int t = threadIdx.x, l = t & 63, w = t >> 6;
    int vbase = blockIdx.x * 16;
    ((uint4*)xb)[t] = make_uint4(0, 0, 0, 0);  // zero incl. k=20..31 pad
    __syncthreads();
    // hoist self-loop prm constants (broadcast scalars)
    float pe[3][4], pl[3];
    #pragma unroll
    for (int j = 0; j < 3; j++) {
        #pragma unroll
        for (int h = 0; h < 4; h++) pe[j][h] = prm[160 + j*4 + h];
        pl[j] = prm[172 + j];
    }
    int e = l >> 2, fs = l & 3;
    for (int nl = 0; nl < 4; nl++) {
        int v = vbase + w * 4 + nl;
        int beg = offs[v], end1 = offs[v + 1] - 1;   // real edges in [beg, end1)
        float acc[4][5] = {};
        float psa[4] = {0.f, 0.f, 0.f, 0.f};
        float eaS = 0.f;                             // component (fs<3) partial
        for (int j0 = beg; j0 < end1; j0 += 16) {
            int jl = j0 + e;
            bool valid = jl < end1;
            int s = csrs_in[valid ? jl : beg];
            float4 a4 = valid ? *(const float4*)(cex1 + (size_t)jl * 4)
                              : make_float4(0.f, 0.f, 0.f, 0.f);
            if (valid && fs < 3) eaS += ea3[(size_t)jl * 3 + fs];
            psa[0] += a4.x; psa[1] += a4.y; psa[2] += a4.z; psa[3] += a4.w;
            #pragma unroll
            for (int k = 0; k < 5; k++) {
                float xv = x[(size_t)s * IND + fs * 5 + k];
                acc[0][k] += a4.x * xv; acc[1][k] += a4.y * xv;
                acc[2][k] += a4.z * xv; acc[3][k] += a4.w * xv;
            }
        }
        #pragma unroll
        for (int o = 4; o <= 32; o <<= 1) {
            eaS += __shfl_xor(eaS, o, 64);
            #pragma unroll
            for (int h = 0; h < 4; h++) {
                psa[h] += __shfl_xor(psa[h], o, 64);
                #pragma unroll
                for (int k = 0; k < 5; k++) acc[h][k] += __shfl_xor(acc[h][k], o, 64);
            }
        }
        // self-loop inline: mean edge-attr over real edges, alpha, contribution
        float ic = 1.f / fmaxf((float)(end1 - beg), 1.0f);
        float e0 = __shfl(eaS, 0, 64) * ic;
        float e1 = __shfl(eaS, 1, 64) * ic;
        float e2 = __shfl(eaS, 2, 64) * ic;
        float exs[4];
        #pragma unroll
        for (int h = 0; h < 4; h++) {
            float le = e0 * pe[0][h] + e1 * pe[1][h] + e2 * pe[2][h];
            float lg = al1[v*8 + h] + al1[v*8 + 4 + h] + le;
            lg = lg > 0.f ? lg : 0.2f * lg;
            exs[h] = __expf(lg);
            psa[h] += exs[h];
        }
        #pragma unroll
        for (int k = 0; k < 5; k++) {
            float xv = x[(size_t)v * IND + fs * 5 + k];
            #pragma unroll
            for (int h = 0; h < 4; h++) acc[h][k] += exs[h] * xv;
        }
        if (l == 0) {
            csrs_out[end1] = v;
            elog2[end1] = e0*pl[0] + e1*pl[1] + e2*pl[2];
        }
        if (e == 0) {
            int node = w * 4 + nl;
            #pragma unroll
            for (int h = 0; h < 4; h++) {
                float inv = 1.f / (psa[h] + 1e-16f);
                #pragma unroll
                for (int k = 0; k < 5; k++)
                    xb[node][h][fs * 5 + k] = bf16bits(acc[h][k] * inv);
            }
        }
    }
    __syncthreads();
    // Phase 2: MFMA projection, head = w
    int vn = l & 15, g = l >> 4;
    short8v bfrag = *(const short8v*)&xb[vn][w][g * 8];
    const __hip_bfloat16* wp = w1t + ((size_t)w * 256 + vn) * 32 + g * 8;
    f32x4 accp[16];
    #pragma unroll
    for (int ft = 0; ft < 16; ft++) {
        short8v afrag = *(const short8v*)(wp + (size_t)ft * 16 * 32);
        accp[ft] = __builtin_amdgcn_mfma_f32_16x16x32_bf16(afrag, bfrag,
                                                           (f32x4){0.f,0.f,0.f,0.f}, 0, 0, 0);
    }
    // bias + ELU + LN stats (lane owns node vn; holds 64 of its 1024 feats, head w)
    float s1 = 0.f, s2 = 0.f;
    #pragma unroll
    for (int ft = 0; ft < 16; ft++) {
        int fb = w * 256 + ft * 16 + g * 4;
        float4 bb = *(const float4*)(b1 + fb);
        #pragma unroll
        for (int r = 0; r < 4; r++) {
            float xv = accp[ft][r] + ((const float*)&bb)[r];
            xv = xv > 0.f ? xv : (__expf(xv) - 1.f);
            accp[ft][r] = xv;
            s1 += xv; s2 += xv * xv;
        }
    }
    s1 += __shfl_xor(s1, 16, 64); s1 += __shfl_xor(s1, 32, 64);
    s2 += __shfl_xor(s2, 16, 64); s2 += __shfl_xor(s2, 32, 64);
    if (g == 0) { sred[w][vn][0] = s1; sred[w][vn][1] = s2; }
    __syncthreads();
    float S1 = sred[0][vn][0] + sred[1][vn][0] + sred[2][vn][0] + sred[3][vn][0];
    float S2 = sred[0][vn][1] + sred[1][vn][1] + sred[2][vn][1] + sred[3][vn][1];
    float mu = S1 * (1.f / 1024.f);
    float var = S2 * (1.f / 1024.f) - mu * mu;
    float rstd = rsqrtf(var + 1e-5f);
    int v = vbase + vn;
    #pragma unroll
    for (int ft = 0; ft < 16; ft++) {
        int fb = w * 256 + ft * 16 + g * 4;
        float4 gg = *(const float4*)(g1 + fb);
        float4 ee = *(const float4*)(be1 + fb);
        unsigned p0 = pk2(gg.x * (accp[ft][0] - mu) * rstd + ee.x,
                          gg.y * (accp[ft][1] - mu) * rstd + ee.y);
        unsigned p1 = pk2(gg.z * (accp[ft][2] - mu) * rstd + ee.z,
                          gg.w * (accp[ft][3] - mu) * rstd + ee.w);
        *(uint2*)(h1b + (size_t)v * HCD + fb) = make_uint2(p0, p1);
    }
}

// ---------------- h2b = h1b @ W2t^T via MFMA; BM=32, BN=256; al2 epilogue ----------
__global__ void __launch_bounds__(256)
k_gemm2m(const __hip_bfloat16* __restrict__ A, const __hip_bfloat16* __restrict__ Bt,
         const float* __restrict__ as2, const float* __restrict__ ad2,
         __hip_bfloat16* __restrict__ h2b, float* __restrict__ al2) {
    __shared__ uint4 As4[256];           // 32 rows x 64 bf16, XOR-swizzled
    __shared__ float part[4][32][2];     // [wave][row][{s,d}]
    char* As = (char*)As4;
    int t = threadIdx.x, l = t & 63, w = t >> 6;
    int m0 = blockIdx.x * 32;
    int srow = t >> 3, skc = t & 7;
    const __hip_bfloat16* gA = A + (size_t)(m0 + srow) * 1024 + skc * 8;
    int wbyte = (srow * 128 + skc * 16) ^ ((srow & 7) << 4);
    int r0 = l & 15, g = l >> 4;
    int ra[2][2];
    #pragma unroll
    for (int m = 0; m < 2; m++)
        #pragma unroll
        for (int kk = 0; kk < 2; kk++) {
            int r = r0 + m * 16;
            ra[m][kk] = (r * 128 + kk * 64 + g * 16) ^ ((r & 7) << 4);
        }
    const __hip_bfloat16* gB = Bt + (size_t)(w * 64 + r0) * 1024 + g * 8;
    f32x4 acc[2][4];
    #pragma unroll
    for (int m = 0; m < 2; m++)
        #pragma unroll
        for (int n = 0; n < 4; n++) acc[m][n] = (f32x4){0.f,0.f,0.f,0.f};
    uint4 sreg = *(const uint4*)gA;
    for (int it = 0; it < 16; ++it) {
        *(uint4*)(As + wbyte) = sreg;
        __syncthreads();
        if (it < 15) sreg = *(const uint4*)(gA + (it + 1) * 64);
        int k0 = it * 64;
        short8v bfr[4][2];
        #pragma unroll
        for (int n = 0; n < 4; n++)
            #pragma unroll
            for (int kk = 0; kk < 2; kk++)
                bfr[n][kk] = *(const short8v*)(gB + (size_t)n * 16 * 1024 + k0 + kk * 32);
        short8v afr[2][2];
        #pragma unroll
        for (int m = 0; m < 2; m++)
            #pragma unroll
            for (int kk = 0; kk < 2; kk++)
                afr[m][kk] = *(const short8v*)(As + ra[m][kk]);
        #pragma unroll
        for (int kk = 0; kk < 2; kk++)
            #pragma unroll
            for (int m = 0; m < 2; m++)
                #pragma unroll
                for (int n = 0; n < 4; n++)
                    acc[m][n] = __builtin_amdgcn_mfma_f32_16x16x32_bf16(afr[m][kk], bfr[n][kk], acc[m][n], 0, 0, 0);
        __syncthreads();
    }
    // store h2b + al2 partials
    float as2v[4], ad2v[4];
    #pragma unroll
    for (int n = 0; n < 4; n++) {
        int col = w * 64 + n * 16 + r0;
        as2v[n] = as2[col]; ad2v[n] = ad2[col];
    }
    float sp[2][4], dp[2][4];
    #pragma unroll
    for (int m = 0; m < 2; m++)
        #pragma unroll
        for (int r = 0; r < 4; r++) { sp[m][r] = 0.f; dp[m][r] = 0.f; }
    #pragma unroll
    for (int m = 0; m < 2; m++) {
        #pragma unroll
        for (int r = 0; r < 4; r++) {
            int row = m0 + m * 16 + g * 4 + r;
            if (row < NN) {
                #pragma unroll
                for (int n = 0; n < 4; n++) {
                    int col = w * 64 + n * 16 + r0;
                    h2b[(size_t)row * HIDD + col] = __float2bfloat16(acc[m][n][r]);
                    sp[m][r] += acc[m][n][r] * as2v[n];
                    dp[m][r] += acc[m][n][r] * ad2v[n];
                }
            }
        }
    }
    #pragma unroll
    for (int o = 1; o <= 8; o <<= 1) {
        #pragma unroll
        for (int m = 0; m < 2; m++)
            #pragma unroll
            for (int r = 0; r < 4; r++) {
                sp[m][r] += __shfl_xor(sp[m][r], o, 64);
                dp[m][r] += __shfl_xor(dp[m][r], o, 64);
            }
    }
    if (r0 == 0) {
        #pragma unroll
        for (int m = 0; m < 2; m++)
            #pragma unroll
            for (int r = 0; r < 4; r++) {
                part[w][m * 16 + g * 4 + r][0] = sp[m][r];
                part[w][m * 16 + g * 4 + r][1] = dp[m][r];
            }
    }
    __syncthreads();
    if (t < 64) {
        int row = t >> 1, c = t & 1;
        if (m0 + row < NN) {
            float s = part[0][row][c] + part[1][row][c] + part[2][row][c] + part[3][row][c];
            al2[(m0 + row) * 2 + c] = s;
        }
    }
}

// ---------------- layer-2: inline logits + gather + bias+ELU+LN + pooling ----------
__global__ void __launch_bounds__(256)
k_agg2y(const int* __restrict__ offs, const int* __restrict__ csrs,
        const float* __restrict__ elog2, const float* __restrict__ al2,
        const __hip_bfloat16* __restrict__ h2b, const float* __restrict__ b2,
        const float* __restrict__ g2, const float* __restrict__ be2,
        float* __restrict__ gsum, unsigned* __restrict__ gmaxU) {
    __shared__ float sal[128];
    __shared__ int   ssr[128];
    __shared__ float sred[16];
    int t = threadIdx.x;
    int v = blockIdx.x;
    int beg = offs[v], end = offs[v + 1];
    float ald = al2[2 * v + 1];
    float acc = 0.f, ps = 0.f;
    for (int j0 = beg; j0 < end; j0 += 128) {
        int nb = end - j0; if (nb > 128) nb = 128;
        __syncthreads();
        if (t < 128) {
            int jl = j0 + t;
            float wv = 0.f; int s = 0;
            if (jl < end) {
                s = csrs[jl];
                float lg = al2[2 * s] + ald + elog2[jl];
                lg = lg > 0.f ? lg : 0.2f * lg;
                wv = __expf(lg);
            }
            sal[t] = wv; ssr[t] = s;
            ps += wv;
        }
        __syncthreads();
        int nbr = (nb + 3) & ~3;
        for (int u = 0; u < nbr; u += 4) {
            float a0 = sal[u], a1 = sal[u+1], a2 = sal[u+2], a3 = sal[u+3];
            int s0 = ssr[u], s1 = ssr[u+1], s2 = ssr[u+2], s3 = ssr[u+3];
            float h0 = __bfloat162float(h2b[(size_t)s0 * HIDD + t]);
            float h1 = __bfloat162float(h2b[(size_t)s1 * HIDD + t]);
            float h2 = __bfloat162float(h2b[(size_t)s2 * HIDD + t]);
            float h3 = __bfloat162float(h2b[(size_t)s3 * HIDD + t]);
            acc += a0*h0 + a1*h1 + a2*h2 + a3*h3;
        }
    }
    float pst = block_reduce_sum1(ps, sred);
    float inv = 1.f / (pst + 1e-16f);
    float vf = acc * inv + b2[t];
    vf = vf > 0.f ? vf : (__expf(vf) - 1.f);
    float mu = block_reduce_sum1(vf, sred) * (1.f / 256.f);
    float dv = vf - mu;
    float var = block_reduce_sum1(dv * dv, sred) * (1.f / 256.f);
    float rstd = rsqrtf(var + 1e-5f);
    float outv = g2[t] * dv * rstd + be2[t];
    int rep = blockIdx.x & (NREP - 1);
    atomicAdd(&gsum[rep * 256 + t], outv);
    unsigned b = __float_as_uint(outv);
    unsigned k = (b & 0x80000000u) ? ~b : (b | 0x80000000u);
    atomicMax(&gmaxU[rep * 256 + t], k);
}

// ---------------- fold gvec + split-K FC into fcacc ----------------
__global__ void k_fcg(const float* __restrict__ gsum, const unsigned* __restrict__ gmaxU,
                      const float* __restrict__ Wfc, float* __restrict__ fcacc) {
    __shared__ float gv[512];
    int t = threadIdx.x;
    float s = 0.f; unsigned km = 0u;
    for (int r = 0; r < NREP; r++) {
        s += gsum[r * 256 + t];
        unsigned k = gmaxU[r * 256 + t];
        km = k > km ? k : km;
    }
    gv[t] = s * (1.f / (float)NN);
    unsigned b = (km & 0x80000000u) ? (km & 0x7fffffffu) : ~km;
    gv[256 + t] = __uint_as_float(b);
    __syncthreads();
    int kc = blockIdx.x >> 2;
    int c = (blockIdx.x & 3) * 256 + t;
    int r0 = kc * 64;
    float acc = 0.f;
    #pragma unroll 8
    for (int i = 0; i < 64; i++) acc += gv[r0 + i] * Wfc[(size_t)(r0 + i) * LATD + c];
    atomicAdd(&fcacc[c], acc);
}

__global__ void k_out(const float* __restrict__ fcacc, const float* __restrict__ bfc,
                      const float* __restrict__ gf, const float* __restrict__ bf,
                      float* __restrict__ outp) {
    __shared__ float sm[16];
    int t = threadIdx.x;
    float v = fmaxf(fcacc[t] + bfc[t], 0.f);
    float mu = block_reduce_sum1(v, sm) * (1.f / 1024.f);
    float dv = v - mu;
    float var = block_reduce_sum1(dv * dv, sm) * (1.f / 1024.f);
    float rstd = rsqrtf(var + 1e-5f);
    outp[t] = gf[t] * dv * rstd + bf[t];
}

// ---------------- launch ----------------
extern "C" void kernel_launch(void* const* d_in, const int* in_sizes, int n_in,
                              void* d_out, int out_size, void* d_ws, size_t ws_size,
                              hipStream_t stream) {
    const float* x      = (const float*)d_in[0];
    const float* ea     = (const float*)d_in[1];
    const float* W1     = (const float*)d_in[2];
    const float* a_src1 = (const float*)d_in[3];
    const float* a_dst1 = (const float*)d_in[4];
    const float* We1    = (const float*)d_in[5];
    const float* a_e1   = (const float*)d_in[6];
    const float* b1     = (const float*)d_in[7];
    const float* g1     = (const float*)d_in[8];
    const float* be1    = (const float*)d_in[9];
    const float* W2     = (const float*)d_in[10];
    const float* a_src2 = (const float*)d_in[11];
    const float* a_dst2 = (const float*)d_in[12];
    const float* We2    = (const float*)d_in[13];
    const float* a_e2   = (const float*)d_in[14];
    const float* b2     = (const float*)d_in[15];
    const float* g2     = (const float*)d_in[16];
    const float* be2    = (const float*)d_in[17];
    const float* Wfc    = (const float*)d_in[18];
    const float* bfc    = (const float*)d_in[19];
    const float* gf     = (const float*)d_in[20];
    const float* bf     = (const float*)d_in[21];
    const int*   ei     = (const int*)d_in[22];
    float* outp = (float*)d_out;

    char* p = (char*)d_ws;
    auto alloc = [&](size_t bytes) -> char* {
        char* r = p;
        p += (bytes + 255) & ~(size_t)255;
        return r;
    };
    // zero zone (one memset): cnt, fill1, gsum, gmaxU, fcacc
    int*   cnt     = (int*)  alloc((size_t)NN * 4);
    int*   fill1   = (int*)  alloc((size_t)NN * 4);
    float* gsum    = (float*)alloc((size_t)NREP * 256 * 4);
    unsigned* gmaxU= (unsigned*)alloc((size_t)NREP * 256 * 4);
    float* fcacc   = (float*)alloc(1024 * 4);
    size_t zbytes  = (size_t)((char*)fcacc + 1024*4 - (char*)cnt);
    float* prm     = (float*)alloc(256 * 4);
    float* al1     = (float*)alloc((size_t)NN * 8 * 4);
    float* al2     = (float*)alloc((size_t)NN * 2 * 4);
    int*   offs    = (int*)  alloc((size_t)(NN + 1) * 4);
    int*   csrs    = (int*)  alloc((size_t)NEP * 4);
    float* cex1    = (float*)alloc((size_t)NEP * 4 * 4);
    float* elog2   = (float*)alloc((size_t)NEP * 4);
    float* ea3     = (float*)alloc((size_t)NEP * 3 * 4);
    __hip_bfloat16* w1t = (__hip_bfloat16*)alloc((size_t)HCD * 32 * 2);
    __hip_bfloat16* h1b = (__hip_bfloat16*)alloc((size_t)MPAD * HCD * 2);
    __hip_bfloat16* w2t = (__hip_bfloat16*)alloc((size_t)HIDD * HCD * 2);
    __hip_bfloat16* h2b = (__hip_bfloat16*)alloc((size_t)NN * HIDD * 2);

    hipMemsetAsync(cnt, 0, zbytes, stream);

    k_front<<<73 + (NE + 255) / 256, 256, 0, stream>>>(W1, a_src1, a_dst1, We1, a_e1,
                                                       We2, a_e2, W2, ei,
                                                       prm, w2t, w1t, cnt);
    k_scan<<<11, 1024, 0, stream>>>(cnt, x, prm, offs, al1);
    k_edge1<<<(NE + 255) / 256, 256, 0, stream>>>(ei, ea, al1, prm, offs,
                                                  fill1, csrs, cex1, elog2, ea3);
    k_l1<<<NN / 16, 256, 0, stream>>>(offs, csrs, cex1, ea3, al1, x, w1t, prm,
                                      b1, g1, be1, csrs, elog2, h1b);
    k_gemm2m<<<313, 256, 0, stream>>>(h1b, w2t, a_src2, a_dst2, h2b, al2);
    k_agg2y<<<NN, 256, 0, stream>>>(offs, csrs, elog2, al2, h2b, b2, g2, be2,
                                    gsum, gmaxU);
    k_fcg<<<32, 256, 0, stream>>>(gsum, gmaxU, Wfc, fcacc);
    k_out<<<1, 1024, 0, stream>>>(fcacc, bfc, gf, bf, outp);
}